// Round 14
// baseline (344.437 us; speedup 1.0000x reference)
//
#include <hip/hip_runtime.h>
#include <cstdint>
#include <cstddef>

namespace {

constexpr int B_ = 4, NC_ = 4095, N_ = 4096, DIN_ = 64, D_ = 128, K_ = 6;
constexpr int XROW_ = 6 + DIN_;   // 70
constexpr int ROWS_ = B_ * N_;    // 16384
constexpr int KNQ = 4;            // queries per wave in knn
constexpr int KCAP = 48;          // hit-list capacity per query (looser T -> more hits)
constexpr int P1IT = 16;          // phase-1 subset iterations (1024 candidates)

typedef unsigned short u16;
typedef unsigned int u32;
typedef unsigned long long u64;
typedef __attribute__((ext_vector_type(8))) short short8;
typedef __attribute__((ext_vector_type(8))) unsigned short ushort8;
typedef __attribute__((ext_vector_type(4))) float f32x4;

__device__ __forceinline__ float sigm(float x) { return 1.f / (1.f + expf(-x)); }
__device__ __forceinline__ float silu(float x) { return x / (1.f + expf(-x)); }
__device__ __forceinline__ u16 f2bf(float x) {
    u32 u = __float_as_uint(x);
    u += 0x7FFFu + ((u >> 16) & 1u);
    return (u16)(u >> 16);
}
__device__ __forceinline__ float bf2f(u16 x) {
    return __uint_as_float(((u32)x) << 16);
}

// ---------------- prep: pos4 + feats(bf16) ----------------
__global__ void k_prep(const float* __restrict__ X, float4* __restrict__ pos4,
                       u16* __restrict__ featsb)
{
    int g = blockIdx.x * 256 + threadIdx.x;
    if (g >= ROWS_ * 64) return;
    int c = g & 63, row = g >> 6;
    int b = row >> 12, n = row & (N_ - 1);
    const float* xr = X + (size_t)(b * NC_ + n - 1) * XROW_;
    featsb[g] = (n > 0) ? f2bf(xr[6 + c]) : (u16)0;
    if (c == 0) {
        float4 p = {0.f, 0.f, 0.f, 0.f};
        if (n > 0) { p.x = xr[0]; p.y = xr[1]; p.z = xr[2]; }
        pos4[row] = p;
    }
}

// ---------------- knn helpers ----------------
__device__ __forceinline__ u64 shflxor64(u64 v, int mask)
{
    int lo = __shfl_xor((int)(u32)(v & 0xffffffffull), mask, 64);
    int hi = __shfl_xor((int)(u32)(v >> 32), mask, 64);
    return ((u64)(u32)hi << 32) | (u32)lo;
}

__device__ __forceinline__ float kth6min(float v)
{
    const float BIG = 3.4e38f;
    float kth = BIG;
    #pragma unroll
    for (int r = 0; r < 6; ++r) {
        float m = v;
        #pragma unroll
        for (int off = 1; off < 64; off <<= 1) m = fminf(m, __shfl_xor(m, off, 64));
        kth = m;
        if (v == m) v = BIG;   // dedup only raises bound (safe)
    }
    return kth;
}

__device__ __forceinline__ void geom_write(const float4* __restrict__ pb, int q, int j,
                                           size_t e, float* __restrict__ uv,
                                           float* __restrict__ rbfv)
{
    float4 pj = pb[j], pn = pb[q];
    float rx = pj.x - pn.x, ry = pj.y - pn.y, rz = pj.z - pn.z;
    float dist = sqrtf(rx * rx + ry * ry + rz * rz + 1e-8f);
    float inv = 1.f / dist;
    uv[e * 3 + 0] = rx * inv; uv[e * 3 + 1] = ry * inv; uv[e * 3 + 2] = rz * inv;
    #pragma unroll
    for (int r = 0; r < 16; ++r) {
        float t = (dist - (4.0f / 15.0f) * r) * 4.0f;
        rbfv[e * 16 + r] = expf(-t * t);
    }
}

// ---------------- KNN: 4 q/wave; SUBSET phase-1 threshold + full exact phase-2 ----------------
// Phase 1 scans only 1024 candidates: its 6th-smallest lane-min is >= true 6th-smallest
// over all 4096 (subset kth >= superset kth), so T remains a valid upper bound; phase 2
// (full scan, gated compaction) + extraction are exact as before.
__global__ __launch_bounds__(256) void k_knn(const float4* __restrict__ pos4,
                                             int* __restrict__ idxv,
                                             float* __restrict__ uv,
                                             float* __restrict__ rbfv)
{
    __shared__ u64 sHits[4][KNQ][KCAP];
    __shared__ int sCnt[4][KNQ];
    const int w = threadIdx.x >> 6, lane = threadIdx.x & 63;
    const int wave = (blockIdx.x << 2) | w;
    const int b = wave >> 10;
    const int i0 = (wave & 1023) << 2;
    const float4* pb = pos4 + (size_t)b * N_;
    const float BIG = 3.4e38f;

    if (lane < KNQ) sCnt[w][lane] = 0;
    __syncthreads();

    float4 qv[KNQ];
    #pragma unroll
    for (int qq = 0; qq < KNQ; ++qq) qv[qq] = pb[i0 + qq];

    // phase 1 (subset): per-lane min d2 per query over first 1024 candidates
    float dmin[KNQ];
    #pragma unroll
    for (int qq = 0; qq < KNQ; ++qq) dmin[qq] = BIG;
    #pragma unroll 4
    for (int it = 0; it < P1IT; ++it) {
        int j = lane + (it << 6);
        float4 p = pb[j];
        #pragma unroll
        for (int qq = 0; qq < KNQ; ++qq) {
            float dx = p.x - qv[qq].x, dy = p.y - qv[qq].y, dz = p.z - qv[qq].z;
            float dd = dx * dx + dy * dy + dz * dz;
            if (j != i0 + qq) dmin[qq] = fminf(dmin[qq], dd);
        }
    }
    float T[KNQ];
    #pragma unroll
    for (int qq = 0; qq < KNQ; ++qq) T[qq] = kth6min(dmin[qq]) * 1.000002f;

    // phase 2: full scan, compact hits (dd <= T) into LDS
    #pragma unroll 4
    for (int it = 0; it < 64; ++it) {
        int j = lane + (it << 6);
        float4 p = pb[j];
        #pragma unroll
        for (int qq = 0; qq < KNQ; ++qq) {
            float dx = p.x - qv[qq].x, dy = p.y - qv[qq].y, dz = p.z - qv[qq].z;
            float dd = dx * dx + dy * dy + dz * dz;
            if (dd <= T[qq] && j != i0 + qq) {
                int slot = atomicAdd(&sCnt[w][qq], 1);
                if (slot < KCAP)
                    sHits[w][qq][slot] = ((u64)__float_as_uint(dd) << 32) | (u32)j;
            }
        }
    }
    __syncthreads();

    // extraction: 16-lane group g handles query g; exact 6x min over hit list
    const int g = lane >> 4, li = lane & 15;
    const int cnt = sCnt[w][g];
    const int q = i0 + g;
    u64 ent[KCAP / 16];
    #pragma unroll
    for (int e = 0; e < KCAP / 16; ++e) {
        int slot = li + e * 16;
        ent[e] = (slot < (cnt < KCAP ? cnt : KCAP)) ? sHits[w][g][slot] : ~0ull;
    }
    int myj = -1;
    #pragma unroll
    for (int k = 0; k < 6; ++k) {
        u64 m = ent[0];
        #pragma unroll
        for (int e = 1; e < KCAP / 16; ++e) m = (ent[e] < m) ? ent[e] : m;
        #pragma unroll
        for (int off = 1; off < 16; off <<= 1) {
            u64 o = shflxor64(m, off);
            if (o < m) m = o;
        }
        if (li == k) myj = (int)(u32)(m & 0xffffffffull);
        #pragma unroll
        for (int e = 0; e < KCAP / 16; ++e) if (ent[e] == m) ent[e] = ~0ull;
    }
    if (cnt <= KCAP && li < 6) {
        size_t e = (size_t)(b * N_ + q) * 6 + li;
        idxv[e] = myj;
        geom_write(pb, q, myj, e, uv, rbfv);
    }

    // fallback for overflowed queries (exact per-lane insert; rare)
    u64 ovf = __ballot(li == 0 && cnt > KCAP);
    while (ovf) {
        int gl = __ffsll(ovf) - 1; ovf &= ovf - 1;
        int qq = gl >> 4;
        int qx = i0 + qq;
        float4 qp = pb[qx];
        float Tq = T[0];
        #pragma unroll
        for (int z = 1; z < KNQ; ++z) if (z == qq) Tq = T[z];
        float e0 = BIG, e1 = BIG, e2 = BIG, e3 = BIG, e4 = BIG, e5 = BIG;
        int j0 = 0, j1 = 0, j2 = 0, j3 = 0, j4 = 0, j5 = 0;
        for (int it = 0; it < 64; ++it) {
            int j = lane + (it << 6);
            float4 p = pb[j];
            float dx = p.x - qp.x, dy = p.y - qp.y, dz = p.z - qp.z;
            float dd = dx * dx + dy * dy + dz * dz;
            if (dd <= Tq && j != qx && dd < e5) {
                e5 = dd; j5 = j;
                float td; int tj;
                if (e5 < e4) { td = e4; e4 = e5; e5 = td; tj = j4; j4 = j5; j5 = tj; }
                if (e4 < e3) { td = e3; e3 = e4; e4 = td; tj = j3; j3 = j4; j4 = tj; }
                if (e3 < e2) { td = e2; e2 = e3; e3 = td; tj = j2; j2 = j3; j3 = tj; }
                if (e2 < e1) { td = e1; e1 = e2; e2 = td; tj = j1; j1 = j2; j2 = tj; }
                if (e1 < e0) { td = e0; e0 = e1; e1 = td; tj = j0; j0 = j1; j1 = tj; }
            }
        }
        u64 a0 = ((u64)__float_as_uint(e0) << 32) | (u32)j0;
        u64 a1 = ((u64)__float_as_uint(e1) << 32) | (u32)j1;
        u64 a2 = ((u64)__float_as_uint(e2) << 32) | (u32)j2;
        u64 a3 = ((u64)__float_as_uint(e3) << 32) | (u32)j3;
        u64 a4 = ((u64)__float_as_uint(e4) << 32) | (u32)j4;
        u64 a5 = ((u64)__float_as_uint(e5) << 32) | (u32)j5;
        int fj = -1;
        #pragma unroll
        for (int k = 0; k < 6; ++k) {
            u64 m = a0;
            #pragma unroll
            for (int off = 1; off < 64; off <<= 1) {
                u64 o = shflxor64(m, off);
                if (o < m) m = o;
            }
            if (a0 == m) { a0 = a1; a1 = a2; a2 = a3; a3 = a4; a4 = a5; a5 = ~0ull; }
            if (lane == k) fj = (int)(u32)(m & 0xffffffffull);
        }
        if (lane < 6) {
            size_t e = (size_t)(b * N_ + qx) * 6 + lane;
            idxv[e] = fj;
            geom_write(pb, qx, fj, e, uv, rbfv);
        }
    }
}

// ---------------- one-time weight prep (both layers) ----------------
// total flattened items: 49152+49152+16384*3+32768+384+64+4+256+2048+8192 = 191172
__global__ void k_prepw(const float* __restrict__ Wq, const float* __restrict__ Wk,
                        const float* __restrict__ Wv, const float* __restrict__ gw,
                        const float* __restrict__ fw1, const float* __restrict__ gb_,
                        const float* __restrict__ fb1, const float* __restrict__ Wvv,
                        const float* __restrict__ Wov, const float* __restrict__ Wo_,
                        const float* __restrict__ fw2, const float* __restrict__ rw2,
                        const float* __restrict__ rb2, const float* __restrict__ W_embed,
                        const float* __restrict__ rw1,
                        u16* __restrict__ WqkvT, u16* __restrict__ Wc2T,
                        u16* __restrict__ WvvT, u16* __restrict__ WovT,
                        u16* __restrict__ WoT, u16* __restrict__ fw2T,
                        u16* __restrict__ WembT,
                        float* __restrict__ bias2, float* __restrict__ rwg,
                        float* __restrict__ rw1T, float* __restrict__ rw2vT)
{
    const int l = blockIdx.y;
    int g = blockIdx.x * 256 + threadIdx.x;
    const float* Wq_l = Wq + l * 16384;  const float* Wk_l = Wk + l * 16384;
    const float* Wv_l = Wv + l * 16384;  const float* gw_l = gw + l * 16384;
    const float* fw1_l = fw1 + l * 32768; const float* gb_l = gb_ + l * 128;
    const float* fb1_l = fb1 + l * 256;  const float* Wvv_l = Wvv + l * 16384;
    const float* Wov_l = Wov + l * 16384; const float* Wo_ll = Wo_ + l * 16384;
    const float* fw2_l = fw2 + l * 32768; const float* rw2_l = rw2 + l * 4096;
    const float* rb2_l = rb2 + l * 256;  const float* rw1_l = rw1 + l * 256;

    if (g < 49152) {
        int n = g >> 7, k = g & 127;
        const float* src = (n < 128) ? Wq_l : ((n < 256) ? Wk_l : Wv_l);
        WqkvT[l * 49152 + g] = f2bf(src[k * 128 + (n & 127)]); return;
    }
    g -= 49152;
    if (g < 49152) {
        int n = g >> 7, k = g & 127;
        Wc2T[l * 49152 + g] = f2bf((n < 128) ? gw_l[k * 128 + n] : fw1_l[k * 256 + (n - 128)]); return;
    }
    g -= 49152;
    if (g < 16384) { int n = g >> 7, k = g & 127; WvvT[l * 16384 + g] = f2bf(Wvv_l[k * 128 + n]); return; }
    g -= 16384;
    if (g < 16384) { int n = g >> 7, k = g & 127; WovT[l * 16384 + g] = f2bf(Wov_l[k * 128 + n]); return; }
    g -= 16384;
    if (g < 16384) { int n = g >> 7, k = g & 127; WoT[l * 16384 + g] = f2bf(Wo_ll[k * 128 + n]); return; }
    g -= 16384;
    if (g < 32768) { int n = g >> 8, k = g & 255; fw2T[l * 32768 + g] = f2bf(fw2_l[k * 128 + n]); return; }
    g -= 32768;
    if (g < 384) { bias2[l * 384 + g] = (g < 128) ? gb_l[g] : fb1_l[g - 128]; return; }
    g -= 384;
    if (g < 64) {
        int hh = g >> 2, h = g & 3;
        float a = 0.f;
        #pragma unroll
        for (int dh = 0; dh < 32; ++dh) a += rw2_l[hh * 256 + h * 32 + dh];
        rwg[l * 128 + g] = a * (1.f / 32.f); return;
    }
    g -= 64;
    if (g < 4) {
        float a = 0.f;
        #pragma unroll
        for (int dh = 0; dh < 32; ++dh) a += rb2_l[g * 32 + dh];
        rwg[l * 128 + 64 + g] = a * (1.f / 32.f); return;
    }
    g -= 4;
    if (g < 256) {          // rw1T[l][hh][rr] = rw1[rr][hh]  (fp32)
        int hh = g >> 4, rr = g & 15;
        rw1T[l * 256 + hh * 16 + rr] = rw1_l[rr * 16 + hh]; return;
    }
    g -= 256;
    if (g < 2048) {         // rw2vT[l][t][hh] = rw2[hh][128+t]  (fp32)
        int t = g >> 4, hh = g & 15;
        rw2vT[l * 2048 + t * 16 + hh] = rw2_l[hh * 256 + 128 + t]; return;
    }
    g -= 2048;
    if (g < 8192 && l == 0) {
        int n = g >> 6, k = g & 63;
        WembT[g] = f2bf(W_embed[k * 128 + n]);
    }
}

// ---------------- MFMA bf16 GEMM: 64x128 tile, 4 waves x (64x32) ----------------
template<int KD, int EPI, bool LN, bool X1ACC>
__global__ __launch_bounds__(256) void k_mgemm(
    const u16* __restrict__ A, const u16* __restrict__ WT,
    const float* __restrict__ bias, const float* __restrict__ aux,
    float* __restrict__ C, u16* __restrict__ Cb, int ldc,
    const float* __restrict__ lns, const float* __restrict__ lnb,
    u16* __restrict__ lnout)
{
    __shared__ u16 sA[64 * 40];
    __shared__ u16 sB[128 * 40];
    const int tid = threadIdx.x;
    const int lane = tid & 63, wn = tid >> 6;
    const int m0 = blockIdx.x * 64, n0 = blockIdx.y * 128;
    f32x4 acc[4][2] = {};

    for (int k0 = 0; k0 < KD; k0 += 32) {
        __syncthreads();
        {
            int row = tid >> 2, gk = tid & 3;
            *(uint4*)&sA[row * 40 + gk * 8] =
                *(const uint4*)&A[(size_t)(m0 + row) * KD + k0 + gk * 8];
        }
        #pragma unroll
        for (int cc = 0; cc < 2; ++cc) {
            int c = tid * 2 + cc;
            int row = c >> 2, gk = c & 3;
            *(uint4*)&sB[row * 40 + gk * 8] =
                *(const uint4*)&WT[(size_t)(n0 + row) * KD + k0 + gk * 8];
        }
        __syncthreads();
        const int gk = lane >> 4, lr = lane & 15;
        short8 af[4], bfr[2];
        #pragma unroll
        for (int i = 0; i < 4; ++i)
            af[i] = *(const short8*)&sA[(i * 16 + lr) * 40 + gk * 8];
        #pragma unroll
        for (int i = 0; i < 2; ++i)
            bfr[i] = *(const short8*)&sB[(wn * 32 + i * 16 + lr) * 40 + gk * 8];
        #pragma unroll
        for (int mi = 0; mi < 4; ++mi)
            #pragma unroll
            for (int ni = 0; ni < 2; ++ni)
                acc[mi][ni] = __builtin_amdgcn_mfma_f32_16x16x32_bf16(af[mi], bfr[ni], acc[mi][ni], 0, 0, 0);
    }

    const int lg = lane >> 4;         // 0..3 row-group
    const int lc = lane & 15;         // col within 16
    if (LN) {
        __shared__ float sLN[64][4][2];
        float s1[4][4], s2[4][4];
        #pragma unroll
        for (int mi = 0; mi < 4; ++mi) {
            int rbase = m0 + mi * 16 + lg * 4;
            #pragma unroll
            for (int ee = 0; ee < 4; ++ee) { s1[mi][ee] = 0.f; s2[mi][ee] = 0.f; }
            #pragma unroll
            for (int ni = 0; ni < 2; ++ni) {
                int col = wn * 32 + ni * 16 + lc;
                float bc = bias ? bias[col] : 0.f;
                #pragma unroll
                for (int ee = 0; ee < 4; ++ee) {
                    float v = acc[mi][ni][ee] + bc;
                    if (EPI == 1) v += C[(size_t)(rbase + ee) * 128 + col];
                    acc[mi][ni][ee] = v;
                    s1[mi][ee] += v;
                    s2[mi][ee] += v * v;
                }
            }
        }
        #pragma unroll
        for (int mi = 0; mi < 4; ++mi)
            #pragma unroll
            for (int ee = 0; ee < 4; ++ee)
                #pragma unroll
                for (int off = 1; off < 16; off <<= 1) {
                    s1[mi][ee] += __shfl_xor(s1[mi][ee], off, 64);
                    s2[mi][ee] += __shfl_xor(s2[mi][ee], off, 64);
                }
        if (lc == 0) {
            #pragma unroll
            for (int mi = 0; mi < 4; ++mi)
                #pragma unroll
                for (int ee = 0; ee < 4; ++ee) {
                    int r = mi * 16 + lg * 4 + ee;
                    sLN[r][wn][0] = s1[mi][ee];
                    sLN[r][wn][1] = s2[mi][ee];
                }
        }
        __syncthreads();
        #pragma unroll
        for (int mi = 0; mi < 4; ++mi) {
            int rbase = m0 + mi * 16 + lg * 4;
            #pragma unroll
            for (int ee = 0; ee < 4; ++ee) {
                int r = mi * 16 + lg * 4 + ee;
                float sum = sLN[r][0][0] + sLN[r][1][0] + sLN[r][2][0] + sLN[r][3][0];
                float sq  = sLN[r][0][1] + sLN[r][1][1] + sLN[r][2][1] + sLN[r][3][1];
                float mean = sum * (1.f / 128.f);
                float var = sq * (1.f / 128.f) - mean * mean;
                float inv = 1.f / sqrtf(var + 1e-5f);
                #pragma unroll
                for (int ni = 0; ni < 2; ++ni) {
                    int col = wn * 32 + ni * 16 + lc;
                    float v = acc[mi][ni][ee];
                    size_t o = (size_t)(rbase + ee) * 128 + col;
                    C[o] = v;
                    lnout[o] = f2bf((v - mean) * inv * lns[col] + lnb[col]);
                }
            }
        }
        return;
    }

    #pragma unroll
    for (int mi = 0; mi < 4; ++mi) {
        int rbase = m0 + mi * 16 + lg * 4;
        #pragma unroll
        for (int ni = 0; ni < 2; ++ni) {
            int col = n0 + wn * 32 + ni * 16 + lc;
            if (EPI == 0) {
                float bc = bias ? bias[col] : 0.f;
                #pragma unroll
                for (int ee = 0; ee < 4; ++ee)
                    C[(size_t)(rbase + ee) * ldc + col] = acc[mi][ni][ee] + bc;
            } else if (EPI == 1) {
                float bc = bias ? bias[col] : 0.f;
                #pragma unroll
                for (int ee = 0; ee < 4; ++ee) {
                    size_t o = (size_t)(rbase + ee) * ldc + col;
                    C[o] += acc[mi][ni][ee] + bc;
                }
            } else if (EPI == 2) {
                float bc = bias[col];
                if (n0 == 0) {
                    #pragma unroll
                    for (int ee = 0; ee < 4; ++ee)
                        C[(size_t)(rbase + ee) * 128 + col] = sigm(acc[mi][ni][ee] + bc);
                } else {
                    int c2 = col - 128;
                    #pragma unroll
                    for (int ee = 0; ee < 4; ++ee)
                        Cb[(size_t)(rbase + ee) * 256 + c2] = f2bf(silu(acc[mi][ni][ee] + bc));
                }
            } else if (EPI == 4) {
                float bc = bias ? bias[col] : 0.f;
                #pragma unroll
                for (int ee = 0; ee < 4; ++ee)
                    Cb[(size_t)(rbase + ee) * ldc + col] = f2bf(acc[mi][ni][ee] + bc);
            } else {
                #pragma unroll
                for (int ee = 0; ee < 4; ++ee) {
                    int m = rbase + ee;
                    size_t o = (size_t)m * 128 + col;
                    float v = acc[mi][ni][ee];
                    if (X1ACC) v += C[o];
                    v *= aux[(size_t)(m / 3) * 128 + col];
                    C[o] = v;
                    Cb[o] = f2bf(v);
                }
            }
        }
    }
}

// ---------------- fp32 tiled GEMM (state head only) ----------------
template<int KD>
__global__ __launch_bounds__(256) void k_tgemm(
    const float* __restrict__ A, const float* __restrict__ W, const float* __restrict__ bias,
    float* __restrict__ C, int ldw, int ldc)
{
    __shared__ __align__(16) float As[32 * 132];
    __shared__ __align__(16) float Ws[32 * 68];
    const int tid = threadIdx.x;
    const int tx = tid & 15, ty = tid >> 4;
    const int m0 = blockIdx.x * 128, n0 = blockIdx.y * 64;
    float acc[8][4] = {};
    for (int k0 = 0; k0 < KD; k0 += 32) {
        __syncthreads();
        #pragma unroll
        for (int r = 0; r < 4; ++r) {
            int id = tid + r * 256;
            int row = id >> 3, kq = id & 7;
            float4 a4 = *(const float4*)&A[(size_t)(m0 + row) * KD + k0 + kq * 4];
            As[(kq * 4 + 0) * 132 + row] = a4.x;
            As[(kq * 4 + 1) * 132 + row] = a4.y;
            As[(kq * 4 + 2) * 132 + row] = a4.z;
            As[(kq * 4 + 3) * 132 + row] = a4.w;
        }
        #pragma unroll
        for (int r = 0; r < 2; ++r) {
            int id = tid + r * 256;
            int kr = id >> 4, cq = id & 15;
            *(float4*)&Ws[kr * 68 + cq * 4] =
                *(const float4*)&W[(size_t)(k0 + kr) * ldw + n0 + cq * 4];
        }
        __syncthreads();
        #pragma unroll 8
        for (int k = 0; k < 32; ++k) {
            float4 aA = *(const float4*)&As[k * 132 + ty * 8];
            float4 aB = *(const float4*)&As[k * 132 + ty * 8 + 4];
            float4 w4 = *(const float4*)&Ws[k * 68 + tx * 4];
            float av[8] = {aA.x, aA.y, aA.z, aA.w, aB.x, aB.y, aB.z, aB.w};
            float wv[4] = {w4.x, w4.y, w4.z, w4.w};
            #pragma unroll
            for (int r = 0; r < 8; ++r)
                #pragma unroll
                for (int j = 0; j < 4; ++j)
                    acc[r][j] += av[r] * wv[j];
        }
    }
    float bv[4];
    #pragma unroll
    for (int j = 0; j < 4; ++j) bv[j] = bias[n0 + tx * 4 + j];
    #pragma unroll
    for (int r = 0; r < 8; ++r) {
        int m = m0 + ty * 8 + r;
        int n = m & (N_ - 1), bb2 = m >> 12;
        if (n == 0) continue;
        float* dst = C + ((size_t)(bb2 * NC_ + n - 1)) * ldc + n0 + tx * 4;
        float4 res = {acc[r][0] + bv[0], acc[r][1] + bv[1], acc[r][2] + bv[2], acc[r][3] + bv[3]};
        *(float4*)dst = res;
    }
}

// ---------------- fused attention v3: wave-per-row, barrier-free ----------------
template<bool HASY1>
__global__ __launch_bounds__(256) void k_attn(
    const u16* __restrict__ qkvb, const int* __restrict__ idxv,
    const float* __restrict__ rbfv, const float* __restrict__ uv,
    const u16* __restrict__ y1b,
    const float* __restrict__ rw1T, const float* __restrict__ rb1,
    const float* __restrict__ rw2vT, const float* __restrict__ rwg,
    const float* __restrict__ rb2,
    u16* __restrict__ o0b, u16* __restrict__ o1b)
{
    const int wid = threadIdx.x >> 6, lane = threadIdx.x & 63;
    const int row = blockIdx.x * 4 + wid;
    const int b = row >> 12;
    const int ch0 = lane * 2;
    const int h = lane >> 4;

    __shared__ float sHid[4][6][16];
    __shared__ float sU[4][6][3];

    int jl = 0;
    if (lane < 6) jl = idxv[row * 6 + lane];
    int jj[6];
    #pragma unroll
    for (int k = 0; k < 6; ++k) jj[k] = __shfl(jl, k, 64);

    if (lane < 18) sU[wid][lane / 3][lane % 3] = uv[(size_t)row * 18 + lane];

    {
        int idx = lane;
        #pragma unroll
        for (int rep = 0; rep < 2; ++rep) {
            if (idx < 96) {
                int k = idx >> 4, hh = idx & 15;
                float a = rb1[hh];
                const float* rb = rbfv + (size_t)(row * 6 + k) * 16;
                const float* wr = rw1T + hh * 16;
                #pragma unroll
                for (int rr = 0; rr < 16; ++rr) a += rb[rr] * wr[rr];
                sHid[wid][k][hh] = silu(a);
            }
            idx += 64;
        }
    }
    __builtin_amdgcn_wave_barrier();
    __threadfence_block();
    __builtin_amdgcn_wave_barrier();

    u32 qp = *(const u32*)&qkvb[(size_t)row * 384 + ch0];
    float q0 = bf2f((u16)qp), q1 = bf2f((u16)(qp >> 16));

    float part[6];
    #pragma unroll
    for (int k = 0; k < 6; ++k) {
        u32 kp = *(const u32*)&qkvb[(size_t)(b * N_ + jj[k]) * 384 + 128 + ch0];
        part[k] = q0 * bf2f((u16)kp) + q1 * bf2f((u16)(kp >> 16));
    }
    #pragma unroll
    for (int off = 1; off < 16; off <<= 1)
        #pragma unroll
        for (int k = 0; k < 6; ++k)
            part[k] += __shfl_xor(part[k], off, 64);

    float lg[6];
    #pragma unroll
    for (int k = 0; k < 6; ++k) {
        float bias = rwg[64 + h];
        #pragma unroll
        for (int hh = 0; hh < 16; ++hh) bias += sHid[wid][k][hh] * rwg[hh * 4 + h];
        lg[k] = part[k] * 0.17677669529663687f + bias;
    }

    float mx = lg[0];
    #pragma unroll
    for (int k = 1; k < 6; ++k) mx = fmaxf(mx, lg[k]);
    float a[6], smv = 0.f;
    #pragma unroll
    for (int k = 0; k < 6; ++k) { a[k] = expf(lg[k] - mx); smv += a[k]; }
    float inv = 1.f / smv;
    #pragma unroll
    for (int k = 0; k < 6; ++k) a[k] *= inv;

    float rwc0[16], rwc1[16];
    {
        const float4* wp = (const float4*)(rw2vT + ch0 * 16);
        #pragma unroll
        for (int i = 0; i < 4; ++i) {
            float4 v0 = wp[i], v1 = wp[i + 4];
            rwc0[i * 4 + 0] = v0.x; rwc0[i * 4 + 1] = v0.y; rwc0[i * 4 + 2] = v0.z; rwc0[i * 4 + 3] = v0.w;
            rwc1[i * 4 + 0] = v1.x; rwc1[i * 4 + 1] = v1.y; rwc1[i * 4 + 2] = v1.z; rwc1[i * 4 + 3] = v1.w;
        }
    }
    float rb20 = rb2[128 + ch0], rb21 = rb2[128 + ch0 + 1];
    float rvk0[6], rvk1[6];
    #pragma unroll
    for (int k = 0; k < 6; ++k) {
        float a0 = rb20, a1 = rb21;
        #pragma unroll
        for (int hh = 0; hh < 16; ++hh) {
            float hv = sHid[wid][k][hh];
            a0 += hv * rwc0[hh];
            a1 += hv * rwc1[hh];
        }
        rvk0[k] = a0; rvk1[k] = a1;
    }

    float o00 = 0.f, o01 = 0.f;
    #pragma unroll
    for (int k = 0; k < 6; ++k) {
        u32 vp = *(const u32*)&qkvb[(size_t)(b * N_ + jj[k]) * 384 + 256 + ch0];
        o00 += a[k] * bf2f((u16)vp) * silu(rvk0[k]);
        o01 += a[k] * bf2f((u16)(vp >> 16)) * silu(rvk1[k]);
    }
    *(u32*)&o0b[(size_t)row * 128 + ch0] = (u32)f2bf(o00) | ((u32)f2bf(o01) << 16);

    #pragma unroll
    for (int c = 0; c < 3; ++c) {
        float s0 = 0.f, s1 = 0.f;
        #pragma unroll
        for (int k = 0; k < 6; ++k) {
            float b0 = 0.f, b1 = 0.f;
            if (HASY1) {
                u32 yp = *(const u32*)&y1b[((size_t)(b * N_ + jj[k]) * 3 + c) * 128 + ch0];
                b0 = bf2f((u16)yp); b1 = bf2f((u16)(yp >> 16));
            }
            float uk = sU[wid][k][c];
            s0 += a[k] * (b0 + rvk0[k] * uk);
            s1 += a[k] * (b1 + rvk1[k] * uk);
        }
        *(u32*)&o1b[((size_t)row * 3 + c) * 128 + ch0] = (u32)f2bf(s0) | ((u32)f2bf(s1) << 16);
    }
}

// ---------------- force head ----------------
__global__ void k_force1(const float* __restrict__ x1, const float* __restrict__ W,
                         const float* __restrict__ bias, float* __restrict__ frc)
{
    int g = blockIdx.x * 256 + threadIdx.x;
    if (g >= B_ * NC_ * 3) return;
    int c = g % 3, rr = g / 3;
    int b = rr / NC_, n = rr - b * NC_;
    const float* xr = x1 + (size_t)(b * N_ + n + 1) * 384 + c * 128;
    float a = bias[0];
    for (int d = 0; d < 128; ++d) a += xr[d] * W[d];
    frc[g] = a;
}

__global__ __launch_bounds__(256) void k_fsum(const float* __restrict__ frc, float* __restrict__ fsum)
{
    int b = blockIdx.x / 3, c = blockIdx.x % 3;
    __shared__ float red[256];
    float a = 0.f;
    for (int n = threadIdx.x; n < NC_; n += 256) a += frc[(b * NC_ + n) * 3 + c];
    red[threadIdx.x] = a; __syncthreads();
    for (int st = 128; st > 0; st >>= 1) { if (threadIdx.x < st) red[threadIdx.x] += red[threadIdx.x + st]; __syncthreads(); }
    if (threadIdx.x == 0) fsum[blockIdx.x] = red[0] / (float)NC_;
}

__global__ void k_force2(const float* __restrict__ frc, const float* __restrict__ fsum,
                         float* __restrict__ out)
{
    int g = blockIdx.x * 256 + threadIdx.x;
    if (g >= B_ * NC_ * 3) return;
    int c = g % 3;
    int b = g / (NC_ * 3);
    out[g] = frc[g] - fsum[b * 3 + c];
}

} // namespace

extern "C" void kernel_launch(void* const* d_in, const int* in_sizes, int n_in,
                              void* d_out, int out_size, void* d_ws, size_t ws_size,
                              hipStream_t stream)
{
    const float* X       = (const float*)d_in[0];
    const float* W_embed = (const float*)d_in[1];
    const float* b_embed = (const float*)d_in[2];
    const float* Wq      = (const float*)d_in[3];
    const float* Wk      = (const float*)d_in[4];
    const float* Wv      = (const float*)d_in[5];
    const float* Wvv     = (const float*)d_in[6];
    const float* rw1     = (const float*)d_in[7];
    const float* rb1     = (const float*)d_in[8];
    const float* rw2     = (const float*)d_in[9];
    const float* rb2     = (const float*)d_in[10];
    const float* Wo      = (const float*)d_in[11];
    const float* Wov     = (const float*)d_in[12];
    const float* ff_w1   = (const float*)d_in[13];
    const float* ff_b1   = (const float*)d_in[14];
    const float* ff_w2   = (const float*)d_in[15];
    const float* ff_b2   = (const float*)d_in[16];
    const float* gate_w  = (const float*)d_in[17];
    const float* gate_b  = (const float*)d_in[18];
    const float* ln1_s   = (const float*)d_in[19];
    const float* ln1_b   = (const float*)d_in[20];
    const float* ln2_s   = (const float*)d_in[21];
    const float* ln2_b   = (const float*)d_in[22];
    const float* W_state = (const float*)d_in[23];
    const float* b_state = (const float*)d_in[24];
    const float* W_force = (const float*)d_in[25];
    const float* b_force = (const float*)d_in[26];
    (void)in_sizes; (void)n_in; (void)out_size; (void)ws_size;

    float* out = (float*)d_out;
    float* w = (float*)d_ws;

    float4* pos4  = (float4*)w;                    // -> 65536
    int*    idxv  = (int*)(w + 65536);             // -> 163840
    float*  uv    = w + 163840;                    // -> 458752
    float*  rbfv  = w + 458752;                    // -> 2031616
    u16*    featsb= (u16*)(w + 2031616);           // -> 2555904 (frc/fsum alias later)
    float*  x0    = w + 2555904;                   // -> 4653056
    u16*    hbb   = (u16*)(w + 4653056);           // -> 5701632
    u16*    qkvbb = (u16*)(w + 5701632);           // -> 8847360 used
    float*  gb    = w + 11993088;                  // -> 14090240
    u16*    o0b   = (u16*)(w + 14090240);          // -> 15138816
    u16*    o1b   = (u16*)(w + 15138816);          // -> 18284544
    float*  x1    = w + 18284544;                  // -> 24576000
    u16*    x1b   = (u16*)(w + 24576000);          // -> 27721728
    u16*    t1b   = (u16*)(w + 27721728);          // bf16; also y1b (disjoint live ranges)
    u16*    y1b   = t1b;
    u16*    WqkvT = (u16*)(w + 34013184);
    u16*    Wc2T  = (u16*)(w + 34062336);
    u16*    WvvT  = (u16*)(w + 34111488);
    u16*    WovT  = (u16*)(w + 34127872);
    u16*    WoT   = (u16*)(w + 34144256);
    u16*    fw2T  = (u16*)(w + 34160640);
    u16*    WembT = (u16*)(w + 34193408);
    float*  bias2 = w + 34197504;                  // 2x384 -> 34198272
    float*  rwg   = w + 34198272;                  // 2x128 -> 34198528
    float*  rw1T  = w + 34198528;                  // 2x256 -> 34199040
    float*  rw2vT = w + 34199040;                  // 2x2048 -> 34203136
    float*  frc   = (float*)featsb;
    float*  fsum  = ((float*)featsb) + 49152;

    // one-time prep (both layers) + inputs   [747 blocks: 747*256=191232 >= 191172 items]
    k_prepw<<<dim3(747, 2), 256, 0, stream>>>(Wq, Wk, Wv, gate_w, ff_w1, gate_b, ff_b1,
                                              Wvv, Wov, Wo, ff_w2, rw2, rb2, W_embed, rw1,
                                              WqkvT, Wc2T, WvvT, WovT, WoT, fw2T, WembT,
                                              bias2, rwg, rw1T, rw2vT);
    k_prep<<<(ROWS_ * 64 + 255) / 256, 256, 0, stream>>>(X, pos4, featsb);
    k_knn<<<ROWS_ / 16, 256, 0, stream>>>(pos4, idxv, uv, rbfv);
    // x0 = feats @ W_embed + b_embed ; hbb = LN1(x0)
    k_mgemm<64, 0, true, true><<<dim3(256, 1), 256, 0, stream>>>(
        featsb, WembT, b_embed, nullptr, x0, nullptr, 128, ln1_s, ln1_b, hbb);

    for (int l = 0; l < 2; ++l) {
        const float* rb1_l = rb1 + l * 16;
        const float* rb2_l = rb2 + l * 256;
        const float* fb2_l = ff_b2 + l * 128;

        // qkv = h @ Wqkv (bf16 out)
        k_mgemm<128, 4, false, true><<<dim3(256, 3), 256, 0, stream>>>(
            hbb, WqkvT + l * 49152, nullptr, nullptr, nullptr, qkvbb, 384, nullptr, nullptr, nullptr);
        // y1 = x1 @ Wvv (bf16 out, layer 1 only)
        if (l > 0)
            k_mgemm<128, 4, false, true><<<dim3(768, 1), 256, 0, stream>>>(
                x1b, WvvT + l * 16384, nullptr, nullptr, nullptr, y1b, 128, nullptr, nullptr, nullptr);
        // attention (wave-per-row)
        if (l == 0)
            k_attn<false><<<ROWS_ / 4, 256, 0, stream>>>(qkvbb, idxv, rbfv, uv, nullptr,
                rw1T + l * 256, rb1_l, rw2vT + l * 2048, rwg + l * 128, rb2_l, o0b, o1b);
        else
            k_attn<true><<<ROWS_ / 4, 256, 0, stream>>>(qkvbb, idxv, rbfv, uv, y1b,
                rw1T + l * 256, rb1_l, rw2vT + l * 2048, rwg + l * 128, rb2_l, o0b, o1b);
        // x0 += o0 @ Wo ; hbb = LN2(x0)
        k_mgemm<128, 1, true, true><<<dim3(256, 1), 256, 0, stream>>>(
            o0b, WoT + l * 16384, nullptr, nullptr, x0, nullptr, 128,
            ln2_s + l * 128, ln2_b + l * 128, hbb);
        // [gate fp32 | t1 bf16] = h2 @ [gate_w|ff_w1]
        k_mgemm<128, 2, false, true><<<dim3(256, 3), 256, 0, stream>>>(
            hbb, Wc2T + l * 49152, bias2 + l * 384, nullptr, gb, t1b, 128, nullptr, nullptr, nullptr);
        // x1 = ((l? x1:0) + o1 @ Wov) * gate ; x1b = bf16(x1)
        if (l == 0)
            k_mgemm<128, 3, false, false><<<dim3(768, 1), 256, 0, stream>>>(
                o1b, WovT + l * 16384, nullptr, gb, x1, x1b, 128, nullptr, nullptr, nullptr);
        else
            k_mgemm<128, 3, false, true><<<dim3(768, 1), 256, 0, stream>>>(
                o1b, WovT + l * 16384, nullptr, gb, x1, x1b, 128, nullptr, nullptr, nullptr);
        // x0 += t1 @ ff_w2 + fb2 ; (l==0: hbb = LN1_{l+1}(x0))
        if (l == 0)
            k_mgemm<256, 1, true, true><<<dim3(256, 1), 256, 0, stream>>>(
                t1b, fw2T + l * 32768, fb2_l, nullptr, x0, nullptr, 128,
                ln1_s + 128, ln1_b + 128, hbb);
        else
            k_mgemm<256, 1, false, true><<<dim3(256, 1), 256, 0, stream>>>(
                t1b, fw2T + l * 32768, fb2_l, nullptr, x0, nullptr, 128, nullptr, nullptr, nullptr);
    }

    // state head -> out (row-remapped)
    k_tgemm<128><<<dim3(128, 1), 256, 0, stream>>>(x0, W_state, b_state, out, 64, 64);
    // force head
    k_force1<<<(B_ * NC_ * 3 + 255) / 256, 256, 0, stream>>>(x1, W_force, b_force, frc);
    k_fsum<<<12, 256, 0, stream>>>(frc, fsum);
    k_force2<<<(B_ * NC_ * 3 + 255) / 256, 256, 0, stream>>>(frc, fsum, out + (size_t)B_ * NC_ * DIN_);
}

// Round 15
// 323.455 us; speedup vs baseline: 1.0649x; 1.0649x over previous
//
#include <hip/hip_runtime.h>
#include <cstdint>
#include <cstddef>

namespace {

constexpr int B_ = 4, NC_ = 4095, N_ = 4096, DIN_ = 64, D_ = 128, K_ = 6;
constexpr int XROW_ = 6 + DIN_;   // 70
constexpr int ROWS_ = B_ * N_;    // 16384
constexpr int KNQ = 2;            // queries per wave in knn (occupancy: 8192 waves = 8/SIMD)
constexpr int KCAP = 32;          // hit-list capacity per query

typedef unsigned short u16;
typedef unsigned int u32;
typedef unsigned long long u64;
typedef __attribute__((ext_vector_type(8))) short short8;
typedef __attribute__((ext_vector_type(8))) unsigned short ushort8;
typedef __attribute__((ext_vector_type(4))) float f32x4;

__device__ __forceinline__ float sigm(float x) { return 1.f / (1.f + expf(-x)); }
__device__ __forceinline__ float silu(float x) { return x / (1.f + expf(-x)); }
__device__ __forceinline__ u16 f2bf(float x) {
    u32 u = __float_as_uint(x);
    u += 0x7FFFu + ((u >> 16) & 1u);
    return (u16)(u >> 16);
}
__device__ __forceinline__ float bf2f(u16 x) {
    return __uint_as_float(((u32)x) << 16);
}

// ---------------- prep: pos4 + feats(bf16) ----------------
__global__ void k_prep(const float* __restrict__ X, float4* __restrict__ pos4,
                       u16* __restrict__ featsb)
{
    int g = blockIdx.x * 256 + threadIdx.x;
    if (g >= ROWS_ * 64) return;
    int c = g & 63, row = g >> 6;
    int b = row >> 12, n = row & (N_ - 1);
    const float* xr = X + (size_t)(b * NC_ + n - 1) * XROW_;
    featsb[g] = (n > 0) ? f2bf(xr[6 + c]) : (u16)0;
    if (c == 0) {
        float4 p = {0.f, 0.f, 0.f, 0.f};
        if (n > 0) { p.x = xr[0]; p.y = xr[1]; p.z = xr[2]; }
        pos4[row] = p;
    }
}

// ---------------- knn helpers ----------------
__device__ __forceinline__ u64 shflxor64(u64 v, int mask)
{
    int lo = __shfl_xor((int)(u32)(v & 0xffffffffull), mask, 64);
    int hi = __shfl_xor((int)(u32)(v >> 32), mask, 64);
    return ((u64)(u32)hi << 32) | (u32)lo;
}

__device__ __forceinline__ float kth6min(float v)
{
    const float BIG = 3.4e38f;
    float kth = BIG;
    #pragma unroll
    for (int r = 0; r < 6; ++r) {
        float m = v;
        #pragma unroll
        for (int off = 1; off < 64; off <<= 1) m = fminf(m, __shfl_xor(m, off, 64));
        kth = m;
        if (v == m) v = BIG;   // dedup only raises bound (safe)
    }
    return kth;
}

__device__ __forceinline__ void geom_write(const float4* __restrict__ pb, int q, int j,
                                           size_t e, float* __restrict__ uv,
                                           float* __restrict__ rbfv)
{
    float4 pj = pb[j], pn = pb[q];
    float rx = pj.x - pn.x, ry = pj.y - pn.y, rz = pj.z - pn.z;
    float dist = sqrtf(rx * rx + ry * ry + rz * rz + 1e-8f);
    float inv = 1.f / dist;
    uv[e * 3 + 0] = rx * inv; uv[e * 3 + 1] = ry * inv; uv[e * 3 + 2] = rz * inv;
    #pragma unroll
    for (int r = 0; r < 16; ++r) {
        float t = (dist - (4.0f / 15.0f) * r) * 4.0f;
        rbfv[e * 16 + r] = expf(-t * t);
    }
}

// ---------------- KNN: 2 q/wave (8/SIMD occupancy), full exact two-phase ----------------
__global__ __launch_bounds__(256) void k_knn(const float4* __restrict__ pos4,
                                             int* __restrict__ idxv,
                                             float* __restrict__ uv,
                                             float* __restrict__ rbfv)
{
    __shared__ u64 sHits[4][KNQ][KCAP];
    __shared__ int sCnt[4][KNQ];
    const int w = threadIdx.x >> 6, lane = threadIdx.x & 63;
    const int wave = (blockIdx.x << 2) | w;
    const int b = wave >> 11;
    const int i0 = (wave & 2047) << 1;
    const float4* pb = pos4 + (size_t)b * N_;
    const float BIG = 3.4e38f;

    if (lane < KNQ) sCnt[w][lane] = 0;
    __syncthreads();

    float4 qv[KNQ];
    #pragma unroll
    for (int qq = 0; qq < KNQ; ++qq) qv[qq] = pb[i0 + qq];

    // phase 1: per-lane min d2 per query (full scan -> tight T)
    float dmin[KNQ];
    #pragma unroll
    for (int qq = 0; qq < KNQ; ++qq) dmin[qq] = BIG;
    #pragma unroll 4
    for (int it = 0; it < 64; ++it) {
        int j = lane + (it << 6);
        float4 p = pb[j];
        #pragma unroll
        for (int qq = 0; qq < KNQ; ++qq) {
            float dx = p.x - qv[qq].x, dy = p.y - qv[qq].y, dz = p.z - qv[qq].z;
            float dd = dx * dx + dy * dy + dz * dz;
            if (j != i0 + qq) dmin[qq] = fminf(dmin[qq], dd);
        }
    }
    float T[KNQ];
    #pragma unroll
    for (int qq = 0; qq < KNQ; ++qq) T[qq] = kth6min(dmin[qq]) * 1.000002f;

    // phase 2: compact hits (dd <= T) into LDS
    #pragma unroll 4
    for (int it = 0; it < 64; ++it) {
        int j = lane + (it << 6);
        float4 p = pb[j];
        #pragma unroll
        for (int qq = 0; qq < KNQ; ++qq) {
            float dx = p.x - qv[qq].x, dy = p.y - qv[qq].y, dz = p.z - qv[qq].z;
            float dd = dx * dx + dy * dy + dz * dz;
            if (dd <= T[qq] && j != i0 + qq) {
                int slot = atomicAdd(&sCnt[w][qq], 1);
                if (slot < KCAP)
                    sHits[w][qq][slot] = ((u64)__float_as_uint(dd) << 32) | (u32)j;
            }
        }
    }
    __syncthreads();

    // extraction: 32-lane group g handles query g; exact 6x min over hit list
    const int g = lane >> 5, li = lane & 31;
    const int cnt = sCnt[w][g];
    const int q = i0 + g;
    u64 ent = (li < (cnt < KCAP ? cnt : KCAP)) ? sHits[w][g][li] : ~0ull;
    int myj = -1;
    #pragma unroll
    for (int k = 0; k < 6; ++k) {
        u64 m = ent;
        #pragma unroll
        for (int off = 1; off < 32; off <<= 1) {     // offsets 1..16 stay within 32-half
            u64 o = shflxor64(m, off);
            if (o < m) m = o;
        }
        if (li == k) myj = (int)(u32)(m & 0xffffffffull);
        if (ent == m) ent = ~0ull;
    }
    if (cnt <= KCAP && li < 6) {
        size_t e = (size_t)(b * N_ + q) * 6 + li;
        idxv[e] = myj;
        geom_write(pb, q, myj, e, uv, rbfv);
    }

    // fallback for overflowed queries (exact per-lane insert; essentially never taken)
    u64 ovf = __ballot(li == 0 && cnt > KCAP);
    while (ovf) {
        int gl = __ffsll(ovf) - 1; ovf &= ovf - 1;
        int qq = gl >> 5;
        int qx = i0 + qq;
        float4 qp = pb[qx];
        float Tq = T[0];
        #pragma unroll
        for (int z = 1; z < KNQ; ++z) if (z == qq) Tq = T[z];
        float e0 = BIG, e1 = BIG, e2 = BIG, e3 = BIG, e4 = BIG, e5 = BIG;
        int j0 = 0, j1 = 0, j2 = 0, j3 = 0, j4 = 0, j5 = 0;
        for (int it = 0; it < 64; ++it) {
            int j = lane + (it << 6);
            float4 p = pb[j];
            float dx = p.x - qp.x, dy = p.y - qp.y, dz = p.z - qp.z;
            float dd = dx * dx + dy * dy + dz * dz;
            if (dd <= Tq && j != qx && dd < e5) {
                e5 = dd; j5 = j;
                float td; int tj;
                if (e5 < e4) { td = e4; e4 = e5; e5 = td; tj = j4; j4 = j5; j5 = tj; }
                if (e4 < e3) { td = e3; e3 = e4; e4 = td; tj = j3; j3 = j4; j4 = tj; }
                if (e3 < e2) { td = e2; e2 = e3; e3 = td; tj = j2; j2 = j3; j3 = tj; }
                if (e2 < e1) { td = e1; e1 = e2; e2 = td; tj = j1; j1 = j2; j2 = tj; }
                if (e1 < e0) { td = e0; e0 = e1; e1 = td; tj = j0; j0 = j1; j1 = tj; }
            }
        }
        u64 a0 = ((u64)__float_as_uint(e0) << 32) | (u32)j0;
        u64 a1 = ((u64)__float_as_uint(e1) << 32) | (u32)j1;
        u64 a2 = ((u64)__float_as_uint(e2) << 32) | (u32)j2;
        u64 a3 = ((u64)__float_as_uint(e3) << 32) | (u32)j3;
        u64 a4 = ((u64)__float_as_uint(e4) << 32) | (u32)j4;
        u64 a5 = ((u64)__float_as_uint(e5) << 32) | (u32)j5;
        int fj = -1;
        #pragma unroll
        for (int k = 0; k < 6; ++k) {
            u64 m = a0;
            #pragma unroll
            for (int off = 1; off < 64; off <<= 1) {
                u64 o = shflxor64(m, off);
                if (o < m) m = o;
            }
            if (a0 == m) { a0 = a1; a1 = a2; a2 = a3; a3 = a4; a4 = a5; a5 = ~0ull; }
            if (lane == k) fj = (int)(u32)(m & 0xffffffffull);
        }
        if (lane < 6) {
            size_t e = (size_t)(b * N_ + qx) * 6 + lane;
            idxv[e] = fj;
            geom_write(pb, qx, fj, e, uv, rbfv);
        }
    }
}

// ---------------- one-time weight prep (both layers) ----------------
// total flattened items: 49152+49152+16384*3+32768+384+64+4+256+2048+8192 = 191172
__global__ void k_prepw(const float* __restrict__ Wq, const float* __restrict__ Wk,
                        const float* __restrict__ Wv, const float* __restrict__ gw,
                        const float* __restrict__ fw1, const float* __restrict__ gb_,
                        const float* __restrict__ fb1, const float* __restrict__ Wvv,
                        const float* __restrict__ Wov, const float* __restrict__ Wo_,
                        const float* __restrict__ fw2, const float* __restrict__ rw2,
                        const float* __restrict__ rb2, const float* __restrict__ W_embed,
                        const float* __restrict__ rw1,
                        u16* __restrict__ WqkvT, u16* __restrict__ Wc2T,
                        u16* __restrict__ WvvT, u16* __restrict__ WovT,
                        u16* __restrict__ WoT, u16* __restrict__ fw2T,
                        u16* __restrict__ WembT,
                        float* __restrict__ bias2, float* __restrict__ rwg,
                        float* __restrict__ rw1T, float* __restrict__ rw2vT)
{
    const int l = blockIdx.y;
    int g = blockIdx.x * 256 + threadIdx.x;
    const float* Wq_l = Wq + l * 16384;  const float* Wk_l = Wk + l * 16384;
    const float* Wv_l = Wv + l * 16384;  const float* gw_l = gw + l * 16384;
    const float* fw1_l = fw1 + l * 32768; const float* gb_l = gb_ + l * 128;
    const float* fb1_l = fb1 + l * 256;  const float* Wvv_l = Wvv + l * 16384;
    const float* Wov_l = Wov + l * 16384; const float* Wo_ll = Wo_ + l * 16384;
    const float* fw2_l = fw2 + l * 32768; const float* rw2_l = rw2 + l * 4096;
    const float* rb2_l = rb2 + l * 256;  const float* rw1_l = rw1 + l * 256;

    if (g < 49152) {
        int n = g >> 7, k = g & 127;
        const float* src = (n < 128) ? Wq_l : ((n < 256) ? Wk_l : Wv_l);
        WqkvT[l * 49152 + g] = f2bf(src[k * 128 + (n & 127)]); return;
    }
    g -= 49152;
    if (g < 49152) {
        int n = g >> 7, k = g & 127;
        Wc2T[l * 49152 + g] = f2bf((n < 128) ? gw_l[k * 128 + n] : fw1_l[k * 256 + (n - 128)]); return;
    }
    g -= 49152;
    if (g < 16384) { int n = g >> 7, k = g & 127; WvvT[l * 16384 + g] = f2bf(Wvv_l[k * 128 + n]); return; }
    g -= 16384;
    if (g < 16384) { int n = g >> 7, k = g & 127; WovT[l * 16384 + g] = f2bf(Wov_l[k * 128 + n]); return; }
    g -= 16384;
    if (g < 16384) { int n = g >> 7, k = g & 127; WoT[l * 16384 + g] = f2bf(Wo_ll[k * 128 + n]); return; }
    g -= 16384;
    if (g < 32768) { int n = g >> 8, k = g & 255; fw2T[l * 32768 + g] = f2bf(fw2_l[k * 128 + n]); return; }
    g -= 32768;
    if (g < 384) { bias2[l * 384 + g] = (g < 128) ? gb_l[g] : fb1_l[g - 128]; return; }
    g -= 384;
    if (g < 64) {
        int hh = g >> 2, h = g & 3;
        float a = 0.f;
        #pragma unroll
        for (int dh = 0; dh < 32; ++dh) a += rw2_l[hh * 256 + h * 32 + dh];
        rwg[l * 128 + g] = a * (1.f / 32.f); return;
    }
    g -= 64;
    if (g < 4) {
        float a = 0.f;
        #pragma unroll
        for (int dh = 0; dh < 32; ++dh) a += rb2_l[g * 32 + dh];
        rwg[l * 128 + 64 + g] = a * (1.f / 32.f); return;
    }
    g -= 4;
    if (g < 256) {          // rw1T[l][hh][rr] = rw1[rr][hh]  (fp32)
        int hh = g >> 4, rr = g & 15;
        rw1T[l * 256 + hh * 16 + rr] = rw1_l[rr * 16 + hh]; return;
    }
    g -= 256;
    if (g < 2048) {         // rw2vT[l][t][hh] = rw2[hh][128+t]  (fp32)
        int t = g >> 4, hh = g & 15;
        rw2vT[l * 2048 + t * 16 + hh] = rw2_l[hh * 256 + 128 + t]; return;
    }
    g -= 2048;
    if (g < 8192 && l == 0) {
        int n = g >> 6, k = g & 63;
        WembT[g] = f2bf(W_embed[k * 128 + n]);
    }
}

// ---------------- MFMA bf16 GEMM: 64x128 tile, 4 waves x (64x32) ----------------
template<int KD, int EPI, bool LN, bool X1ACC>
__global__ __launch_bounds__(256) void k_mgemm(
    const u16* __restrict__ A, const u16* __restrict__ WT,
    const float* __restrict__ bias, const float* __restrict__ aux,
    float* __restrict__ C, u16* __restrict__ Cb, int ldc,
    const float* __restrict__ lns, const float* __restrict__ lnb,
    u16* __restrict__ lnout)
{
    __shared__ u16 sA[64 * 40];
    __shared__ u16 sB[128 * 40];
    const int tid = threadIdx.x;
    const int lane = tid & 63, wn = tid >> 6;
    const int m0 = blockIdx.x * 64, n0 = blockIdx.y * 128;
    f32x4 acc[4][2] = {};

    for (int k0 = 0; k0 < KD; k0 += 32) {
        __syncthreads();
        {
            int row = tid >> 2, gk = tid & 3;
            *(uint4*)&sA[row * 40 + gk * 8] =
                *(const uint4*)&A[(size_t)(m0 + row) * KD + k0 + gk * 8];
        }
        #pragma unroll
        for (int cc = 0; cc < 2; ++cc) {
            int c = tid * 2 + cc;
            int row = c >> 2, gk = c & 3;
            *(uint4*)&sB[row * 40 + gk * 8] =
                *(const uint4*)&WT[(size_t)(n0 + row) * KD + k0 + gk * 8];
        }
        __syncthreads();
        const int gk = lane >> 4, lr = lane & 15;
        short8 af[4], bfr[2];
        #pragma unroll
        for (int i = 0; i < 4; ++i)
            af[i] = *(const short8*)&sA[(i * 16 + lr) * 40 + gk * 8];
        #pragma unroll
        for (int i = 0; i < 2; ++i)
            bfr[i] = *(const short8*)&sB[(wn * 32 + i * 16 + lr) * 40 + gk * 8];
        #pragma unroll
        for (int mi = 0; mi < 4; ++mi)
            #pragma unroll
            for (int ni = 0; ni < 2; ++ni)
                acc[mi][ni] = __builtin_amdgcn_mfma_f32_16x16x32_bf16(af[mi], bfr[ni], acc[mi][ni], 0, 0, 0);
    }

    const int lg = lane >> 4;         // 0..3 row-group
    const int lc = lane & 15;         // col within 16
    if (LN) {
        __shared__ float sLN[64][4][2];
        float s1[4][4], s2[4][4];
        #pragma unroll
        for (int mi = 0; mi < 4; ++mi) {
            int rbase = m0 + mi * 16 + lg * 4;
            #pragma unroll
            for (int ee = 0; ee < 4; ++ee) { s1[mi][ee] = 0.f; s2[mi][ee] = 0.f; }
            #pragma unroll
            for (int ni = 0; ni < 2; ++ni) {
                int col = wn * 32 + ni * 16 + lc;
                float bc = bias ? bias[col] : 0.f;
                #pragma unroll
                for (int ee = 0; ee < 4; ++ee) {
                    float v = acc[mi][ni][ee] + bc;
                    if (EPI == 1) v += C[(size_t)(rbase + ee) * 128 + col];
                    acc[mi][ni][ee] = v;
                    s1[mi][ee] += v;
                    s2[mi][ee] += v * v;
                }
            }
        }
        #pragma unroll
        for (int mi = 0; mi < 4; ++mi)
            #pragma unroll
            for (int ee = 0; ee < 4; ++ee)
                #pragma unroll
                for (int off = 1; off < 16; off <<= 1) {
                    s1[mi][ee] += __shfl_xor(s1[mi][ee], off, 64);
                    s2[mi][ee] += __shfl_xor(s2[mi][ee], off, 64);
                }
        if (lc == 0) {
            #pragma unroll
            for (int mi = 0; mi < 4; ++mi)
                #pragma unroll
                for (int ee = 0; ee < 4; ++ee) {
                    int r = mi * 16 + lg * 4 + ee;
                    sLN[r][wn][0] = s1[mi][ee];
                    sLN[r][wn][1] = s2[mi][ee];
                }
        }
        __syncthreads();
        #pragma unroll
        for (int mi = 0; mi < 4; ++mi) {
            int rbase = m0 + mi * 16 + lg * 4;
            #pragma unroll
            for (int ee = 0; ee < 4; ++ee) {
                int r = mi * 16 + lg * 4 + ee;
                float sum = sLN[r][0][0] + sLN[r][1][0] + sLN[r][2][0] + sLN[r][3][0];
                float sq  = sLN[r][0][1] + sLN[r][1][1] + sLN[r][2][1] + sLN[r][3][1];
                float mean = sum * (1.f / 128.f);
                float var = sq * (1.f / 128.f) - mean * mean;
                float inv = 1.f / sqrtf(var + 1e-5f);
                #pragma unroll
                for (int ni = 0; ni < 2; ++ni) {
                    int col = wn * 32 + ni * 16 + lc;
                    float v = acc[mi][ni][ee];
                    size_t o = (size_t)(rbase + ee) * 128 + col;
                    C[o] = v;
                    lnout[o] = f2bf((v - mean) * inv * lns[col] + lnb[col]);
                }
            }
        }
        return;
    }

    #pragma unroll
    for (int mi = 0; mi < 4; ++mi) {
        int rbase = m0 + mi * 16 + lg * 4;
        #pragma unroll
        for (int ni = 0; ni < 2; ++ni) {
            int col = n0 + wn * 32 + ni * 16 + lc;
            if (EPI == 0) {
                float bc = bias ? bias[col] : 0.f;
                #pragma unroll
                for (int ee = 0; ee < 4; ++ee)
                    C[(size_t)(rbase + ee) * ldc + col] = acc[mi][ni][ee] + bc;
            } else if (EPI == 1) {
                float bc = bias ? bias[col] : 0.f;
                #pragma unroll
                for (int ee = 0; ee < 4; ++ee) {
                    size_t o = (size_t)(rbase + ee) * ldc + col;
                    C[o] += acc[mi][ni][ee] + bc;
                }
            } else if (EPI == 2) {
                float bc = bias[col];
                if (n0 == 0) {
                    #pragma unroll
                    for (int ee = 0; ee < 4; ++ee)
                        C[(size_t)(rbase + ee) * 128 + col] = sigm(acc[mi][ni][ee] + bc);
                } else {
                    int c2 = col - 128;
                    #pragma unroll
                    for (int ee = 0; ee < 4; ++ee)
                        Cb[(size_t)(rbase + ee) * 256 + c2] = f2bf(silu(acc[mi][ni][ee] + bc));
                }
            } else if (EPI == 4) {
                float bc = bias ? bias[col] : 0.f;
                #pragma unroll
                for (int ee = 0; ee < 4; ++ee)
                    Cb[(size_t)(rbase + ee) * ldc + col] = f2bf(acc[mi][ni][ee] + bc);
            } else {
                #pragma unroll
                for (int ee = 0; ee < 4; ++ee) {
                    int m = rbase + ee;
                    size_t o = (size_t)m * 128 + col;
                    float v = acc[mi][ni][ee];
                    if (X1ACC) v += C[o];
                    v *= aux[(size_t)(m / 3) * 128 + col];
                    C[o] = v;
                    Cb[o] = f2bf(v);
                }
            }
        }
    }
}

// ---------------- fp32 tiled GEMM (state head only) ----------------
template<int KD>
__global__ __launch_bounds__(256) void k_tgemm(
    const float* __restrict__ A, const float* __restrict__ W, const float* __restrict__ bias,
    float* __restrict__ C, int ldw, int ldc)
{
    __shared__ __align__(16) float As[32 * 132];
    __shared__ __align__(16) float Ws[32 * 68];
    const int tid = threadIdx.x;
    const int tx = tid & 15, ty = tid >> 4;
    const int m0 = blockIdx.x * 128, n0 = blockIdx.y * 64;
    float acc[8][4] = {};
    for (int k0 = 0; k0 < KD; k0 += 32) {
        __syncthreads();
        #pragma unroll
        for (int r = 0; r < 4; ++r) {
            int id = tid + r * 256;
            int row = id >> 3, kq = id & 7;
            float4 a4 = *(const float4*)&A[(size_t)(m0 + row) * KD + k0 + kq * 4];
            As[(kq * 4 + 0) * 132 + row] = a4.x;
            As[(kq * 4 + 1) * 132 + row] = a4.y;
            As[(kq * 4 + 2) * 132 + row] = a4.z;
            As[(kq * 4 + 3) * 132 + row] = a4.w;
        }
        #pragma unroll
        for (int r = 0; r < 2; ++r) {
            int id = tid + r * 256;
            int kr = id >> 4, cq = id & 15;
            *(float4*)&Ws[kr * 68 + cq * 4] =
                *(const float4*)&W[(size_t)(k0 + kr) * ldw + n0 + cq * 4];
        }
        __syncthreads();
        #pragma unroll 8
        for (int k = 0; k < 32; ++k) {
            float4 aA = *(const float4*)&As[k * 132 + ty * 8];
            float4 aB = *(const float4*)&As[k * 132 + ty * 8 + 4];
            float4 w4 = *(const float4*)&Ws[k * 68 + tx * 4];
            float av[8] = {aA.x, aA.y, aA.z, aA.w, aB.x, aB.y, aB.z, aB.w};
            float wv[4] = {w4.x, w4.y, w4.z, w4.w};
            #pragma unroll
            for (int r = 0; r < 8; ++r)
                #pragma unroll
                for (int j = 0; j < 4; ++j)
                    acc[r][j] += av[r] * wv[j];
        }
    }
    float bv[4];
    #pragma unroll
    for (int j = 0; j < 4; ++j) bv[j] = bias[n0 + tx * 4 + j];
    #pragma unroll
    for (int r = 0; r < 8; ++r) {
        int m = m0 + ty * 8 + r;
        int n = m & (N_ - 1), bb2 = m >> 12;
        if (n == 0) continue;
        float* dst = C + ((size_t)(bb2 * NC_ + n - 1)) * ldc + n0 + tx * 4;
        float4 res = {acc[r][0] + bv[0], acc[r][1] + bv[1], acc[r][2] + bv[2], acc[r][3] + bv[3]};
        *(float4*)dst = res;
    }
}

// ---------------- fused attention v3: wave-per-row, barrier-free ----------------
template<bool HASY1>
__global__ __launch_bounds__(256) void k_attn(
    const u16* __restrict__ qkvb, const int* __restrict__ idxv,
    const float* __restrict__ rbfv, const float* __restrict__ uv,
    const u16* __restrict__ y1b,
    const float* __restrict__ rw1T, const float* __restrict__ rb1,
    const float* __restrict__ rw2vT, const float* __restrict__ rwg,
    const float* __restrict__ rb2,
    u16* __restrict__ o0b, u16* __restrict__ o1b)
{
    const int wid = threadIdx.x >> 6, lane = threadIdx.x & 63;
    const int row = blockIdx.x * 4 + wid;
    const int b = row >> 12;
    const int ch0 = lane * 2;
    const int h = lane >> 4;

    __shared__ float sHid[4][6][16];
    __shared__ float sU[4][6][3];

    int jl = 0;
    if (lane < 6) jl = idxv[row * 6 + lane];
    int jj[6];
    #pragma unroll
    for (int k = 0; k < 6; ++k) jj[k] = __shfl(jl, k, 64);

    if (lane < 18) sU[wid][lane / 3][lane % 3] = uv[(size_t)row * 18 + lane];

    {
        int idx = lane;
        #pragma unroll
        for (int rep = 0; rep < 2; ++rep) {
            if (idx < 96) {
                int k = idx >> 4, hh = idx & 15;
                float a = rb1[hh];
                const float* rb = rbfv + (size_t)(row * 6 + k) * 16;
                const float* wr = rw1T + hh * 16;
                #pragma unroll
                for (int rr = 0; rr < 16; ++rr) a += rb[rr] * wr[rr];
                sHid[wid][k][hh] = silu(a);
            }
            idx += 64;
        }
    }
    __builtin_amdgcn_wave_barrier();
    __threadfence_block();
    __builtin_amdgcn_wave_barrier();

    u32 qp = *(const u32*)&qkvb[(size_t)row * 384 + ch0];
    float q0 = bf2f((u16)qp), q1 = bf2f((u16)(qp >> 16));

    float part[6];
    #pragma unroll
    for (int k = 0; k < 6; ++k) {
        u32 kp = *(const u32*)&qkvb[(size_t)(b * N_ + jj[k]) * 384 + 128 + ch0];
        part[k] = q0 * bf2f((u16)kp) + q1 * bf2f((u16)(kp >> 16));
    }
    #pragma unroll
    for (int off = 1; off < 16; off <<= 1)
        #pragma unroll
        for (int k = 0; k < 6; ++k)
            part[k] += __shfl_xor(part[k], off, 64);

    float lg[6];
    #pragma unroll
    for (int k = 0; k < 6; ++k) {
        float bias = rwg[64 + h];
        #pragma unroll
        for (int hh = 0; hh < 16; ++hh) bias += sHid[wid][k][hh] * rwg[hh * 4 + h];
        lg[k] = part[k] * 0.17677669529663687f + bias;
    }

    float mx = lg[0];
    #pragma unroll
    for (int k = 1; k < 6; ++k) mx = fmaxf(mx, lg[k]);
    float a[6], smv = 0.f;
    #pragma unroll
    for (int k = 0; k < 6; ++k) { a[k] = expf(lg[k] - mx); smv += a[k]; }
    float inv = 1.f / smv;
    #pragma unroll
    for (int k = 0; k < 6; ++k) a[k] *= inv;

    float rwc0[16], rwc1[16];
    {
        const float4* wp = (const float4*)(rw2vT + ch0 * 16);
        #pragma unroll
        for (int i = 0; i < 4; ++i) {
            float4 v0 = wp[i], v1 = wp[i + 4];
            rwc0[i * 4 + 0] = v0.x; rwc0[i * 4 + 1] = v0.y; rwc0[i * 4 + 2] = v0.z; rwc0[i * 4 + 3] = v0.w;
            rwc1[i * 4 + 0] = v1.x; rwc1[i * 4 + 1] = v1.y; rwc1[i * 4 + 2] = v1.z; rwc1[i * 4 + 3] = v1.w;
        }
    }
    float rb20 = rb2[128 + ch0], rb21 = rb2[128 + ch0 + 1];
    float rvk0[6], rvk1[6];
    #pragma unroll
    for (int k = 0; k < 6; ++k) {
        float a0 = rb20, a1 = rb21;
        #pragma unroll
        for (int hh = 0; hh < 16; ++hh) {
            float hv = sHid[wid][k][hh];
            a0 += hv * rwc0[hh];
            a1 += hv * rwc1[hh];
        }
        rvk0[k] = a0; rvk1[k] = a1;
    }

    float o00 = 0.f, o01 = 0.f;
    #pragma unroll
    for (int k = 0; k < 6; ++k) {
        u32 vp = *(const u32*)&qkvb[(size_t)(b * N_ + jj[k]) * 384 + 256 + ch0];
        o00 += a[k] * bf2f((u16)vp) * silu(rvk0[k]);
        o01 += a[k] * bf2f((u16)(vp >> 16)) * silu(rvk1[k]);
    }
    *(u32*)&o0b[(size_t)row * 128 + ch0] = (u32)f2bf(o00) | ((u32)f2bf(o01) << 16);

    #pragma unroll
    for (int c = 0; c < 3; ++c) {
        float s0 = 0.f, s1 = 0.f;
        #pragma unroll
        for (int k = 0; k < 6; ++k) {
            float b0 = 0.f, b1 = 0.f;
            if (HASY1) {
                u32 yp = *(const u32*)&y1b[((size_t)(b * N_ + jj[k]) * 3 + c) * 128 + ch0];
                b0 = bf2f((u16)yp); b1 = bf2f((u16)(yp >> 16));
            }
            float uk = sU[wid][k][c];
            s0 += a[k] * (b0 + rvk0[k] * uk);
            s1 += a[k] * (b1 + rvk1[k] * uk);
        }
        *(u32*)&o1b[((size_t)row * 3 + c) * 128 + ch0] = (u32)f2bf(s0) | ((u32)f2bf(s1) << 16);
    }
}

// ---------------- force head ----------------
__global__ void k_force1(const float* __restrict__ x1, const float* __restrict__ W,
                         const float* __restrict__ bias, float* __restrict__ frc)
{
    int g = blockIdx.x * 256 + threadIdx.x;
    if (g >= B_ * NC_ * 3) return;
    int c = g % 3, rr = g / 3;
    int b = rr / NC_, n = rr - b * NC_;
    const float* xr = x1 + (size_t)(b * N_ + n + 1) * 384 + c * 128;
    float a = bias[0];
    for (int d = 0; d < 128; ++d) a += xr[d] * W[d];
    frc[g] = a;
}

__global__ __launch_bounds__(256) void k_fsum(const float* __restrict__ frc, float* __restrict__ fsum)
{
    int b = blockIdx.x / 3, c = blockIdx.x % 3;
    __shared__ float red[256];
    float a = 0.f;
    for (int n = threadIdx.x; n < NC_; n += 256) a += frc[(b * NC_ + n) * 3 + c];
    red[threadIdx.x] = a; __syncthreads();
    for (int st = 128; st > 0; st >>= 1) { if (threadIdx.x < st) red[threadIdx.x] += red[threadIdx.x + st]; __syncthreads(); }
    if (threadIdx.x == 0) fsum[blockIdx.x] = red[0] / (float)NC_;
}

__global__ void k_force2(const float* __restrict__ frc, const float* __restrict__ fsum,
                         float* __restrict__ out)
{
    int g = blockIdx.x * 256 + threadIdx.x;
    if (g >= B_ * NC_ * 3) return;
    int c = g % 3;
    int b = g / (NC_ * 3);
    out[g] = frc[g] - fsum[b * 3 + c];
}

} // namespace

extern "C" void kernel_launch(void* const* d_in, const int* in_sizes, int n_in,
                              void* d_out, int out_size, void* d_ws, size_t ws_size,
                              hipStream_t stream)
{
    const float* X       = (const float*)d_in[0];
    const float* W_embed = (const float*)d_in[1];
    const float* b_embed = (const float*)d_in[2];
    const float* Wq      = (const float*)d_in[3];
    const float* Wk      = (const float*)d_in[4];
    const float* Wv      = (const float*)d_in[5];
    const float* Wvv     = (const float*)d_in[6];
    const float* rw1     = (const float*)d_in[7];
    const float* rb1     = (const float*)d_in[8];
    const float* rw2     = (const float*)d_in[9];
    const float* rb2     = (const float*)d_in[10];
    const float* Wo      = (const float*)d_in[11];
    const float* Wov     = (const float*)d_in[12];
    const float* ff_w1   = (const float*)d_in[13];
    const float* ff_b1   = (const float*)d_in[14];
    const float* ff_w2   = (const float*)d_in[15];
    const float* ff_b2   = (const float*)d_in[16];
    const float* gate_w  = (const float*)d_in[17];
    const float* gate_b  = (const float*)d_in[18];
    const float* ln1_s   = (const float*)d_in[19];
    const float* ln1_b   = (const float*)d_in[20];
    const float* ln2_s   = (const float*)d_in[21];
    const float* ln2_b   = (const float*)d_in[22];
    const float* W_state = (const float*)d_in[23];
    const float* b_state = (const float*)d_in[24];
    const float* W_force = (const float*)d_in[25];
    const float* b_force = (const float*)d_in[26];
    (void)in_sizes; (void)n_in; (void)out_size; (void)ws_size;

    float* out = (float*)d_out;
    float* w = (float*)d_ws;

    float4* pos4  = (float4*)w;                    // -> 65536
    int*    idxv  = (int*)(w + 65536);             // -> 163840
    float*  uv    = w + 163840;                    // -> 458752
    float*  rbfv  = w + 458752;                    // -> 2031616
    u16*    featsb= (u16*)(w + 2031616);           // -> 2555904 (frc/fsum alias later)
    float*  x0    = w + 2555904;                   // -> 4653056
    u16*    hbb   = (u16*)(w + 4653056);           // -> 5701632
    u16*    qkvbb = (u16*)(w + 5701632);           // -> 8847360 used
    float*  gb    = w + 11993088;                  // -> 14090240
    u16*    o0b   = (u16*)(w + 14090240);          // -> 15138816
    u16*    o1b   = (u16*)(w + 15138816);          // -> 18284544
    float*  x1    = w + 18284544;                  // -> 24576000
    u16*    x1b   = (u16*)(w + 24576000);          // -> 27721728
    u16*    t1b   = (u16*)(w + 27721728);          // bf16; also y1b (disjoint live ranges)
    u16*    y1b   = t1b;
    u16*    WqkvT = (u16*)(w + 34013184);
    u16*    Wc2T  = (u16*)(w + 34062336);
    u16*    WvvT  = (u16*)(w + 34111488);
    u16*    WovT  = (u16*)(w + 34127872);
    u16*    WoT   = (u16*)(w + 34144256);
    u16*    fw2T  = (u16*)(w + 34160640);
    u16*    WembT = (u16*)(w + 34193408);
    float*  bias2 = w + 34197504;                  // 2x384 -> 34198272
    float*  rwg   = w + 34198272;                  // 2x128 -> 34198528
    float*  rw1T  = w + 34198528;                  // 2x256 -> 34199040
    float*  rw2vT = w + 34199040;                  // 2x2048 -> 34203136
    float*  frc   = (float*)featsb;
    float*  fsum  = ((float*)featsb) + 49152;

    // one-time prep (both layers) + inputs   [747 blocks: 747*256=191232 >= 191172 items]
    k_prepw<<<dim3(747, 2), 256, 0, stream>>>(Wq, Wk, Wv, gate_w, ff_w1, gate_b, ff_b1,
                                              Wvv, Wov, Wo, ff_w2, rw2, rb2, W_embed, rw1,
                                              WqkvT, Wc2T, WvvT, WovT, WoT, fw2T, WembT,
                                              bias2, rwg, rw1T, rw2vT);
    k_prep<<<(ROWS_ * 64 + 255) / 256, 256, 0, stream>>>(X, pos4, featsb);
    k_knn<<<ROWS_ / 8, 256, 0, stream>>>(pos4, idxv, uv, rbfv);
    // x0 = feats @ W_embed + b_embed ; hbb = LN1(x0)
    k_mgemm<64, 0, true, true><<<dim3(256, 1), 256, 0, stream>>>(
        featsb, WembT, b_embed, nullptr, x0, nullptr, 128, ln1_s, ln1_b, hbb);

    for (int l = 0; l < 2; ++l) {
        const float* rb1_l = rb1 + l * 16;
        const float* rb2_l = rb2 + l * 256;
        const float* fb2_l = ff_b2 + l * 128;

        // qkv = h @ Wqkv (bf16 out)
        k_mgemm<128, 4, false, true><<<dim3(256, 3), 256, 0, stream>>>(
            hbb, WqkvT + l * 49152, nullptr, nullptr, nullptr, qkvbb, 384, nullptr, nullptr, nullptr);
        // y1 = x1 @ Wvv (bf16 out, layer 1 only)
        if (l > 0)
            k_mgemm<128, 4, false, true><<<dim3(768, 1), 256, 0, stream>>>(
                x1b, WvvT + l * 16384, nullptr, nullptr, nullptr, y1b, 128, nullptr, nullptr, nullptr);
        // attention (wave-per-row)
        if (l == 0)
            k_attn<false><<<ROWS_ / 4, 256, 0, stream>>>(qkvbb, idxv, rbfv, uv, nullptr,
                rw1T + l * 256, rb1_l, rw2vT + l * 2048, rwg + l * 128, rb2_l, o0b, o1b);
        else
            k_attn<true><<<ROWS_ / 4, 256, 0, stream>>>(qkvbb, idxv, rbfv, uv, y1b,
                rw1T + l * 256, rb1_l, rw2vT + l * 2048, rwg + l * 128, rb2_l, o0b, o1b);
        // x0 += o0 @ Wo ; hbb = LN2(x0)
        k_mgemm<128, 1, true, true><<<dim3(256, 1), 256, 0, stream>>>(
            o0b, WoT + l * 16384, nullptr, nullptr, x0, nullptr, 128,
            ln2_s + l * 128, ln2_b + l * 128, hbb);
        // [gate fp32 | t1 bf16] = h2 @ [gate_w|ff_w1]
        k_mgemm<128, 2, false, true><<<dim3(256, 3), 256, 0, stream>>>(
            hbb, Wc2T + l * 49152, bias2 + l * 384, nullptr, gb, t1b, 128, nullptr, nullptr, nullptr);
        // x1 = ((l? x1:0) + o1 @ Wov) * gate ; x1b = bf16(x1)
        if (l == 0)
            k_mgemm<128, 3, false, false><<<dim3(768, 1), 256, 0, stream>>>(
                o1b, WovT + l * 16384, nullptr, gb, x1, x1b, 128, nullptr, nullptr, nullptr);
        else
            k_mgemm<128, 3, false, true><<<dim3(768, 1), 256, 0, stream>>>(
                o1b, WovT + l * 16384, nullptr, gb, x1, x1b, 128, nullptr, nullptr, nullptr);
        // x0 += t1 @ ff_w2 + fb2 ; (l==0: hbb = LN1_{l+1}(x0))
        if (l == 0)
            k_mgemm<256, 1, true, true><<<dim3(256, 1), 256, 0, stream>>>(
                t1b, fw2T + l * 32768, fb2_l, nullptr, x0, nullptr, 128,
                ln1_s + 128, ln1_b + 128, hbb);
        else
            k_mgemm<256, 1, false, true><<<dim3(256, 1), 256, 0, stream>>>(
                t1b, fw2T + l * 32768, fb2_l, nullptr, x0, nullptr, 128, nullptr, nullptr, nullptr);
    }

    // state head -> out (row-remapped)
    k_tgemm<128><<<dim3(128, 1), 256, 0, stream>>>(x0, W_state, b_state, out, 64, 64);
    // force head
    k_force1<<<(B_ * NC_ * 3 + 255) / 256, 256, 0, stream>>>(x1, W_force, b_force, frc);
    k_fsum<<<12, 256, 0, stream>>>(frc, fsum);
    k_force2<<<(B_ * NC_ * 3 + 255) / 256, 256, 0, stream>>>(frc, fsum, out + (size_t)B_ * NC_ * DIN_);
}

// Round 16
// 315.546 us; speedup vs baseline: 1.0916x; 1.0251x over previous
//
#include <hip/hip_runtime.h>
#include <cstdint>
#include <cstddef>

namespace {

constexpr int B_ = 4, NC_ = 4095, N_ = 4096, DIN_ = 64, D_ = 128, K_ = 6;
constexpr int XROW_ = 6 + DIN_;   // 70
constexpr int ROWS_ = B_ * N_;    // 16384
constexpr int KNQ = 2;            // queries per wave in knn (occupancy: 8192 waves = 8/SIMD)
constexpr int KCAP = 32;          // hit-list capacity per query

typedef unsigned short u16;
typedef unsigned int u32;
typedef unsigned long long u64;
typedef __attribute__((ext_vector_type(8))) short short8;
typedef __attribute__((ext_vector_type(8))) unsigned short ushort8;
typedef __attribute__((ext_vector_type(4))) float f32x4;

__device__ __forceinline__ float sigm(float x) { return 1.f / (1.f + expf(-x)); }
__device__ __forceinline__ float silu(float x) { return x / (1.f + expf(-x)); }
__device__ __forceinline__ u16 f2bf(float x) {
    u32 u = __float_as_uint(x);
    u += 0x7FFFu + ((u >> 16) & 1u);
    return (u16)(u >> 16);
}
__device__ __forceinline__ float bf2f(u16 x) {
    return __uint_as_float(((u32)x) << 16);
}

// ---------------- prep: pos4 + feats(bf16) ----------------
__global__ void k_prep(const float* __restrict__ X, float4* __restrict__ pos4,
                       u16* __restrict__ featsb)
{
    int g = blockIdx.x * 256 + threadIdx.x;
    if (g >= ROWS_ * 64) return;
    int c = g & 63, row = g >> 6;
    int b = row >> 12, n = row & (N_ - 1);
    const float* xr = X + (size_t)(b * NC_ + n - 1) * XROW_;
    featsb[g] = (n > 0) ? f2bf(xr[6 + c]) : (u16)0;
    if (c == 0) {
        float4 p = {0.f, 0.f, 0.f, 0.f};
        if (n > 0) { p.x = xr[0]; p.y = xr[1]; p.z = xr[2]; }
        pos4[row] = p;
    }
}

// ---------------- knn helpers ----------------
__device__ __forceinline__ u64 shflxor64(u64 v, int mask)
{
    int lo = __shfl_xor((int)(u32)(v & 0xffffffffull), mask, 64);
    int hi = __shfl_xor((int)(u32)(v >> 32), mask, 64);
    return ((u64)(u32)hi << 32) | (u32)lo;
}

__device__ __forceinline__ float kth6min(float v)
{
    const float BIG = 3.4e38f;
    float kth = BIG;
    #pragma unroll
    for (int r = 0; r < 6; ++r) {
        float m = v;
        #pragma unroll
        for (int off = 1; off < 64; off <<= 1) m = fminf(m, __shfl_xor(m, off, 64));
        kth = m;
        if (v == m) v = BIG;   // dedup only raises bound (safe)
    }
    return kth;
}

__device__ __forceinline__ void geom_write(const float4* __restrict__ pb, int q, int j,
                                           size_t e, float* __restrict__ uv,
                                           float* __restrict__ rbfv)
{
    float4 pj = pb[j], pn = pb[q];
    float rx = pj.x - pn.x, ry = pj.y - pn.y, rz = pj.z - pn.z;
    float dist = sqrtf(rx * rx + ry * ry + rz * rz + 1e-8f);
    float inv = 1.f / dist;
    uv[e * 3 + 0] = rx * inv; uv[e * 3 + 1] = ry * inv; uv[e * 3 + 2] = rz * inv;
    #pragma unroll
    for (int r = 0; r < 16; ++r) {
        float t = (dist - (4.0f / 15.0f) * r) * 4.0f;
        rbfv[e * 16 + r] = expf(-t * t);
    }
}

// ---------------- KNN: 2 q/wave (8/SIMD occupancy), full exact two-phase ----------------
__global__ __launch_bounds__(256) void k_knn(const float4* __restrict__ pos4,
                                             int* __restrict__ idxv,
                                             float* __restrict__ uv,
                                             float* __restrict__ rbfv)
{
    __shared__ u64 sHits[4][KNQ][KCAP];
    __shared__ int sCnt[4][KNQ];
    const int w = threadIdx.x >> 6, lane = threadIdx.x & 63;
    const int wave = (blockIdx.x << 2) | w;
    const int b = wave >> 11;
    const int i0 = (wave & 2047) << 1;
    const float4* pb = pos4 + (size_t)b * N_;
    const float BIG = 3.4e38f;

    if (lane < KNQ) sCnt[w][lane] = 0;
    __syncthreads();

    float4 qv[KNQ];
    #pragma unroll
    for (int qq = 0; qq < KNQ; ++qq) qv[qq] = pb[i0 + qq];

    // phase 1: per-lane min d2 per query (full scan -> tight T)
    float dmin[KNQ];
    #pragma unroll
    for (int qq = 0; qq < KNQ; ++qq) dmin[qq] = BIG;
    #pragma unroll 4
    for (int it = 0; it < 64; ++it) {
        int j = lane + (it << 6);
        float4 p = pb[j];
        #pragma unroll
        for (int qq = 0; qq < KNQ; ++qq) {
            float dx = p.x - qv[qq].x, dy = p.y - qv[qq].y, dz = p.z - qv[qq].z;
            float dd = dx * dx + dy * dy + dz * dz;
            if (j != i0 + qq) dmin[qq] = fminf(dmin[qq], dd);
        }
    }
    float T[KNQ];
    #pragma unroll
    for (int qq = 0; qq < KNQ; ++qq) T[qq] = kth6min(dmin[qq]) * 1.000002f;

    // phase 2: compact hits (dd <= T) into LDS
    #pragma unroll 4
    for (int it = 0; it < 64; ++it) {
        int j = lane + (it << 6);
        float4 p = pb[j];
        #pragma unroll
        for (int qq = 0; qq < KNQ; ++qq) {
            float dx = p.x - qv[qq].x, dy = p.y - qv[qq].y, dz = p.z - qv[qq].z;
            float dd = dx * dx + dy * dy + dz * dz;
            if (dd <= T[qq] && j != i0 + qq) {
                int slot = atomicAdd(&sCnt[w][qq], 1);
                if (slot < KCAP)
                    sHits[w][qq][slot] = ((u64)__float_as_uint(dd) << 32) | (u32)j;
            }
        }
    }
    __syncthreads();

    // extraction: 32-lane group g handles query g; exact 6x min over hit list
    const int g = lane >> 5, li = lane & 31;
    const int cnt = sCnt[w][g];
    const int q = i0 + g;
    u64 ent = (li < (cnt < KCAP ? cnt : KCAP)) ? sHits[w][g][li] : ~0ull;
    int myj = -1;
    #pragma unroll
    for (int k = 0; k < 6; ++k) {
        u64 m = ent;
        #pragma unroll
        for (int off = 1; off < 32; off <<= 1) {     // offsets 1..16 stay within 32-half
            u64 o = shflxor64(m, off);
            if (o < m) m = o;
        }
        if (li == k) myj = (int)(u32)(m & 0xffffffffull);
        if (ent == m) ent = ~0ull;
    }
    if (cnt <= KCAP && li < 6) {
        size_t e = (size_t)(b * N_ + q) * 6 + li;
        idxv[e] = myj;
        geom_write(pb, q, myj, e, uv, rbfv);
    }

    // fallback for overflowed queries (exact per-lane insert; essentially never taken)
    u64 ovf = __ballot(li == 0 && cnt > KCAP);
    while (ovf) {
        int gl = __ffsll(ovf) - 1; ovf &= ovf - 1;
        int qq = gl >> 5;
        int qx = i0 + qq;
        float4 qp = pb[qx];
        float Tq = T[0];
        #pragma unroll
        for (int z = 1; z < KNQ; ++z) if (z == qq) Tq = T[z];
        float e0 = BIG, e1 = BIG, e2 = BIG, e3 = BIG, e4 = BIG, e5 = BIG;
        int j0 = 0, j1 = 0, j2 = 0, j3 = 0, j4 = 0, j5 = 0;
        for (int it = 0; it < 64; ++it) {
            int j = lane + (it << 6);
            float4 p = pb[j];
            float dx = p.x - qp.x, dy = p.y - qp.y, dz = p.z - qp.z;
            float dd = dx * dx + dy * dy + dz * dz;
            if (dd <= Tq && j != qx && dd < e5) {
                e5 = dd; j5 = j;
                float td; int tj;
                if (e5 < e4) { td = e4; e4 = e5; e5 = td; tj = j4; j4 = j5; j5 = tj; }
                if (e4 < e3) { td = e3; e3 = e4; e4 = td; tj = j3; j3 = j4; j4 = tj; }
                if (e3 < e2) { td = e2; e2 = e3; e3 = td; tj = j2; j2 = j3; j3 = tj; }
                if (e2 < e1) { td = e1; e1 = e2; e2 = td; tj = j1; j1 = j2; j2 = tj; }
                if (e1 < e0) { td = e0; e0 = e1; e1 = td; tj = j0; j0 = j1; j1 = tj; }
            }
        }
        u64 a0 = ((u64)__float_as_uint(e0) << 32) | (u32)j0;
        u64 a1 = ((u64)__float_as_uint(e1) << 32) | (u32)j1;
        u64 a2 = ((u64)__float_as_uint(e2) << 32) | (u32)j2;
        u64 a3 = ((u64)__float_as_uint(e3) << 32) | (u32)j3;
        u64 a4 = ((u64)__float_as_uint(e4) << 32) | (u32)j4;
        u64 a5 = ((u64)__float_as_uint(e5) << 32) | (u32)j5;
        int fj = -1;
        #pragma unroll
        for (int k = 0; k < 6; ++k) {
            u64 m = a0;
            #pragma unroll
            for (int off = 1; off < 64; off <<= 1) {
                u64 o = shflxor64(m, off);
                if (o < m) m = o;
            }
            if (a0 == m) { a0 = a1; a1 = a2; a2 = a3; a3 = a4; a4 = a5; a5 = ~0ull; }
            if (lane == k) fj = (int)(u32)(m & 0xffffffffull);
        }
        if (lane < 6) {
            size_t e = (size_t)(b * N_ + qx) * 6 + lane;
            idxv[e] = fj;
            geom_write(pb, qx, fj, e, uv, rbfv);
        }
    }
}

// ---------------- one-time weight prep (both layers) ----------------
// total flattened items: 49152+49152+16384*3+32768+384+64+4+256+2048+8192 = 191172
__global__ void k_prepw(const float* __restrict__ Wq, const float* __restrict__ Wk,
                        const float* __restrict__ Wv, const float* __restrict__ gw,
                        const float* __restrict__ fw1, const float* __restrict__ gb_,
                        const float* __restrict__ fb1, const float* __restrict__ Wvv,
                        const float* __restrict__ Wov, const float* __restrict__ Wo_,
                        const float* __restrict__ fw2, const float* __restrict__ rw2,
                        const float* __restrict__ rb2, const float* __restrict__ W_embed,
                        const float* __restrict__ rw1,
                        u16* __restrict__ WqkvT, u16* __restrict__ Wc2T,
                        u16* __restrict__ WvvT, u16* __restrict__ WovT,
                        u16* __restrict__ WoT, u16* __restrict__ fw2T,
                        u16* __restrict__ WembT,
                        float* __restrict__ bias2, float* __restrict__ rwg,
                        float* __restrict__ rw1T, float* __restrict__ rw2vT)
{
    const int l = blockIdx.y;
    int g = blockIdx.x * 256 + threadIdx.x;
    const float* Wq_l = Wq + l * 16384;  const float* Wk_l = Wk + l * 16384;
    const float* Wv_l = Wv + l * 16384;  const float* gw_l = gw + l * 16384;
    const float* fw1_l = fw1 + l * 32768; const float* gb_l = gb_ + l * 128;
    const float* fb1_l = fb1 + l * 256;  const float* Wvv_l = Wvv + l * 16384;
    const float* Wov_l = Wov + l * 16384; const float* Wo_ll = Wo_ + l * 16384;
    const float* fw2_l = fw2 + l * 32768; const float* rw2_l = rw2 + l * 4096;
    const float* rb2_l = rb2 + l * 256;  const float* rw1_l = rw1 + l * 256;

    if (g < 49152) {
        int n = g >> 7, k = g & 127;
        const float* src = (n < 128) ? Wq_l : ((n < 256) ? Wk_l : Wv_l);
        WqkvT[l * 49152 + g] = f2bf(src[k * 128 + (n & 127)]); return;
    }
    g -= 49152;
    if (g < 49152) {
        int n = g >> 7, k = g & 127;
        Wc2T[l * 49152 + g] = f2bf((n < 128) ? gw_l[k * 128 + n] : fw1_l[k * 256 + (n - 128)]); return;
    }
    g -= 49152;
    if (g < 16384) { int n = g >> 7, k = g & 127; WvvT[l * 16384 + g] = f2bf(Wvv_l[k * 128 + n]); return; }
    g -= 16384;
    if (g < 16384) { int n = g >> 7, k = g & 127; WovT[l * 16384 + g] = f2bf(Wov_l[k * 128 + n]); return; }
    g -= 16384;
    if (g < 16384) { int n = g >> 7, k = g & 127; WoT[l * 16384 + g] = f2bf(Wo_ll[k * 128 + n]); return; }
    g -= 16384;
    if (g < 32768) { int n = g >> 8, k = g & 255; fw2T[l * 32768 + g] = f2bf(fw2_l[k * 128 + n]); return; }
    g -= 32768;
    if (g < 384) { bias2[l * 384 + g] = (g < 128) ? gb_l[g] : fb1_l[g - 128]; return; }
    g -= 384;
    if (g < 64) {
        int hh = g >> 2, h = g & 3;
        float a = 0.f;
        #pragma unroll
        for (int dh = 0; dh < 32; ++dh) a += rw2_l[hh * 256 + h * 32 + dh];
        rwg[l * 128 + g] = a * (1.f / 32.f); return;
    }
    g -= 64;
    if (g < 4) {
        float a = 0.f;
        #pragma unroll
        for (int dh = 0; dh < 32; ++dh) a += rb2_l[g * 32 + dh];
        rwg[l * 128 + 64 + g] = a * (1.f / 32.f); return;
    }
    g -= 4;
    if (g < 256) {          // rw1T[l][hh][rr] = rw1[rr][hh]  (fp32)
        int hh = g >> 4, rr = g & 15;
        rw1T[l * 256 + hh * 16 + rr] = rw1_l[rr * 16 + hh]; return;
    }
    g -= 256;
    if (g < 2048) {         // rw2vT[l][t][hh] = rw2[hh][128+t]  (fp32)
        int t = g >> 4, hh = g & 15;
        rw2vT[l * 2048 + t * 16 + hh] = rw2_l[hh * 256 + 128 + t]; return;
    }
    g -= 2048;
    if (g < 8192 && l == 0) {
        int n = g >> 6, k = g & 63;
        WembT[g] = f2bf(W_embed[k * 128 + n]);
    }
}

// ---------------- MFMA bf16 GEMM: BMx128 tile (BM=32 or 64), 4 waves x (BMx32) ----------------
template<int KD, int BM, int EPI, bool LN, bool X1ACC>
__global__ __launch_bounds__(256) void k_mgemm(
    const u16* __restrict__ A, const u16* __restrict__ WT,
    const float* __restrict__ bias, const float* __restrict__ aux,
    float* __restrict__ C, u16* __restrict__ Cb, int ldc,
    const float* __restrict__ lns, const float* __restrict__ lnb,
    u16* __restrict__ lnout)
{
    constexpr int MI = BM / 16;
    __shared__ u16 sA[BM * 40];
    __shared__ u16 sB[128 * 40];
    const int tid = threadIdx.x;
    const int lane = tid & 63, wn = tid >> 6;
    const int m0 = blockIdx.x * BM, n0 = blockIdx.y * 128;
    f32x4 acc[MI][2] = {};

    for (int k0 = 0; k0 < KD; k0 += 32) {
        __syncthreads();
        if (BM == 64) {
            int row = tid >> 2, gk = tid & 3;
            *(uint4*)&sA[row * 40 + gk * 8] =
                *(const uint4*)&A[(size_t)(m0 + row) * KD + k0 + gk * 8];
        } else {
            if (tid < BM * 4) {
                int row = tid >> 2, gk = tid & 3;
                *(uint4*)&sA[row * 40 + gk * 8] =
                    *(const uint4*)&A[(size_t)(m0 + row) * KD + k0 + gk * 8];
            }
        }
        #pragma unroll
        for (int cc = 0; cc < 2; ++cc) {
            int c = tid * 2 + cc;
            int row = c >> 2, gk = c & 3;
            *(uint4*)&sB[row * 40 + gk * 8] =
                *(const uint4*)&WT[(size_t)(n0 + row) * KD + k0 + gk * 8];
        }
        __syncthreads();
        const int gk = lane >> 4, lr = lane & 15;
        short8 af[MI], bfr[2];
        #pragma unroll
        for (int i = 0; i < MI; ++i)
            af[i] = *(const short8*)&sA[(i * 16 + lr) * 40 + gk * 8];
        #pragma unroll
        for (int i = 0; i < 2; ++i)
            bfr[i] = *(const short8*)&sB[(wn * 32 + i * 16 + lr) * 40 + gk * 8];
        #pragma unroll
        for (int mi = 0; mi < MI; ++mi)
            #pragma unroll
            for (int ni = 0; ni < 2; ++ni)
                acc[mi][ni] = __builtin_amdgcn_mfma_f32_16x16x32_bf16(af[mi], bfr[ni], acc[mi][ni], 0, 0, 0);
    }

    const int lg = lane >> 4;         // 0..3 row-group
    const int lc = lane & 15;         // col within 16
    if (LN) {
        __shared__ float sLN[BM][4][2];
        float s1[MI][4], s2[MI][4];
        #pragma unroll
        for (int mi = 0; mi < MI; ++mi) {
            int rbase = m0 + mi * 16 + lg * 4;
            #pragma unroll
            for (int ee = 0; ee < 4; ++ee) { s1[mi][ee] = 0.f; s2[mi][ee] = 0.f; }
            #pragma unroll
            for (int ni = 0; ni < 2; ++ni) {
                int col = wn * 32 + ni * 16 + lc;
                float bc = bias ? bias[col] : 0.f;
                #pragma unroll
                for (int ee = 0; ee < 4; ++ee) {
                    float v = acc[mi][ni][ee] + bc;
                    if (EPI == 1) v += C[(size_t)(rbase + ee) * 128 + col];
                    acc[mi][ni][ee] = v;
                    s1[mi][ee] += v;
                    s2[mi][ee] += v * v;
                }
            }
        }
        #pragma unroll
        for (int mi = 0; mi < MI; ++mi)
            #pragma unroll
            for (int ee = 0; ee < 4; ++ee)
                #pragma unroll
                for (int off = 1; off < 16; off <<= 1) {
                    s1[mi][ee] += __shfl_xor(s1[mi][ee], off, 64);
                    s2[mi][ee] += __shfl_xor(s2[mi][ee], off, 64);
                }
        if (lc == 0) {
            #pragma unroll
            for (int mi = 0; mi < MI; ++mi)
                #pragma unroll
                for (int ee = 0; ee < 4; ++ee) {
                    int r = mi * 16 + lg * 4 + ee;
                    sLN[r][wn][0] = s1[mi][ee];
                    sLN[r][wn][1] = s2[mi][ee];
                }
        }
        __syncthreads();
        #pragma unroll
        for (int mi = 0; mi < MI; ++mi) {
            int rbase = m0 + mi * 16 + lg * 4;
            #pragma unroll
            for (int ee = 0; ee < 4; ++ee) {
                int r = mi * 16 + lg * 4 + ee;
                float sum = sLN[r][0][0] + sLN[r][1][0] + sLN[r][2][0] + sLN[r][3][0];
                float sq  = sLN[r][0][1] + sLN[r][1][1] + sLN[r][2][1] + sLN[r][3][1];
                float mean = sum * (1.f / 128.f);
                float var = sq * (1.f / 128.f) - mean * mean;
                float inv = 1.f / sqrtf(var + 1e-5f);
                #pragma unroll
                for (int ni = 0; ni < 2; ++ni) {
                    int col = wn * 32 + ni * 16 + lc;
                    float v = acc[mi][ni][ee];
                    size_t o = (size_t)(rbase + ee) * 128 + col;
                    C[o] = v;
                    lnout[o] = f2bf((v - mean) * inv * lns[col] + lnb[col]);
                }
            }
        }
        return;
    }

    #pragma unroll
    for (int mi = 0; mi < MI; ++mi) {
        int rbase = m0 + mi * 16 + lg * 4;
        #pragma unroll
        for (int ni = 0; ni < 2; ++ni) {
            int col = n0 + wn * 32 + ni * 16 + lc;
            if (EPI == 0) {
                float bc = bias ? bias[col] : 0.f;
                #pragma unroll
                for (int ee = 0; ee < 4; ++ee)
                    C[(size_t)(rbase + ee) * ldc + col] = acc[mi][ni][ee] + bc;
            } else if (EPI == 1) {
                float bc = bias ? bias[col] : 0.f;
                #pragma unroll
                for (int ee = 0; ee < 4; ++ee) {
                    size_t o = (size_t)(rbase + ee) * ldc + col;
                    C[o] += acc[mi][ni][ee] + bc;
                }
            } else if (EPI == 2) {
                float bc = bias[col];
                if (n0 == 0) {
                    #pragma unroll
                    for (int ee = 0; ee < 4; ++ee)
                        C[(size_t)(rbase + ee) * 128 + col] = sigm(acc[mi][ni][ee] + bc);
                } else {
                    int c2 = col - 128;
                    #pragma unroll
                    for (int ee = 0; ee < 4; ++ee)
                        Cb[(size_t)(rbase + ee) * 256 + c2] = f2bf(silu(acc[mi][ni][ee] + bc));
                }
            } else if (EPI == 4) {
                float bc = bias ? bias[col] : 0.f;
                #pragma unroll
                for (int ee = 0; ee < 4; ++ee)
                    Cb[(size_t)(rbase + ee) * ldc + col] = f2bf(acc[mi][ni][ee] + bc);
            } else {
                #pragma unroll
                for (int ee = 0; ee < 4; ++ee) {
                    int m = rbase + ee;
                    size_t o = (size_t)m * 128 + col;
                    float v = acc[mi][ni][ee];
                    if (X1ACC) v += C[o];
                    v *= aux[(size_t)(m / 3) * 128 + col];
                    C[o] = v;
                    Cb[o] = f2bf(v);
                }
            }
        }
    }
}

// ---------------- fp32 tiled GEMM (state head only) ----------------
template<int KD>
__global__ __launch_bounds__(256) void k_tgemm(
    const float* __restrict__ A, const float* __restrict__ W, const float* __restrict__ bias,
    float* __restrict__ C, int ldw, int ldc)
{
    __shared__ __align__(16) float As[32 * 132];
    __shared__ __align__(16) float Ws[32 * 68];
    const int tid = threadIdx.x;
    const int tx = tid & 15, ty = tid >> 4;
    const int m0 = blockIdx.x * 128, n0 = blockIdx.y * 64;
    float acc[8][4] = {};
    for (int k0 = 0; k0 < KD; k0 += 32) {
        __syncthreads();
        #pragma unroll
        for (int r = 0; r < 4; ++r) {
            int id = tid + r * 256;
            int row = id >> 3, kq = id & 7;
            float4 a4 = *(const float4*)&A[(size_t)(m0 + row) * KD + k0 + kq * 4];
            As[(kq * 4 + 0) * 132 + row] = a4.x;
            As[(kq * 4 + 1) * 132 + row] = a4.y;
            As[(kq * 4 + 2) * 132 + row] = a4.z;
            As[(kq * 4 + 3) * 132 + row] = a4.w;
        }
        #pragma unroll
        for (int r = 0; r < 2; ++r) {
            int id = tid + r * 256;
            int kr = id >> 4, cq = id & 15;
            *(float4*)&Ws[kr * 68 + cq * 4] =
                *(const float4*)&W[(size_t)(k0 + kr) * ldw + n0 + cq * 4];
        }
        __syncthreads();
        #pragma unroll 8
        for (int k = 0; k < 32; ++k) {
            float4 aA = *(const float4*)&As[k * 132 + ty * 8];
            float4 aB = *(const float4*)&As[k * 132 + ty * 8 + 4];
            float4 w4 = *(const float4*)&Ws[k * 68 + tx * 4];
            float av[8] = {aA.x, aA.y, aA.z, aA.w, aB.x, aB.y, aB.z, aB.w};
            float wv[4] = {w4.x, w4.y, w4.z, w4.w};
            #pragma unroll
            for (int r = 0; r < 8; ++r)
                #pragma unroll
                for (int j = 0; j < 4; ++j)
                    acc[r][j] += av[r] * wv[j];
        }
    }
    float bv[4];
    #pragma unroll
    for (int j = 0; j < 4; ++j) bv[j] = bias[n0 + tx * 4 + j];
    #pragma unroll
    for (int r = 0; r < 8; ++r) {
        int m = m0 + ty * 8 + r;
        int n = m & (N_ - 1), bb2 = m >> 12;
        if (n == 0) continue;
        float* dst = C + ((size_t)(bb2 * NC_ + n - 1)) * ldc + n0 + tx * 4;
        float4 res = {acc[r][0] + bv[0], acc[r][1] + bv[1], acc[r][2] + bv[2], acc[r][3] + bv[3]};
        *(float4*)dst = res;
    }
}

// ---------------- fused attention v3: wave-per-row, barrier-free ----------------
template<bool HASY1>
__global__ __launch_bounds__(256) void k_attn(
    const u16* __restrict__ qkvb, const int* __restrict__ idxv,
    const float* __restrict__ rbfv, const float* __restrict__ uv,
    const u16* __restrict__ y1b,
    const float* __restrict__ rw1T, const float* __restrict__ rb1,
    const float* __restrict__ rw2vT, const float* __restrict__ rwg,
    const float* __restrict__ rb2,
    u16* __restrict__ o0b, u16* __restrict__ o1b)
{
    const int wid = threadIdx.x >> 6, lane = threadIdx.x & 63;
    const int row = blockIdx.x * 4 + wid;
    const int b = row >> 12;
    const int ch0 = lane * 2;
    const int h = lane >> 4;

    __shared__ float sHid[4][6][16];
    __shared__ float sU[4][6][3];

    int jl = 0;
    if (lane < 6) jl = idxv[row * 6 + lane];
    int jj[6];
    #pragma unroll
    for (int k = 0; k < 6; ++k) jj[k] = __shfl(jl, k, 64);

    if (lane < 18) sU[wid][lane / 3][lane % 3] = uv[(size_t)row * 18 + lane];

    {
        int idx = lane;
        #pragma unroll
        for (int rep = 0; rep < 2; ++rep) {
            if (idx < 96) {
                int k = idx >> 4, hh = idx & 15;
                float a = rb1[hh];
                const float* rb = rbfv + (size_t)(row * 6 + k) * 16;
                const float* wr = rw1T + hh * 16;
                #pragma unroll
                for (int rr = 0; rr < 16; ++rr) a += rb[rr] * wr[rr];
                sHid[wid][k][hh] = silu(a);
            }
            idx += 64;
        }
    }
    __builtin_amdgcn_wave_barrier();
    __threadfence_block();
    __builtin_amdgcn_wave_barrier();

    u32 qp = *(const u32*)&qkvb[(size_t)row * 384 + ch0];
    float q0 = bf2f((u16)qp), q1 = bf2f((u16)(qp >> 16));

    float part[6];
    #pragma unroll
    for (int k = 0; k < 6; ++k) {
        u32 kp = *(const u32*)&qkvb[(size_t)(b * N_ + jj[k]) * 384 + 128 + ch0];
        part[k] = q0 * bf2f((u16)kp) + q1 * bf2f((u16)(kp >> 16));
    }
    #pragma unroll
    for (int off = 1; off < 16; off <<= 1)
        #pragma unroll
        for (int k = 0; k < 6; ++k)
            part[k] += __shfl_xor(part[k], off, 64);

    float lg[6];
    #pragma unroll
    for (int k = 0; k < 6; ++k) {
        float bias = rwg[64 + h];
        #pragma unroll
        for (int hh = 0; hh < 16; ++hh) bias += sHid[wid][k][hh] * rwg[hh * 4 + h];
        lg[k] = part[k] * 0.17677669529663687f + bias;
    }

    float mx = lg[0];
    #pragma unroll
    for (int k = 1; k < 6; ++k) mx = fmaxf(mx, lg[k]);
    float a[6], smv = 0.f;
    #pragma unroll
    for (int k = 0; k < 6; ++k) { a[k] = expf(lg[k] - mx); smv += a[k]; }
    float inv = 1.f / smv;
    #pragma unroll
    for (int k = 0; k < 6; ++k) a[k] *= inv;

    float rwc0[16], rwc1[16];
    {
        const float4* wp = (const float4*)(rw2vT + ch0 * 16);
        #pragma unroll
        for (int i = 0; i < 4; ++i) {
            float4 v0 = wp[i], v1 = wp[i + 4];
            rwc0[i * 4 + 0] = v0.x; rwc0[i * 4 + 1] = v0.y; rwc0[i * 4 + 2] = v0.z; rwc0[i * 4 + 3] = v0.w;
            rwc1[i * 4 + 0] = v1.x; rwc1[i * 4 + 1] = v1.y; rwc1[i * 4 + 2] = v1.z; rwc1[i * 4 + 3] = v1.w;
        }
    }
    float rb20 = rb2[128 + ch0], rb21 = rb2[128 + ch0 + 1];
    float rvk0[6], rvk1[6];
    #pragma unroll
    for (int k = 0; k < 6; ++k) {
        float a0 = rb20, a1 = rb21;
        #pragma unroll
        for (int hh = 0; hh < 16; ++hh) {
            float hv = sHid[wid][k][hh];
            a0 += hv * rwc0[hh];
            a1 += hv * rwc1[hh];
        }
        rvk0[k] = a0; rvk1[k] = a1;
    }

    float o00 = 0.f, o01 = 0.f;
    #pragma unroll
    for (int k = 0; k < 6; ++k) {
        u32 vp = *(const u32*)&qkvb[(size_t)(b * N_ + jj[k]) * 384 + 256 + ch0];
        o00 += a[k] * bf2f((u16)vp) * silu(rvk0[k]);
        o01 += a[k] * bf2f((u16)(vp >> 16)) * silu(rvk1[k]);
    }
    *(u32*)&o0b[(size_t)row * 128 + ch0] = (u32)f2bf(o00) | ((u32)f2bf(o01) << 16);

    #pragma unroll
    for (int c = 0; c < 3; ++c) {
        float s0 = 0.f, s1 = 0.f;
        #pragma unroll
        for (int k = 0; k < 6; ++k) {
            float b0 = 0.f, b1 = 0.f;
            if (HASY1) {
                u32 yp = *(const u32*)&y1b[((size_t)(b * N_ + jj[k]) * 3 + c) * 128 + ch0];
                b0 = bf2f((u16)yp); b1 = bf2f((u16)(yp >> 16));
            }
            float uk = sU[wid][k][c];
            s0 += a[k] * (b0 + rvk0[k] * uk);
            s1 += a[k] * (b1 + rvk1[k] * uk);
        }
        *(u32*)&o1b[((size_t)row * 3 + c) * 128 + ch0] = (u32)f2bf(s0) | ((u32)f2bf(s1) << 16);
    }
}

// ---------------- force head ----------------
__global__ void k_force1(const float* __restrict__ x1, const float* __restrict__ W,
                         const float* __restrict__ bias, float* __restrict__ frc)
{
    int g = blockIdx.x * 256 + threadIdx.x;
    if (g >= B_ * NC_ * 3) return;
    int c = g % 3, rr = g / 3;
    int b = rr / NC_, n = rr - b * NC_;
    const float* xr = x1 + (size_t)(b * N_ + n + 1) * 384 + c * 128;
    float a = bias[0];
    for (int d = 0; d < 128; ++d) a += xr[d] * W[d];
    frc[g] = a;
}

__global__ __launch_bounds__(256) void k_fsum(const float* __restrict__ frc, float* __restrict__ fsum)
{
    int b = blockIdx.x / 3, c = blockIdx.x % 3;
    __shared__ float red[256];
    float a = 0.f;
    for (int n = threadIdx.x; n < NC_; n += 256) a += frc[(b * NC_ + n) * 3 + c];
    red[threadIdx.x] = a; __syncthreads();
    for (int st = 128; st > 0; st >>= 1) { if (threadIdx.x < st) red[threadIdx.x] += red[threadIdx.x + st]; __syncthreads(); }
    if (threadIdx.x == 0) fsum[blockIdx.x] = red[0] / (float)NC_;
}

__global__ void k_force2(const float* __restrict__ frc, const float* __restrict__ fsum,
                         float* __restrict__ out)
{
    int g = blockIdx.x * 256 + threadIdx.x;
    if (g >= B_ * NC_ * 3) return;
    int c = g % 3;
    int b = g / (NC_ * 3);
    out[g] = frc[g] - fsum[b * 3 + c];
}

} // namespace

extern "C" void kernel_launch(void* const* d_in, const int* in_sizes, int n_in,
                              void* d_out, int out_size, void* d_ws, size_t ws_size,
                              hipStream_t stream)
{
    const float* X       = (const float*)d_in[0];
    const float* W_embed = (const float*)d_in[1];
    const float* b_embed = (const float*)d_in[2];
    const float* Wq      = (const float*)d_in[3];
    const float* Wk      = (const float*)d_in[4];
    const float* Wv      = (const float*)d_in[5];
    const float* Wvv     = (const float*)d_in[6];
    const float* rw1     = (const float*)d_in[7];
    const float* rb1     = (const float*)d_in[8];
    const float* rw2     = (const float*)d_in[9];
    const float* rb2     = (const float*)d_in[10];
    const float* Wo      = (const float*)d_in[11];
    const float* Wov     = (const float*)d_in[12];
    const float* ff_w1   = (const float*)d_in[13];
    const float* ff_b1   = (const float*)d_in[14];
    const float* ff_w2   = (const float*)d_in[15];
    const float* ff_b2   = (const float*)d_in[16];
    const float* gate_w  = (const float*)d_in[17];
    const float* gate_b  = (const float*)d_in[18];
    const float* ln1_s   = (const float*)d_in[19];
    const float* ln1_b   = (const float*)d_in[20];
    const float* ln2_s   = (const float*)d_in[21];
    const float* ln2_b   = (const float*)d_in[22];
    const float* W_state = (const float*)d_in[23];
    const float* b_state = (const float*)d_in[24];
    const float* W_force = (const float*)d_in[25];
    const float* b_force = (const float*)d_in[26];
    (void)in_sizes; (void)n_in; (void)out_size; (void)ws_size;

    float* out = (float*)d_out;
    float* w = (float*)d_ws;

    float4* pos4  = (float4*)w;                    // -> 65536
    int*    idxv  = (int*)(w + 65536);             // -> 163840
    float*  uv    = w + 163840;                    // -> 458752
    float*  rbfv  = w + 458752;                    // -> 2031616
    u16*    featsb= (u16*)(w + 2031616);           // -> 2555904 (frc/fsum alias later)
    float*  x0    = w + 2555904;                   // -> 4653056
    u16*    hbb   = (u16*)(w + 4653056);           // -> 5701632
    u16*    qkvbb = (u16*)(w + 5701632);           // -> 8847360 used
    float*  gb    = w + 11993088;                  // -> 14090240
    u16*    o0b   = (u16*)(w + 14090240);          // -> 15138816
    u16*    o1b   = (u16*)(w + 15138816);          // -> 18284544
    float*  x1    = w + 18284544;                  // -> 24576000
    u16*    x1b   = (u16*)(w + 24576000);          // -> 27721728
    u16*    t1b   = (u16*)(w + 27721728);          // bf16; also y1b (disjoint live ranges)
    u16*    y1b   = t1b;
    u16*    WqkvT = (u16*)(w + 34013184);
    u16*    Wc2T  = (u16*)(w + 34062336);
    u16*    WvvT  = (u16*)(w + 34111488);
    u16*    WovT  = (u16*)(w + 34127872);
    u16*    WoT   = (u16*)(w + 34144256);
    u16*    fw2T  = (u16*)(w + 34160640);
    u16*    WembT = (u16*)(w + 34193408);
    float*  bias2 = w + 34197504;                  // 2x384 -> 34198272
    float*  rwg   = w + 34198272;                  // 2x128 -> 34198528
    float*  rw1T  = w + 34198528;                  // 2x256 -> 34199040
    float*  rw2vT = w + 34199040;                  // 2x2048 -> 34203136
    float*  frc   = (float*)featsb;
    float*  fsum  = ((float*)featsb) + 49152;

    // one-time prep (both layers) + inputs   [747 blocks: 747*256=191232 >= 191172 items]
    k_prepw<<<dim3(747, 2), 256, 0, stream>>>(Wq, Wk, Wv, gate_w, ff_w1, gate_b, ff_b1,
                                              Wvv, Wov, Wo, ff_w2, rw2, rb2, W_embed, rw1,
                                              WqkvT, Wc2T, WvvT, WovT, WoT, fw2T, WembT,
                                              bias2, rwg, rw1T, rw2vT);
    k_prep<<<(ROWS_ * 64 + 255) / 256, 256, 0, stream>>>(X, pos4, featsb);
    k_knn<<<ROWS_ / 8, 256, 0, stream>>>(pos4, idxv, uv, rbfv);
    // x0 = feats @ W_embed + b_embed ; hbb = LN1(x0)   [BM=32 -> 512 blocks]
    k_mgemm<64, 32, 0, true, true><<<dim3(512, 1), 256, 0, stream>>>(
        featsb, WembT, b_embed, nullptr, x0, nullptr, 128, ln1_s, ln1_b, hbb);

    for (int l = 0; l < 2; ++l) {
        const float* rb1_l = rb1 + l * 16;
        const float* rb2_l = rb2 + l * 256;
        const float* fb2_l = ff_b2 + l * 128;

        // qkv = h @ Wqkv (bf16 out)
        k_mgemm<128, 64, 4, false, true><<<dim3(256, 3), 256, 0, stream>>>(
            hbb, WqkvT + l * 49152, nullptr, nullptr, nullptr, qkvbb, 384, nullptr, nullptr, nullptr);
        // y1 = x1 @ Wvv (bf16 out, layer 1 only)
        if (l > 0)
            k_mgemm<128, 64, 4, false, true><<<dim3(768, 1), 256, 0, stream>>>(
                x1b, WvvT + l * 16384, nullptr, nullptr, nullptr, y1b, 128, nullptr, nullptr, nullptr);
        // attention (wave-per-row)
        if (l == 0)
            k_attn<false><<<ROWS_ / 4, 256, 0, stream>>>(qkvbb, idxv, rbfv, uv, nullptr,
                rw1T + l * 256, rb1_l, rw2vT + l * 2048, rwg + l * 128, rb2_l, o0b, o1b);
        else
            k_attn<true><<<ROWS_ / 4, 256, 0, stream>>>(qkvbb, idxv, rbfv, uv, y1b,
                rw1T + l * 256, rb1_l, rw2vT + l * 2048, rwg + l * 128, rb2_l, o0b, o1b);
        // x0 += o0 @ Wo ; hbb = LN2(x0)   [BM=32 -> 512 blocks]
        k_mgemm<128, 32, 1, true, true><<<dim3(512, 1), 256, 0, stream>>>(
            o0b, WoT + l * 16384, nullptr, nullptr, x0, nullptr, 128,
            ln2_s + l * 128, ln2_b + l * 128, hbb);
        // [gate fp32 | t1 bf16] = h2 @ [gate_w|ff_w1]
        k_mgemm<128, 64, 2, false, true><<<dim3(256, 3), 256, 0, stream>>>(
            hbb, Wc2T + l * 49152, bias2 + l * 384, nullptr, gb, t1b, 128, nullptr, nullptr, nullptr);
        // x1 = ((l? x1:0) + o1 @ Wov) * gate ; x1b = bf16(x1)
        if (l == 0)
            k_mgemm<128, 64, 3, false, false><<<dim3(768, 1), 256, 0, stream>>>(
                o1b, WovT + l * 16384, nullptr, gb, x1, x1b, 128, nullptr, nullptr, nullptr);
        else
            k_mgemm<128, 64, 3, false, true><<<dim3(768, 1), 256, 0, stream>>>(
                o1b, WovT + l * 16384, nullptr, gb, x1, x1b, 128, nullptr, nullptr, nullptr);
        // x0 += t1 @ ff_w2 + fb2 ; (l==0: hbb = LN1_{l+1}(x0))   [BM=32 -> 512 blocks]
        if (l == 0)
            k_mgemm<256, 32, 1, true, true><<<dim3(512, 1), 256, 0, stream>>>(
                t1b, fw2T + l * 32768, fb2_l, nullptr, x0, nullptr, 128,
                ln1_s + 128, ln1_b + 128, hbb);
        else
            k_mgemm<256, 32, 1, false, true><<<dim3(512, 1), 256, 0, stream>>>(
                t1b, fw2T + l * 32768, fb2_l, nullptr, x0, nullptr, 128, nullptr, nullptr, nullptr);
    }

    // state head -> out (row-remapped)
    k_tgemm<128><<<dim3(128, 1), 256, 0, stream>>>(x0, W_state, b_state, out, 64, 64);
    // force head
    k_force1<<<(B_ * NC_ * 3 + 255) / 256, 256, 0, stream>>>(x1, W_force, b_force, frc);
    k_fsum<<<12, 256, 0, stream>>>(frc, fsum);
    k_force2<<<(B_ * NC_ * 3 + 255) / 256, 256, 0, stream>>>(frc, fsum, out + (size_t)B_ * NC_ * DIN_);
}

// Round 17
// 290.721 us; speedup vs baseline: 1.1848x; 1.0854x over previous
//
#include <hip/hip_runtime.h>
#include <cstdint>
#include <cstddef>

namespace {

constexpr int B_ = 4, NC_ = 4095, N_ = 4096, DIN_ = 64, D_ = 128, K_ = 6;
constexpr int XROW_ = 6 + DIN_;   // 70
constexpr int ROWS_ = B_ * N_;    // 16384
constexpr int KNQ = 2;            // queries per wave in knn
constexpr int KCAP = 32;          // hit-list capacity per query

typedef unsigned short u16;
typedef unsigned int u32;
typedef unsigned long long u64;
typedef __attribute__((ext_vector_type(8))) short short8;
typedef __attribute__((ext_vector_type(4))) float f32x4;

__device__ __forceinline__ float sigm(float x) { return 1.f / (1.f + expf(-x)); }
__device__ __forceinline__ float silu(float x) { return x / (1.f + expf(-x)); }
__device__ __forceinline__ u16 f2bf(float x) {
    u32 u = __float_as_uint(x);
    u += 0x7FFFu + ((u >> 16) & 1u);
    return (u16)(u >> 16);
}
__device__ __forceinline__ float bf2f(u16 x) {
    return __uint_as_float(((u32)x) << 16);
}

// ---------------- prep body: pos4 + feats(bf16) ----------------
__device__ __forceinline__ void prep_body(const float* __restrict__ X, float4* __restrict__ pos4,
                                          u16* __restrict__ featsb, int g)
{
    if (g >= ROWS_ * 64) return;
    int c = g & 63, row = g >> 6;
    int b = row >> 12, n = row & (N_ - 1);
    const float* xr = X + (size_t)(b * NC_ + n - 1) * XROW_;
    featsb[g] = (n > 0) ? f2bf(xr[6 + c]) : (u16)0;
    if (c == 0) {
        float4 p = {0.f, 0.f, 0.f, 0.f};
        if (n > 0) { p.x = xr[0]; p.y = xr[1]; p.z = xr[2]; }
        pos4[row] = p;
    }
}

// ---------------- prepw body (one layer slice) ----------------
__device__ __forceinline__ void prepw_body(int l, int g,
    const float* Wq, const float* Wk, const float* Wv, const float* gw,
    const float* fw1, const float* gb_, const float* fb1, const float* Wvv,
    const float* Wov, const float* Wo_, const float* fw2, const float* rw2,
    const float* rb2, const float* W_embed, const float* rw1,
    u16* WqkvT, u16* Wc2T, u16* WvvT, u16* WovT, u16* WoT, u16* fw2T, u16* WembT,
    float* bias2, float* rwg, float* rw1T, float* rw2vT)
{
    const float* Wq_l = Wq + l * 16384;  const float* Wk_l = Wk + l * 16384;
    const float* Wv_l = Wv + l * 16384;  const float* gw_l = gw + l * 16384;
    const float* fw1_l = fw1 + l * 32768; const float* gb_l = gb_ + l * 128;
    const float* fb1_l = fb1 + l * 256;  const float* Wvv_l = Wvv + l * 16384;
    const float* Wov_l = Wov + l * 16384; const float* Wo_ll = Wo_ + l * 16384;
    const float* fw2_l = fw2 + l * 32768; const float* rw2_l = rw2 + l * 4096;
    const float* rb2_l = rb2 + l * 256;  const float* rw1_l = rw1 + l * 256;

    if (g < 49152) {
        int n = g >> 7, k = g & 127;
        const float* src = (n < 128) ? Wq_l : ((n < 256) ? Wk_l : Wv_l);
        WqkvT[l * 49152 + g] = f2bf(src[k * 128 + (n & 127)]); return;
    }
    g -= 49152;
    if (g < 49152) {
        int n = g >> 7, k = g & 127;
        Wc2T[l * 49152 + g] = f2bf((n < 128) ? gw_l[k * 128 + n] : fw1_l[k * 256 + (n - 128)]); return;
    }
    g -= 49152;
    if (g < 16384) { int n = g >> 7, k = g & 127; WvvT[l * 16384 + g] = f2bf(Wvv_l[k * 128 + n]); return; }
    g -= 16384;
    if (g < 16384) { int n = g >> 7, k = g & 127; WovT[l * 16384 + g] = f2bf(Wov_l[k * 128 + n]); return; }
    g -= 16384;
    if (g < 16384) { int n = g >> 7, k = g & 127; WoT[l * 16384 + g] = f2bf(Wo_ll[k * 128 + n]); return; }
    g -= 16384;
    if (g < 32768) { int n = g >> 8, k = g & 255; fw2T[l * 32768 + g] = f2bf(fw2_l[k * 128 + n]); return; }
    g -= 32768;
    if (g < 384) { bias2[l * 384 + g] = (g < 128) ? gb_l[g] : fb1_l[g - 128]; return; }
    g -= 384;
    if (g < 64) {
        int hh = g >> 2, h = g & 3;
        float a = 0.f;
        #pragma unroll
        for (int dh = 0; dh < 32; ++dh) a += rw2_l[hh * 256 + h * 32 + dh];
        rwg[l * 128 + g] = a * (1.f / 32.f); return;
    }
    g -= 64;
    if (g < 4) {
        float a = 0.f;
        #pragma unroll
        for (int dh = 0; dh < 32; ++dh) a += rb2_l[g * 32 + dh];
        rwg[l * 128 + 64 + g] = a * (1.f / 32.f); return;
    }
    g -= 4;
    if (g < 256) {
        int hh = g >> 4, rr = g & 15;
        rw1T[l * 256 + hh * 16 + rr] = rw1_l[rr * 16 + hh]; return;
    }
    g -= 256;
    if (g < 2048) {
        int t = g >> 4, hh = g & 15;
        rw2vT[l * 2048 + t * 16 + hh] = rw2_l[hh * 256 + 128 + t]; return;
    }
    g -= 2048;
    if (g < 8192 && l == 0) {
        int n = g >> 6, k = g & 63;
        WembT[g] = f2bf(W_embed[k * 128 + n]);
    }
}

// ---------------- fused prep + prepw: blocks [0,4096) prep, [4096,5590) prepw ----------------
__global__ void k_prepall(const float* __restrict__ X, float4* __restrict__ pos4,
                          u16* __restrict__ featsb,
                          const float* Wq, const float* Wk, const float* Wv, const float* gw,
                          const float* fw1, const float* gb_, const float* fb1, const float* Wvv,
                          const float* Wov, const float* Wo_, const float* fw2, const float* rw2,
                          const float* rb2, const float* W_embed, const float* rw1,
                          u16* WqkvT, u16* Wc2T, u16* WvvT, u16* WovT, u16* WoT, u16* fw2T,
                          u16* WembT, float* bias2, float* rwg, float* rw1T, float* rw2vT)
{
    int id = blockIdx.x;
    if (id < 4096) {
        prep_body(X, pos4, featsb, id * 256 + threadIdx.x);
    } else {
        int id2 = id - 4096;
        int l = id2 / 747, gx = id2 % 747;
        prepw_body(l, gx * 256 + threadIdx.x, Wq, Wk, Wv, gw, fw1, gb_, fb1, Wvv, Wov, Wo_,
                   fw2, rw2, rb2, W_embed, rw1, WqkvT, Wc2T, WvvT, WovT, WoT, fw2T, WembT,
                   bias2, rwg, rw1T, rw2vT);
    }
}

// ---------------- knn helpers ----------------
__device__ __forceinline__ u64 shflxor64(u64 v, int mask)
{
    int lo = __shfl_xor((int)(u32)(v & 0xffffffffull), mask, 64);
    int hi = __shfl_xor((int)(u32)(v >> 32), mask, 64);
    return ((u64)(u32)hi << 32) | (u32)lo;
}

// 7th-smallest distinct lane value (self's 0 included in input -> still an upper
// bound on the true 6th-smallest candidate distance: the 7 smallest values contain
// self plus >=6 genuine candidate distances)
__device__ __forceinline__ float kth7min(float v)
{
    const float BIG = 3.4e38f;
    float kth = BIG;
    #pragma unroll
    for (int r = 0; r < 7; ++r) {
        float m = v;
        #pragma unroll
        for (int off = 1; off < 64; off <<= 1) m = fminf(m, __shfl_xor(m, off, 64));
        kth = m;
        if (v == m) v = BIG;   // dedup only raises bound (safe)
    }
    return kth;
}

__device__ __forceinline__ void geom_write(const float4* __restrict__ pb, int q, int j,
                                           size_t e, float* __restrict__ uv,
                                           float* __restrict__ rbfv)
{
    float4 pj = pb[j], pn = pb[q];
    float rx = pj.x - pn.x, ry = pj.y - pn.y, rz = pj.z - pn.z;
    float dist = sqrtf(rx * rx + ry * ry + rz * rz + 1e-8f);
    float inv = 1.f / dist;
    uv[e * 3 + 0] = rx * inv; uv[e * 3 + 1] = ry * inv; uv[e * 3 + 2] = rz * inv;
    #pragma unroll
    for (int r = 0; r < 16; ++r) {
        float t = (dist - (4.0f / 15.0f) * r) * 4.0f;
        rbfv[e * 16 + r] = expf(-t * t);
    }
}

// ---------------- KNN: 2 q/wave, branchless phase-1 (kth7 bound) + exact phase-2 ----------------
__global__ __launch_bounds__(256) void k_knn(const float4* __restrict__ pos4,
                                             int* __restrict__ idxv,
                                             float* __restrict__ uv,
                                             float* __restrict__ rbfv)
{
    __shared__ u64 sHits[4][KNQ][KCAP];
    __shared__ int sCnt[4][KNQ];
    const int w = threadIdx.x >> 6, lane = threadIdx.x & 63;
    const int wave = (blockIdx.x << 2) | w;
    const int b = wave >> 11;
    const int i0 = (wave & 2047) << 1;
    const float4* pb = pos4 + (size_t)b * N_;
    const float BIG = 3.4e38f;

    if (lane < KNQ) sCnt[w][lane] = 0;
    __syncthreads();

    float4 qv[KNQ];
    #pragma unroll
    for (int qq = 0; qq < KNQ; ++qq) qv[qq] = pb[i0 + qq];

    // phase 1: per-lane min d2 per query, self INCLUDED (branchless)
    float dmin[KNQ];
    #pragma unroll
    for (int qq = 0; qq < KNQ; ++qq) dmin[qq] = BIG;
    #pragma unroll 4
    for (int it = 0; it < 64; ++it) {
        int j = lane + (it << 6);
        float4 p = pb[j];
        #pragma unroll
        for (int qq = 0; qq < KNQ; ++qq) {
            float dx = p.x - qv[qq].x, dy = p.y - qv[qq].y, dz = p.z - qv[qq].z;
            float dd = dx * dx + dy * dy + dz * dz;
            dmin[qq] = fminf(dmin[qq], dd);
        }
    }
    float T[KNQ];
    #pragma unroll
    for (int qq = 0; qq < KNQ; ++qq) T[qq] = kth7min(dmin[qq]) * 1.000002f;

    // phase 2: compact hits (dd <= T, self excluded) into LDS
    #pragma unroll 4
    for (int it = 0; it < 64; ++it) {
        int j = lane + (it << 6);
        float4 p = pb[j];
        #pragma unroll
        for (int qq = 0; qq < KNQ; ++qq) {
            float dx = p.x - qv[qq].x, dy = p.y - qv[qq].y, dz = p.z - qv[qq].z;
            float dd = dx * dx + dy * dy + dz * dz;
            if (dd <= T[qq] && j != i0 + qq) {
                int slot = atomicAdd(&sCnt[w][qq], 1);
                if (slot < KCAP)
                    sHits[w][qq][slot] = ((u64)__float_as_uint(dd) << 32) | (u32)j;
            }
        }
    }
    __syncthreads();

    // extraction: 32-lane group g handles query g; exact 6x min over hit list
    const int g = lane >> 5, li = lane & 31;
    const int cnt = sCnt[w][g];
    const int q = i0 + g;
    u64 ent = (li < (cnt < KCAP ? cnt : KCAP)) ? sHits[w][g][li] : ~0ull;
    int myj = -1;
    #pragma unroll
    for (int k = 0; k < 6; ++k) {
        u64 m = ent;
        #pragma unroll
        for (int off = 1; off < 32; off <<= 1) {
            u64 o = shflxor64(m, off);
            if (o < m) m = o;
        }
        if (li == k) myj = (int)(u32)(m & 0xffffffffull);
        if (ent == m) ent = ~0ull;
    }
    if (cnt <= KCAP && li < 6) {
        size_t e = (size_t)(b * N_ + q) * 6 + li;
        idxv[e] = myj;
        geom_write(pb, q, myj, e, uv, rbfv);
    }

    // fallback for overflowed queries (exact per-lane insert; essentially never taken)
    u64 ovf = __ballot(li == 0 && cnt > KCAP);
    while (ovf) {
        int gl = __ffsll(ovf) - 1; ovf &= ovf - 1;
        int qq = gl >> 5;
        int qx = i0 + qq;
        float4 qp = pb[qx];
        float Tq = T[0];
        #pragma unroll
        for (int z = 1; z < KNQ; ++z) if (z == qq) Tq = T[z];
        float e0 = BIG, e1 = BIG, e2 = BIG, e3 = BIG, e4 = BIG, e5 = BIG;
        int j0 = 0, j1 = 0, j2 = 0, j3 = 0, j4 = 0, j5 = 0;
        for (int it = 0; it < 64; ++it) {
            int j = lane + (it << 6);
            float4 p = pb[j];
            float dx = p.x - qp.x, dy = p.y - qp.y, dz = p.z - qp.z;
            float dd = dx * dx + dy * dy + dz * dz;
            if (dd <= Tq && j != qx && dd < e5) {
                e5 = dd; j5 = j;
                float td; int tj;
                if (e5 < e4) { td = e4; e4 = e5; e5 = td; tj = j4; j4 = j5; j5 = tj; }
                if (e4 < e3) { td = e3; e3 = e4; e4 = td; tj = j3; j3 = j4; j4 = tj; }
                if (e3 < e2) { td = e2; e2 = e3; e3 = td; tj = j2; j2 = j3; j3 = tj; }
                if (e2 < e1) { td = e1; e1 = e2; e2 = td; tj = j1; j1 = j2; j2 = tj; }
                if (e1 < e0) { td = e0; e0 = e1; e1 = td; tj = j0; j0 = j1; j1 = tj; }
            }
        }
        u64 a0 = ((u64)__float_as_uint(e0) << 32) | (u32)j0;
        u64 a1 = ((u64)__float_as_uint(e1) << 32) | (u32)j1;
        u64 a2 = ((u64)__float_as_uint(e2) << 32) | (u32)j2;
        u64 a3 = ((u64)__float_as_uint(e3) << 32) | (u32)j3;
        u64 a4 = ((u64)__float_as_uint(e4) << 32) | (u32)j4;
        u64 a5 = ((u64)__float_as_uint(e5) << 32) | (u32)j5;
        int fj = -1;
        #pragma unroll
        for (int k = 0; k < 6; ++k) {
            u64 m = a0;
            #pragma unroll
            for (int off = 1; off < 64; off <<= 1) {
                u64 o = shflxor64(m, off);
                if (o < m) m = o;
            }
            if (a0 == m) { a0 = a1; a1 = a2; a2 = a3; a3 = a4; a4 = a5; a5 = ~0ull; }
            if (lane == k) fj = (int)(u32)(m & 0xffffffffull);
        }
        if (lane < 6) {
            size_t e = (size_t)(b * N_ + qx) * 6 + lane;
            idxv[e] = fj;
            geom_write(pb, qx, fj, e, uv, rbfv);
        }
    }
}

// ---------------- MFMA bf16 GEMM device body: BMx128 tile, 4 waves x (BMx32) ----------------
template<int KD, int BM, int EPI, bool LN, bool X1ACC>
__device__ __forceinline__ void mgemm_body(
    const u16* __restrict__ A, const u16* __restrict__ WT,
    const float* __restrict__ bias, const float* __restrict__ aux,
    float* __restrict__ C, u16* __restrict__ Cb, int ldc,
    const float* __restrict__ lns, const float* __restrict__ lnb,
    u16* __restrict__ lnout,
    int bx, int by, u16* sA, u16* sB, float* sLNraw)
{
    constexpr int MI = BM / 16;
    float (*sLN)[4][2] = (float(*)[4][2])sLNraw;
    const int tid = threadIdx.x;
    const int lane = tid & 63, wn = tid >> 6;
    const int m0 = bx * BM, n0 = by * 128;
    f32x4 acc[MI][2] = {};

    for (int k0 = 0; k0 < KD; k0 += 32) {
        __syncthreads();
        if (BM == 64) {
            int row = tid >> 2, gk = tid & 3;
            *(uint4*)&sA[row * 40 + gk * 8] =
                *(const uint4*)&A[(size_t)(m0 + row) * KD + k0 + gk * 8];
        } else {
            if (tid < BM * 4) {
                int row = tid >> 2, gk = tid & 3;
                *(uint4*)&sA[row * 40 + gk * 8] =
                    *(const uint4*)&A[(size_t)(m0 + row) * KD + k0 + gk * 8];
            }
        }
        #pragma unroll
        for (int cc = 0; cc < 2; ++cc) {
            int c = tid * 2 + cc;
            int row = c >> 2, gk = c & 3;
            *(uint4*)&sB[row * 40 + gk * 8] =
                *(const uint4*)&WT[(size_t)(n0 + row) * KD + k0 + gk * 8];
        }
        __syncthreads();
        const int gk = lane >> 4, lr = lane & 15;
        short8 af[MI], bfr[2];
        #pragma unroll
        for (int i = 0; i < MI; ++i)
            af[i] = *(const short8*)&sA[(i * 16 + lr) * 40 + gk * 8];
        #pragma unroll
        for (int i = 0; i < 2; ++i)
            bfr[i] = *(const short8*)&sB[(wn * 32 + i * 16 + lr) * 40 + gk * 8];
        #pragma unroll
        for (int mi = 0; mi < MI; ++mi)
            #pragma unroll
            for (int ni = 0; ni < 2; ++ni)
                acc[mi][ni] = __builtin_amdgcn_mfma_f32_16x16x32_bf16(af[mi], bfr[ni], acc[mi][ni], 0, 0, 0);
    }

    const int lg = lane >> 4;
    const int lc = lane & 15;
    if (LN) {
        float s1[MI][4], s2[MI][4];
        #pragma unroll
        for (int mi = 0; mi < MI; ++mi) {
            int rbase = m0 + mi * 16 + lg * 4;
            #pragma unroll
            for (int ee = 0; ee < 4; ++ee) { s1[mi][ee] = 0.f; s2[mi][ee] = 0.f; }
            #pragma unroll
            for (int ni = 0; ni < 2; ++ni) {
                int col = wn * 32 + ni * 16 + lc;
                float bc = bias ? bias[col] : 0.f;
                #pragma unroll
                for (int ee = 0; ee < 4; ++ee) {
                    float v = acc[mi][ni][ee] + bc;
                    if (EPI == 1) v += C[(size_t)(rbase + ee) * 128 + col];
                    acc[mi][ni][ee] = v;
                    s1[mi][ee] += v;
                    s2[mi][ee] += v * v;
                }
            }
        }
        #pragma unroll
        for (int mi = 0; mi < MI; ++mi)
            #pragma unroll
            for (int ee = 0; ee < 4; ++ee)
                #pragma unroll
                for (int off = 1; off < 16; off <<= 1) {
                    s1[mi][ee] += __shfl_xor(s1[mi][ee], off, 64);
                    s2[mi][ee] += __shfl_xor(s2[mi][ee], off, 64);
                }
        if (lc == 0) {
            #pragma unroll
            for (int mi = 0; mi < MI; ++mi)
                #pragma unroll
                for (int ee = 0; ee < 4; ++ee) {
                    int r = mi * 16 + lg * 4 + ee;
                    sLN[r][wn][0] = s1[mi][ee];
                    sLN[r][wn][1] = s2[mi][ee];
                }
        }
        __syncthreads();
        #pragma unroll
        for (int mi = 0; mi < MI; ++mi) {
            int rbase = m0 + mi * 16 + lg * 4;
            #pragma unroll
            for (int ee = 0; ee < 4; ++ee) {
                int r = mi * 16 + lg * 4 + ee;
                float sum = sLN[r][0][0] + sLN[r][1][0] + sLN[r][2][0] + sLN[r][3][0];
                float sq  = sLN[r][0][1] + sLN[r][1][1] + sLN[r][2][1] + sLN[r][3][1];
                float mean = sum * (1.f / 128.f);
                float var = sq * (1.f / 128.f) - mean * mean;
                float inv = 1.f / sqrtf(var + 1e-5f);
                #pragma unroll
                for (int ni = 0; ni < 2; ++ni) {
                    int col = wn * 32 + ni * 16 + lc;
                    float v = acc[mi][ni][ee];
                    size_t o = (size_t)(rbase + ee) * 128 + col;
                    C[o] = v;
                    lnout[o] = f2bf((v - mean) * inv * lns[col] + lnb[col]);
                }
            }
        }
        return;
    }

    #pragma unroll
    for (int mi = 0; mi < MI; ++mi) {
        int rbase = m0 + mi * 16 + lg * 4;
        #pragma unroll
        for (int ni = 0; ni < 2; ++ni) {
            int col = n0 + wn * 32 + ni * 16 + lc;
            if (EPI == 0) {
                float bc = bias ? bias[col] : 0.f;
                #pragma unroll
                for (int ee = 0; ee < 4; ++ee)
                    C[(size_t)(rbase + ee) * ldc + col] = acc[mi][ni][ee] + bc;
            } else if (EPI == 1) {
                float bc = bias ? bias[col] : 0.f;
                #pragma unroll
                for (int ee = 0; ee < 4; ++ee) {
                    size_t o = (size_t)(rbase + ee) * ldc + col;
                    C[o] += acc[mi][ni][ee] + bc;
                }
            } else if (EPI == 2) {
                float bc = bias[col];
                if (n0 == 0) {
                    #pragma unroll
                    for (int ee = 0; ee < 4; ++ee)
                        C[(size_t)(rbase + ee) * 128 + col] = sigm(acc[mi][ni][ee] + bc);
                } else {
                    int c2 = col - 128;
                    #pragma unroll
                    for (int ee = 0; ee < 4; ++ee)
                        Cb[(size_t)(rbase + ee) * 256 + c2] = f2bf(silu(acc[mi][ni][ee] + bc));
                }
            } else if (EPI == 4) {
                float bc = bias ? bias[col] : 0.f;
                #pragma unroll
                for (int ee = 0; ee < 4; ++ee)
                    Cb[(size_t)(rbase + ee) * ldc + col] = f2bf(acc[mi][ni][ee] + bc);
            } else {
                #pragma unroll
                for (int ee = 0; ee < 4; ++ee) {
                    int m = rbase + ee;
                    size_t o = (size_t)m * 128 + col;
                    float v = acc[mi][ni][ee];
                    if (X1ACC) v += C[o];
                    v *= aux[(size_t)(m / 3) * 128 + col];
                    C[o] = v;
                    Cb[o] = f2bf(v);
                }
            }
        }
    }
}

template<int KD, int BM, int EPI, bool LN, bool X1ACC>
__global__ __launch_bounds__(256) void k_mgemm(
    const u16* __restrict__ A, const u16* __restrict__ WT,
    const float* __restrict__ bias, const float* __restrict__ aux,
    float* __restrict__ C, u16* __restrict__ Cb, int ldc,
    const float* __restrict__ lns, const float* __restrict__ lnb,
    u16* __restrict__ lnout)
{
    __shared__ u16 sA[64 * 40];
    __shared__ u16 sB[128 * 40];
    __shared__ float sLN[64 * 4 * 2];
    mgemm_body<KD, BM, EPI, LN, X1ACC>(A, WT, bias, aux, C, Cb, ldc, lns, lnb, lnout,
                                       blockIdx.x, blockIdx.y, sA, sB, sLN);
}

// dual GEMM: blocks [0,nx0) run part 0 (bx=id%nxdiv0, by=id/nxdiv0); rest part 1 (by=0)
template<int KD0, int BM0, int EPI0, bool LN0, bool XA0,
         int KD1, int BM1, int EPI1, bool LN1v, bool XA1>
__global__ __launch_bounds__(256) void k_mgemm_dual(
    const u16* A0, const u16* WT0, const float* b0, const float* aux0,
    float* C0, u16* Cb0, int ldc0, const float* lns0, const float* lnb0, u16* ln0,
    int nx0, int nxdiv0,
    const u16* A1, const u16* WT1, const float* b1, const float* aux1,
    float* C1, u16* Cb1, int ldc1, const float* lns1, const float* lnb1, u16* ln1)
{
    __shared__ u16 sA[64 * 40];
    __shared__ u16 sB[128 * 40];
    __shared__ float sLN[64 * 4 * 2];
    int id = blockIdx.x;
    if (id < nx0) {
        mgemm_body<KD0, BM0, EPI0, LN0, XA0>(A0, WT0, b0, aux0, C0, Cb0, ldc0, lns0, lnb0, ln0,
                                             id % nxdiv0, id / nxdiv0, sA, sB, sLN);
    } else {
        id -= nx0;
        mgemm_body<KD1, BM1, EPI1, LN1v, XA1>(A1, WT1, b1, aux1, C1, Cb1, ldc1, lns1, lnb1, ln1,
                                              id, 0, sA, sB, sLN);
    }
}

// ---------------- fused attention v3: wave-per-row, barrier-free ----------------
template<bool HASY1>
__global__ __launch_bounds__(256) void k_attn(
    const u16* __restrict__ qkvb, const int* __restrict__ idxv,
    const float* __restrict__ rbfv, const float* __restrict__ uv,
    const u16* __restrict__ y1b,
    const float* __restrict__ rw1T, const float* __restrict__ rb1,
    const float* __restrict__ rw2vT, const float* __restrict__ rwg,
    const float* __restrict__ rb2,
    u16* __restrict__ o0b, u16* __restrict__ o1b)
{
    const int wid = threadIdx.x >> 6, lane = threadIdx.x & 63;
    const int row = blockIdx.x * 4 + wid;
    const int b = row >> 12;
    const int ch0 = lane * 2;
    const int h = lane >> 4;

    __shared__ float sHid[4][6][16];
    __shared__ float sU[4][6][3];

    int jl = 0;
    if (lane < 6) jl = idxv[row * 6 + lane];
    int jj[6];
    #pragma unroll
    for (int k = 0; k < 6; ++k) jj[k] = __shfl(jl, k, 64);

    if (lane < 18) sU[wid][lane / 3][lane % 3] = uv[(size_t)row * 18 + lane];

    {
        int idx = lane;
        #pragma unroll
        for (int rep = 0; rep < 2; ++rep) {
            if (idx < 96) {
                int k = idx >> 4, hh = idx & 15;
                float a = rb1[hh];
                const float* rb = rbfv + (size_t)(row * 6 + k) * 16;
                const float* wr = rw1T + hh * 16;
                #pragma unroll
                for (int rr = 0; rr < 16; ++rr) a += rb[rr] * wr[rr];
                sHid[wid][k][hh] = silu(a);
            }
            idx += 64;
        }
    }
    __builtin_amdgcn_wave_barrier();
    __threadfence_block();
    __builtin_amdgcn_wave_barrier();

    u32 qp = *(const u32*)&qkvb[(size_t)row * 384 + ch0];
    float q0 = bf2f((u16)qp), q1 = bf2f((u16)(qp >> 16));

    float part[6];
    #pragma unroll
    for (int k = 0; k < 6; ++k) {
        u32 kp = *(const u32*)&qkvb[(size_t)(b * N_ + jj[k]) * 384 + 128 + ch0];
        part[k] = q0 * bf2f((u16)kp) + q1 * bf2f((u16)(kp >> 16));
    }
    #pragma unroll
    for (int off = 1; off < 16; off <<= 1)
        #pragma unroll
        for (int k = 0; k < 6; ++k)
            part[k] += __shfl_xor(part[k], off, 64);

    float lg[6];
    #pragma unroll
    for (int k = 0; k < 6; ++k) {
        float bias = rwg[64 + h];
        #pragma unroll
        for (int hh = 0; hh < 16; ++hh) bias += sHid[wid][k][hh] * rwg[hh * 4 + h];
        lg[k] = part[k] * 0.17677669529663687f + bias;
    }

    float mx = lg[0];
    #pragma unroll
    for (int k = 1; k < 6; ++k) mx = fmaxf(mx, lg[k]);
    float a[6], smv = 0.f;
    #pragma unroll
    for (int k = 0; k < 6; ++k) { a[k] = expf(lg[k] - mx); smv += a[k]; }
    float inv = 1.f / smv;
    #pragma unroll
    for (int k = 0; k < 6; ++k) a[k] *= inv;

    float rwc0[16], rwc1[16];
    {
        const float4* wp = (const float4*)(rw2vT + ch0 * 16);
        #pragma unroll
        for (int i = 0; i < 4; ++i) {
            float4 v0 = wp[i], v1 = wp[i + 4];
            rwc0[i * 4 + 0] = v0.x; rwc0[i * 4 + 1] = v0.y; rwc0[i * 4 + 2] = v0.z; rwc0[i * 4 + 3] = v0.w;
            rwc1[i * 4 + 0] = v1.x; rwc1[i * 4 + 1] = v1.y; rwc1[i * 4 + 2] = v1.z; rwc1[i * 4 + 3] = v1.w;
        }
    }
    float rb20 = rb2[128 + ch0], rb21 = rb2[128 + ch0 + 1];
    float rvk0[6], rvk1[6];
    #pragma unroll
    for (int k = 0; k < 6; ++k) {
        float a0 = rb20, a1 = rb21;
        #pragma unroll
        for (int hh = 0; hh < 16; ++hh) {
            float hv = sHid[wid][k][hh];
            a0 += hv * rwc0[hh];
            a1 += hv * rwc1[hh];
        }
        rvk0[k] = a0; rvk1[k] = a1;
    }

    float o00 = 0.f, o01 = 0.f;
    #pragma unroll
    for (int k = 0; k < 6; ++k) {
        u32 vp = *(const u32*)&qkvb[(size_t)(b * N_ + jj[k]) * 384 + 256 + ch0];
        o00 += a[k] * bf2f((u16)vp) * silu(rvk0[k]);
        o01 += a[k] * bf2f((u16)(vp >> 16)) * silu(rvk1[k]);
    }
    *(u32*)&o0b[(size_t)row * 128 + ch0] = (u32)f2bf(o00) | ((u32)f2bf(o01) << 16);

    #pragma unroll
    for (int c = 0; c < 3; ++c) {
        float s0 = 0.f, s1 = 0.f;
        #pragma unroll
        for (int k = 0; k < 6; ++k) {
            float b0 = 0.f, b1 = 0.f;
            if (HASY1) {
                u32 yp = *(const u32*)&y1b[((size_t)(b * N_ + jj[k]) * 3 + c) * 128 + ch0];
                b0 = bf2f((u16)yp); b1 = bf2f((u16)(yp >> 16));
            }
            float uk = sU[wid][k][c];
            s0 += a[k] * (b0 + rvk0[k] * uk);
            s1 += a[k] * (b1 + rvk1[k] * uk);
        }
        *(u32*)&o1b[((size_t)row * 3 + c) * 128 + ch0] = (u32)f2bf(s0) | ((u32)f2bf(s1) << 16);
    }
}

// ---------------- fused heads: blocks [0,128) state GEMM; [128,320) force1 ----------------
__global__ __launch_bounds__(256) void k_head(
    const float* __restrict__ x0, const float* __restrict__ W_state,
    const float* __restrict__ b_state, float* __restrict__ out,
    const float* __restrict__ x1, const float* __restrict__ W_force,
    const float* __restrict__ b_force, float* __restrict__ frc)
{
    __shared__ __align__(16) float As[32 * 132];
    __shared__ __align__(16) float Ws[32 * 68];
    const int tid = threadIdx.x;
    if (blockIdx.x < 128) {
        const int tx = tid & 15, ty = tid >> 4;
        const int m0 = blockIdx.x * 128, n0 = 0;
        float acc[8][4] = {};
        for (int k0 = 0; k0 < 128; k0 += 32) {
            __syncthreads();
            #pragma unroll
            for (int r = 0; r < 4; ++r) {
                int id = tid + r * 256;
                int row = id >> 3, kq = id & 7;
                float4 a4 = *(const float4*)&x0[(size_t)(m0 + row) * 128 + k0 + kq * 4];
                As[(kq * 4 + 0) * 132 + row] = a4.x;
                As[(kq * 4 + 1) * 132 + row] = a4.y;
                As[(kq * 4 + 2) * 132 + row] = a4.z;
                As[(kq * 4 + 3) * 132 + row] = a4.w;
            }
            #pragma unroll
            for (int r = 0; r < 2; ++r) {
                int id = tid + r * 256;
                int kr = id >> 4, cq = id & 15;
                *(float4*)&Ws[kr * 68 + cq * 4] =
                    *(const float4*)&W_state[(size_t)(k0 + kr) * 64 + n0 + cq * 4];
            }
            __syncthreads();
            #pragma unroll 8
            for (int k = 0; k < 32; ++k) {
                float4 aA = *(const float4*)&As[k * 132 + ty * 8];
                float4 aB = *(const float4*)&As[k * 132 + ty * 8 + 4];
                float4 w4 = *(const float4*)&Ws[k * 68 + tx * 4];
                float av[8] = {aA.x, aA.y, aA.z, aA.w, aB.x, aB.y, aB.z, aB.w};
                float wv[4] = {w4.x, w4.y, w4.z, w4.w};
                #pragma unroll
                for (int r = 0; r < 8; ++r)
                    #pragma unroll
                    for (int j = 0; j < 4; ++j)
                        acc[r][j] += av[r] * wv[j];
            }
        }
        float bv[4];
        #pragma unroll
        for (int j = 0; j < 4; ++j) bv[j] = b_state[n0 + tx * 4 + j];
        #pragma unroll
        for (int r = 0; r < 8; ++r) {
            int m = m0 + ty * 8 + r;
            int n = m & (N_ - 1), bb2 = m >> 12;
            if (n == 0) continue;
            float* dst = out + ((size_t)(bb2 * NC_ + n - 1)) * 64 + n0 + tx * 4;
            float4 res = {acc[r][0] + bv[0], acc[r][1] + bv[1], acc[r][2] + bv[2], acc[r][3] + bv[3]};
            *(float4*)dst = res;
        }
    } else {
        int g = (blockIdx.x - 128) * 256 + tid;
        if (g >= B_ * NC_ * 3) return;
        int c = g % 3, rr = g / 3;
        int b = rr / NC_, n = rr - b * NC_;
        const float* xr = x1 + (size_t)(b * N_ + n + 1) * 384 + c * 128;
        float a = b_force[0];
        for (int d = 0; d < 128; ++d) a += xr[d * 3 - d * 3 + d] * 0.f + xr[d] * W_force[d];
        frc[g] = a;
    }
}

__global__ __launch_bounds__(256) void k_fsum(const float* __restrict__ frc, float* __restrict__ fsum)
{
    int b = blockIdx.x / 3, c = blockIdx.x % 3;
    __shared__ float red[256];
    float a = 0.f;
    for (int n = threadIdx.x; n < NC_; n += 256) a += frc[(b * NC_ + n) * 3 + c];
    red[threadIdx.x] = a; __syncthreads();
    for (int st = 128; st > 0; st >>= 1) { if (threadIdx.x < st) red[threadIdx.x] += red[threadIdx.x + st]; __syncthreads(); }
    if (threadIdx.x == 0) fsum[blockIdx.x] = red[0] / (float)NC_;
}

__global__ void k_force2(const float* __restrict__ frc, const float* __restrict__ fsum,
                         float* __restrict__ out)
{
    int g = blockIdx.x * 256 + threadIdx.x;
    if (g >= B_ * NC_ * 3) return;
    int c = g % 3;
    int b = g / (NC_ * 3);
    out[g] = frc[g] - fsum[b * 3 + c];
}

} // namespace

extern "C" void kernel_launch(void* const* d_in, const int* in_sizes, int n_in,
                              void* d_out, int out_size, void* d_ws, size_t ws_size,
                              hipStream_t stream)
{
    const float* X       = (const float*)d_in[0];
    const float* W_embed = (const float*)d_in[1];
    const float* b_embed = (const float*)d_in[2];
    const float* Wq      = (const float*)d_in[3];
    const float* Wk      = (const float*)d_in[4];
    const float* Wv      = (const float*)d_in[5];
    const float* Wvv     = (const float*)d_in[6];
    const float* rw1     = (const float*)d_in[7];
    const float* rb1     = (const float*)d_in[8];
    const float* rw2     = (const float*)d_in[9];
    const float* rb2     = (const float*)d_in[10];
    const float* Wo      = (const float*)d_in[11];
    const float* Wov     = (const float*)d_in[12];
    const float* ff_w1   = (const float*)d_in[13];
    const float* ff_b1   = (const float*)d_in[14];
    const float* ff_w2   = (const float*)d_in[15];
    const float* ff_b2   = (const float*)d_in[16];
    const float* gate_w  = (const float*)d_in[17];
    const float* gate_b  = (const float*)d_in[18];
    const float* ln1_s   = (const float*)d_in[19];
    const float* ln1_b   = (const float*)d_in[20];
    const float* ln2_s   = (const float*)d_in[21];
    const float* ln2_b   = (const float*)d_in[22];
    const float* W_state = (const float*)d_in[23];
    const float* b_state = (const float*)d_in[24];
    const float* W_force = (const float*)d_in[25];
    const float* b_force = (const float*)d_in[26];
    (void)in_sizes; (void)n_in; (void)out_size; (void)ws_size;

    float* out = (float*)d_out;
    float* w = (float*)d_ws;

    float4* pos4  = (float4*)w;                    // -> 65536
    int*    idxv  = (int*)(w + 65536);             // -> 163840
    float*  uv    = w + 163840;                    // -> 458752
    float*  rbfv  = w + 458752;                    // -> 2031616
    u16*    featsb= (u16*)(w + 2031616);           // -> 2555904 (frc/fsum alias later)
    float*  x0    = w + 2555904;                   // -> 4653056
    u16*    hbb   = (u16*)(w + 4653056);           // -> 5701632
    u16*    qkvbb = (u16*)(w + 5701632);           // -> 8847360 used
    float*  gb    = w + 11993088;                  // -> 14090240
    u16*    o0b   = (u16*)(w + 14090240);          // -> 15138816
    u16*    o1b   = (u16*)(w + 15138816);          // -> 18284544
    float*  x1    = w + 18284544;                  // -> 24576000
    u16*    x1b   = (u16*)(w + 24576000);          // -> 27721728
    u16*    t1b   = (u16*)(w + 27721728);          // bf16; also y1b (disjoint live ranges)
    u16*    y1b   = t1b;
    u16*    WqkvT = (u16*)(w + 34013184);
    u16*    Wc2T  = (u16*)(w + 34062336);
    u16*    WvvT  = (u16*)(w + 34111488);
    u16*    WovT  = (u16*)(w + 34127872);
    u16*    WoT   = (u16*)(w + 34144256);
    u16*    fw2T  = (u16*)(w + 34160640);
    u16*    WembT = (u16*)(w + 34193408);
    float*  bias2 = w + 34197504;                  // 2x384 -> 34198272
    float*  rwg   = w + 34198272;                  // 2x128 -> 34198528
    float*  rw1T  = w + 34198528;                  // 2x256 -> 34199040
    float*  rw2vT = w + 34199040;                  // 2x2048 -> 34203136
    float*  frc   = (float*)featsb;
    float*  fsum  = ((float*)featsb) + 49152;

    // fused prep + weight prep (4096 + 1494 blocks)
    k_prepall<<<5590, 256, 0, stream>>>(X, pos4, featsb,
                                        Wq, Wk, Wv, gate_w, ff_w1, gate_b, ff_b1,
                                        Wvv, Wov, Wo, ff_w2, rw2, rb2, W_embed, rw1,
                                        WqkvT, Wc2T, WvvT, WovT, WoT, fw2T, WembT,
                                        bias2, rwg, rw1T, rw2vT);
    k_knn<<<ROWS_ / 8, 256, 0, stream>>>(pos4, idxv, uv, rbfv);
    // x0 = feats @ W_embed + b_embed ; hbb = LN1(x0)
    k_mgemm<64, 32, 0, true, true><<<dim3(512, 1), 256, 0, stream>>>(
        featsb, WembT, b_embed, nullptr, x0, nullptr, 128, ln1_s, ln1_b, hbb);

    for (int l = 0; l < 2; ++l) {
        const float* rb1_l = rb1 + l * 16;
        const float* rb2_l = rb2 + l * 256;
        const float* fb2_l = ff_b2 + l * 128;

        // qkv (= h @ Wqkv, bf16 out); layer 1 fused with y1 = x1 @ Wvv
        if (l == 0)
            k_mgemm<128, 64, 4, false, true><<<dim3(256, 3), 256, 0, stream>>>(
                hbb, WqkvT, nullptr, nullptr, nullptr, qkvbb, 384, nullptr, nullptr, nullptr);
        else
            k_mgemm_dual<128, 64, 4, false, true, 128, 64, 4, false, true><<<1536, 256, 0, stream>>>(
                hbb, WqkvT + 49152, nullptr, nullptr, nullptr, qkvbb, 384, nullptr, nullptr, nullptr,
                768, 256,
                x1b, WvvT + 16384, nullptr, nullptr, nullptr, y1b, 128, nullptr, nullptr, nullptr);
        // attention (wave-per-row)
        if (l == 0)
            k_attn<false><<<ROWS_ / 4, 256, 0, stream>>>(qkvbb, idxv, rbfv, uv, nullptr,
                rw1T + l * 256, rb1_l, rw2vT + l * 2048, rwg + l * 128, rb2_l, o0b, o1b);
        else
            k_attn<true><<<ROWS_ / 4, 256, 0, stream>>>(qkvbb, idxv, rbfv, uv, y1b,
                rw1T + l * 256, rb1_l, rw2vT + l * 2048, rwg + l * 128, rb2_l, o0b, o1b);
        // x0 += o0 @ Wo ; hbb = LN2(x0)
        k_mgemm<128, 32, 1, true, true><<<dim3(512, 1), 256, 0, stream>>>(
            o0b, WoT + l * 16384, nullptr, nullptr, x0, nullptr, 128,
            ln2_s + l * 128, ln2_b + l * 128, hbb);
        // [gate fp32 | t1 bf16] = h2 @ [gate_w|ff_w1]
        k_mgemm<128, 64, 2, false, true><<<dim3(256, 3), 256, 0, stream>>>(
            hbb, Wc2T + l * 49152, bias2 + l * 384, nullptr, gb, t1b, 128, nullptr, nullptr, nullptr);
        // fused: x1 = ((l? x1:0) + o1 @ Wov) * gate  ||  x0 += t1 @ ff_w2 (+LN1' on l0)
        if (l == 0)
            k_mgemm_dual<128, 64, 3, false, false, 256, 32, 1, true, true><<<1280, 256, 0, stream>>>(
                o1b, WovT, nullptr, gb, x1, x1b, 128, nullptr, nullptr, nullptr,
                768, 768,
                t1b, fw2T, fb2_l, nullptr, x0, nullptr, 128, ln1_s + 128, ln1_b + 128, hbb);
        else
            k_mgemm_dual<128, 64, 3, false, true, 256, 32, 1, false, true><<<1280, 256, 0, stream>>>(
                o1b, WovT + 16384, nullptr, gb, x1, x1b, 128, nullptr, nullptr, nullptr,
                768, 768,
                t1b, fw2T + 32768, fb2_l, nullptr, x0, nullptr, 128, nullptr, nullptr, nullptr);
    }

    // fused: state head (128 blocks) + force1 (192 blocks)
    k_head<<<320, 256, 0, stream>>>(x0, W_state, b_state, out, x1, W_force, b_force, frc);
    k_fsum<<<12, 256, 0, stream>>>(frc, fsum);
    k_force2<<<(B_ * NC_ * 3 + 255) / 256, 256, 0, stream>>>(frc, fsum, out + (size_t)B_ * NC_ * DIN_);
}

// Round 18
// 285.852 us; speedup vs baseline: 1.2049x; 1.0170x over previous
//
#include <hip/hip_runtime.h>
#include <cstdint>
#include <cstddef>

namespace {

constexpr int B_ = 4, NC_ = 4095, N_ = 4096, DIN_ = 64, D_ = 128, K_ = 6;
constexpr int XROW_ = 6 + DIN_;   // 70
constexpr int ROWS_ = B_ * N_;    // 16384
constexpr int KNQ = 2;            // queries per wave in knn
constexpr int KCAP = 32;          // hit-list capacity per query

typedef unsigned short u16;
typedef unsigned int u32;
typedef unsigned long long u64;
typedef __attribute__((ext_vector_type(8))) short short8;
typedef __attribute__((ext_vector_type(4))) float f32x4;

__device__ __forceinline__ float sigm(float x) { return 1.f / (1.f + expf(-x)); }
__device__ __forceinline__ float silu(float x) { return x / (1.f + expf(-x)); }
__device__ __forceinline__ u16 f2bf(float x) {
    u32 u = __float_as_uint(x);
    u += 0x7FFFu + ((u >> 16) & 1u);
    return (u16)(u >> 16);
}
__device__ __forceinline__ float bf2f(u16 x) {
    return __uint_as_float(((u32)x) << 16);
}

// ---------------- prep body: pos4 + feats(bf16) ----------------
__device__ __forceinline__ void prep_body(const float* __restrict__ X, float4* __restrict__ pos4,
                                          u16* __restrict__ featsb, int g)
{
    if (g >= ROWS_ * 64) return;
    int c = g & 63, row = g >> 6;
    int b = row >> 12, n = row & (N_ - 1);
    const float* xr = X + (size_t)(b * NC_ + n - 1) * XROW_;
    featsb[g] = (n > 0) ? f2bf(xr[6 + c]) : (u16)0;
    if (c == 0) {
        float4 p = {0.f, 0.f, 0.f, 0.f};
        if (n > 0) { p.x = xr[0]; p.y = xr[1]; p.z = xr[2]; }
        pos4[row] = p;
    }
}

// ---------------- prepw body (one layer slice) ----------------
__device__ __forceinline__ void prepw_body(int l, int g,
    const float* Wq, const float* Wk, const float* Wv, const float* gw,
    const float* fw1, const float* gb_, const float* fb1, const float* Wvv,
    const float* Wov, const float* Wo_, const float* fw2, const float* rw2,
    const float* rb2, const float* W_embed, const float* rw1,
    u16* WqkvT, u16* Wc2T, u16* WvvT, u16* WovT, u16* WoT, u16* fw2T, u16* WembT,
    float* bias2, float* rwg, float* rw1T, float* rw2vT)
{
    const float* Wq_l = Wq + l * 16384;  const float* Wk_l = Wk + l * 16384;
    const float* Wv_l = Wv + l * 16384;  const float* gw_l = gw + l * 16384;
    const float* fw1_l = fw1 + l * 32768; const float* gb_l = gb_ + l * 128;
    const float* fb1_l = fb1 + l * 256;  const float* Wvv_l = Wvv + l * 16384;
    const float* Wov_l = Wov + l * 16384; const float* Wo_ll = Wo_ + l * 16384;
    const float* fw2_l = fw2 + l * 32768; const float* rw2_l = rw2 + l * 4096;
    const float* rb2_l = rb2 + l * 256;  const float* rw1_l = rw1 + l * 256;

    if (g < 49152) {
        int n = g >> 7, k = g & 127;
        const float* src = (n < 128) ? Wq_l : ((n < 256) ? Wk_l : Wv_l);
        WqkvT[l * 49152 + g] = f2bf(src[k * 128 + (n & 127)]); return;
    }
    g -= 49152;
    if (g < 49152) {
        int n = g >> 7, k = g & 127;
        Wc2T[l * 49152 + g] = f2bf((n < 128) ? gw_l[k * 128 + n] : fw1_l[k * 256 + (n - 128)]); return;
    }
    g -= 49152;
    if (g < 16384) { int n = g >> 7, k = g & 127; WvvT[l * 16384 + g] = f2bf(Wvv_l[k * 128 + n]); return; }
    g -= 16384;
    if (g < 16384) { int n = g >> 7, k = g & 127; WovT[l * 16384 + g] = f2bf(Wov_l[k * 128 + n]); return; }
    g -= 16384;
    if (g < 16384) { int n = g >> 7, k = g & 127; WoT[l * 16384 + g] = f2bf(Wo_ll[k * 128 + n]); return; }
    g -= 16384;
    if (g < 32768) { int n = g >> 8, k = g & 255; fw2T[l * 32768 + g] = f2bf(fw2_l[k * 128 + n]); return; }
    g -= 32768;
    if (g < 384) { bias2[l * 384 + g] = (g < 128) ? gb_l[g] : fb1_l[g - 128]; return; }
    g -= 384;
    if (g < 64) {
        int hh = g >> 2, h = g & 3;
        float a = 0.f;
        #pragma unroll
        for (int dh = 0; dh < 32; ++dh) a += rw2_l[hh * 256 + h * 32 + dh];
        rwg[l * 128 + g] = a * (1.f / 32.f); return;
    }
    g -= 64;
    if (g < 4) {
        float a = 0.f;
        #pragma unroll
        for (int dh = 0; dh < 32; ++dh) a += rb2_l[g * 32 + dh];
        rwg[l * 128 + 64 + g] = a * (1.f / 32.f); return;
    }
    g -= 4;
    if (g < 256) {
        int hh = g >> 4, rr = g & 15;
        rw1T[l * 256 + hh * 16 + rr] = rw1_l[rr * 16 + hh]; return;
    }
    g -= 256;
    if (g < 2048) {
        int t = g >> 4, hh = g & 15;
        rw2vT[l * 2048 + t * 16 + hh] = rw2_l[hh * 256 + 128 + t]; return;
    }
    g -= 2048;
    if (g < 8192 && l == 0) {
        int n = g >> 6, k = g & 63;
        WembT[g] = f2bf(W_embed[k * 128 + n]);
    }
}

// ---------------- fused prep + prepw: blocks [0,4096) prep, [4096,5590) prepw ----------------
__global__ void k_prepall(const float* __restrict__ X, float4* __restrict__ pos4,
                          u16* __restrict__ featsb,
                          const float* Wq, const float* Wk, const float* Wv, const float* gw,
                          const float* fw1, const float* gb_, const float* fb1, const float* Wvv,
                          const float* Wov, const float* Wo_, const float* fw2, const float* rw2,
                          const float* rb2, const float* W_embed, const float* rw1,
                          u16* WqkvT, u16* Wc2T, u16* WvvT, u16* WovT, u16* WoT, u16* fw2T,
                          u16* WembT, float* bias2, float* rwg, float* rw1T, float* rw2vT)
{
    int id = blockIdx.x;
    if (id < 4096) {
        prep_body(X, pos4, featsb, id * 256 + threadIdx.x);
    } else {
        int id2 = id - 4096;
        int l = id2 / 747, gx = id2 % 747;
        prepw_body(l, gx * 256 + threadIdx.x, Wq, Wk, Wv, gw, fw1, gb_, fb1, Wvv, Wov, Wo_,
                   fw2, rw2, rb2, W_embed, rw1, WqkvT, Wc2T, WvvT, WovT, WoT, fw2T, WembT,
                   bias2, rwg, rw1T, rw2vT);
    }
}

// ---------------- knn helpers ----------------
__device__ __forceinline__ u64 shflxor64(u64 v, int mask)
{
    int lo = __shfl_xor((int)(u32)(v & 0xffffffffull), mask, 64);
    int hi = __shfl_xor((int)(u32)(v >> 32), mask, 64);
    return ((u64)(u32)hi << 32) | (u32)lo;
}

// 7th-smallest distinct lane value (self's 0 included -> valid upper bound on true 6th)
__device__ __forceinline__ float kth7min(float v)
{
    const float BIG = 3.4e38f;
    float kth = BIG;
    #pragma unroll
    for (int r = 0; r < 7; ++r) {
        float m = v;
        #pragma unroll
        for (int off = 1; off < 64; off <<= 1) m = fminf(m, __shfl_xor(m, off, 64));
        kth = m;
        if (v == m) v = BIG;
    }
    return kth;
}

__device__ __forceinline__ void geom_write(const float4* __restrict__ pb, int q, int j,
                                           size_t e, float* __restrict__ uv,
                                           float* __restrict__ rbfv)
{
    float4 pj = pb[j], pn = pb[q];
    float rx = pj.x - pn.x, ry = pj.y - pn.y, rz = pj.z - pn.z;
    float dist = sqrtf(rx * rx + ry * ry + rz * rz + 1e-8f);
    float inv = 1.f / dist;
    uv[e * 3 + 0] = rx * inv; uv[e * 3 + 1] = ry * inv; uv[e * 3 + 2] = rz * inv;
    #pragma unroll
    for (int r = 0; r < 16; ++r) {
        float t = (dist - (4.0f / 15.0f) * r) * 4.0f;
        rbfv[e * 16 + r] = expf(-t * t);
    }
}

// ---------------- KNN: 2 q/wave, branchless phase-1 (kth7 bound) + exact phase-2 ----------------
__global__ __launch_bounds__(256) void k_knn(const float4* __restrict__ pos4,
                                             int* __restrict__ idxv,
                                             float* __restrict__ uv,
                                             float* __restrict__ rbfv)
{
    __shared__ u64 sHits[4][KNQ][KCAP];
    __shared__ int sCnt[4][KNQ];
    const int w = threadIdx.x >> 6, lane = threadIdx.x & 63;
    const int wave = (blockIdx.x << 2) | w;
    const int b = wave >> 11;
    const int i0 = (wave & 2047) << 1;
    const float4* pb = pos4 + (size_t)b * N_;
    const float BIG = 3.4e38f;

    if (lane < KNQ) sCnt[w][lane] = 0;
    __syncthreads();

    float4 qv[KNQ];
    #pragma unroll
    for (int qq = 0; qq < KNQ; ++qq) qv[qq] = pb[i0 + qq];

    float dmin[KNQ];
    #pragma unroll
    for (int qq = 0; qq < KNQ; ++qq) dmin[qq] = BIG;
    #pragma unroll 4
    for (int it = 0; it < 64; ++it) {
        int j = lane + (it << 6);
        float4 p = pb[j];
        #pragma unroll
        for (int qq = 0; qq < KNQ; ++qq) {
            float dx = p.x - qv[qq].x, dy = p.y - qv[qq].y, dz = p.z - qv[qq].z;
            float dd = dx * dx + dy * dy + dz * dz;
            dmin[qq] = fminf(dmin[qq], dd);
        }
    }
    float T[KNQ];
    #pragma unroll
    for (int qq = 0; qq < KNQ; ++qq) T[qq] = kth7min(dmin[qq]) * 1.000002f;

    #pragma unroll 4
    for (int it = 0; it < 64; ++it) {
        int j = lane + (it << 6);
        float4 p = pb[j];
        #pragma unroll
        for (int qq = 0; qq < KNQ; ++qq) {
            float dx = p.x - qv[qq].x, dy = p.y - qv[qq].y, dz = p.z - qv[qq].z;
            float dd = dx * dx + dy * dy + dz * dz;
            if (dd <= T[qq] && j != i0 + qq) {
                int slot = atomicAdd(&sCnt[w][qq], 1);
                if (slot < KCAP)
                    sHits[w][qq][slot] = ((u64)__float_as_uint(dd) << 32) | (u32)j;
            }
        }
    }
    __syncthreads();

    const int g = lane >> 5, li = lane & 31;
    const int cnt = sCnt[w][g];
    const int q = i0 + g;
    u64 ent = (li < (cnt < KCAP ? cnt : KCAP)) ? sHits[w][g][li] : ~0ull;
    int myj = -1;
    #pragma unroll
    for (int k = 0; k < 6; ++k) {
        u64 m = ent;
        #pragma unroll
        for (int off = 1; off < 32; off <<= 1) {
            u64 o = shflxor64(m, off);
            if (o < m) m = o;
        }
        if (li == k) myj = (int)(u32)(m & 0xffffffffull);
        if (ent == m) ent = ~0ull;
    }
    if (cnt <= KCAP && li < 6) {
        size_t e = (size_t)(b * N_ + q) * 6 + li;
        idxv[e] = myj;
        geom_write(pb, q, myj, e, uv, rbfv);
    }

    u64 ovf = __ballot(li == 0 && cnt > KCAP);
    while (ovf) {
        int gl = __ffsll(ovf) - 1; ovf &= ovf - 1;
        int qq = gl >> 5;
        int qx = i0 + qq;
        float4 qp = pb[qx];
        float Tq = T[0];
        #pragma unroll
        for (int z = 1; z < KNQ; ++z) if (z == qq) Tq = T[z];
        float e0 = BIG, e1 = BIG, e2 = BIG, e3 = BIG, e4 = BIG, e5 = BIG;
        int j0 = 0, j1 = 0, j2 = 0, j3 = 0, j4 = 0, j5 = 0;
        for (int it = 0; it < 64; ++it) {
            int j = lane + (it << 6);
            float4 p = pb[j];
            float dx = p.x - qp.x, dy = p.y - qp.y, dz = p.z - qp.z;
            float dd = dx * dx + dy * dy + dz * dz;
            if (dd <= Tq && j != qx && dd < e5) {
                e5 = dd; j5 = j;
                float td; int tj;
                if (e5 < e4) { td = e4; e4 = e5; e5 = td; tj = j4; j4 = j5; j5 = tj; }
                if (e4 < e3) { td = e3; e3 = e4; e4 = td; tj = j3; j3 = j4; j4 = tj; }
                if (e3 < e2) { td = e2; e2 = e3; e3 = td; tj = j2; j2 = j3; j3 = tj; }
                if (e2 < e1) { td = e1; e1 = e2; e2 = td; tj = j1; j1 = j2; j2 = tj; }
                if (e1 < e0) { td = e0; e0 = e1; e1 = td; tj = j0; j0 = j1; j1 = tj; }
            }
        }
        u64 a0 = ((u64)__float_as_uint(e0) << 32) | (u32)j0;
        u64 a1 = ((u64)__float_as_uint(e1) << 32) | (u32)j1;
        u64 a2 = ((u64)__float_as_uint(e2) << 32) | (u32)j2;
        u64 a3 = ((u64)__float_as_uint(e3) << 32) | (u32)j3;
        u64 a4 = ((u64)__float_as_uint(e4) << 32) | (u32)j4;
        u64 a5 = ((u64)__float_as_uint(e5) << 32) | (u32)j5;
        int fj = -1;
        #pragma unroll
        for (int k = 0; k < 6; ++k) {
            u64 m = a0;
            #pragma unroll
            for (int off = 1; off < 64; off <<= 1) {
                u64 o = shflxor64(m, off);
                if (o < m) m = o;
            }
            if (a0 == m) { a0 = a1; a1 = a2; a2 = a3; a3 = a4; a4 = a5; a5 = ~0ull; }
            if (lane == k) fj = (int)(u32)(m & 0xffffffffull);
        }
        if (lane < 6) {
            size_t e = (size_t)(b * N_ + qx) * 6 + lane;
            idxv[e] = fj;
            geom_write(pb, qx, fj, e, uv, rbfv);
        }
    }
}

// ---------------- MFMA bf16 GEMM body: BMx128 tile, register-prefetch pipelined ----------------
template<int KD, int BM, int EPI, bool LN, bool X1ACC>
__device__ __forceinline__ void mgemm_body(
    const u16* __restrict__ A, const u16* __restrict__ WT,
    const float* __restrict__ bias, const float* __restrict__ aux,
    float* __restrict__ C, u16* __restrict__ Cb, int ldc,
    const float* __restrict__ lns, const float* __restrict__ lnb,
    u16* __restrict__ lnout,
    int bx, int by, u16* sA, u16* sB, float* sLNraw)
{
    constexpr int MI = BM / 16;
    float (*sLN)[4][2] = (float(*)[4][2])sLNraw;
    const int tid = threadIdx.x;
    const int lane = tid & 63, wn = tid >> 6;
    const int m0 = bx * BM, n0 = by * 128;
    f32x4 acc[MI][2] = {};

    const bool aload = (BM == 64) || (tid < BM * 4);
    const int arow = tid >> 2, agk = tid & 3;
    const int c0 = tid * 2, c1 = tid * 2 + 1;
    const int brow0 = c0 >> 2, bgk0 = c0 & 3;
    const int brow1 = c1 >> 2, bgk1 = c1 & 3;

    // prefetch tile 0 into registers
    uint4 ra = {}, rb0v, rb1v;
    if (aload) ra = *(const uint4*)&A[(size_t)(m0 + arow) * KD + agk * 8];
    rb0v = *(const uint4*)&WT[(size_t)(n0 + brow0) * KD + bgk0 * 8];
    rb1v = *(const uint4*)&WT[(size_t)(n0 + brow1) * KD + bgk1 * 8];

    #pragma unroll
    for (int k0 = 0; k0 < KD; k0 += 32) {
        // write staged regs to LDS
        if (aload) *(uint4*)&sA[arow * 40 + agk * 8] = ra;
        *(uint4*)&sB[brow0 * 40 + bgk0 * 8] = rb0v;
        *(uint4*)&sB[brow1 * 40 + bgk1 * 8] = rb1v;
        __syncthreads();
        // issue next tile's global loads (overlap with ds_read + MFMA below)
        if (k0 + 32 < KD) {
            if (aload) ra = *(const uint4*)&A[(size_t)(m0 + arow) * KD + k0 + 32 + agk * 8];
            rb0v = *(const uint4*)&WT[(size_t)(n0 + brow0) * KD + k0 + 32 + bgk0 * 8];
            rb1v = *(const uint4*)&WT[(size_t)(n0 + brow1) * KD + k0 + 32 + bgk1 * 8];
        }
        const int gk = lane >> 4, lr = lane & 15;
        short8 af[MI], bfr[2];
        #pragma unroll
        for (int i = 0; i < MI; ++i)
            af[i] = *(const short8*)&sA[(i * 16 + lr) * 40 + gk * 8];
        #pragma unroll
        for (int i = 0; i < 2; ++i)
            bfr[i] = *(const short8*)&sB[(wn * 32 + i * 16 + lr) * 40 + gk * 8];
        #pragma unroll
        for (int mi = 0; mi < MI; ++mi)
            #pragma unroll
            for (int ni = 0; ni < 2; ++ni)
                acc[mi][ni] = __builtin_amdgcn_mfma_f32_16x16x32_bf16(af[mi], bfr[ni], acc[mi][ni], 0, 0, 0);
        __syncthreads();
    }

    const int lg = lane >> 4;
    const int lc = lane & 15;
    if (LN) {
        float s1[MI][4], s2[MI][4];
        #pragma unroll
        for (int mi = 0; mi < MI; ++mi) {
            int rbase = m0 + mi * 16 + lg * 4;
            #pragma unroll
            for (int ee = 0; ee < 4; ++ee) { s1[mi][ee] = 0.f; s2[mi][ee] = 0.f; }
            #pragma unroll
            for (int ni = 0; ni < 2; ++ni) {
                int col = wn * 32 + ni * 16 + lc;
                float bc = bias ? bias[col] : 0.f;
                #pragma unroll
                for (int ee = 0; ee < 4; ++ee) {
                    float v = acc[mi][ni][ee] + bc;
                    if (EPI == 1) v += C[(size_t)(rbase + ee) * 128 + col];
                    acc[mi][ni][ee] = v;
                    s1[mi][ee] += v;
                    s2[mi][ee] += v * v;
                }
            }
        }
        #pragma unroll
        for (int mi = 0; mi < MI; ++mi)
            #pragma unroll
            for (int ee = 0; ee < 4; ++ee)
                #pragma unroll
                for (int off = 1; off < 16; off <<= 1) {
                    s1[mi][ee] += __shfl_xor(s1[mi][ee], off, 64);
                    s2[mi][ee] += __shfl_xor(s2[mi][ee], off, 64);
                }
        if (lc == 0) {
            #pragma unroll
            for (int mi = 0; mi < MI; ++mi)
                #pragma unroll
                for (int ee = 0; ee < 4; ++ee) {
                    int r = mi * 16 + lg * 4 + ee;
                    sLN[r][wn][0] = s1[mi][ee];
                    sLN[r][wn][1] = s2[mi][ee];
                }
        }
        __syncthreads();
        #pragma unroll
        for (int mi = 0; mi < MI; ++mi) {
            int rbase = m0 + mi * 16 + lg * 4;
            #pragma unroll
            for (int ee = 0; ee < 4; ++ee) {
                int r = mi * 16 + lg * 4 + ee;
                float sum = sLN[r][0][0] + sLN[r][1][0] + sLN[r][2][0] + sLN[r][3][0];
                float sq  = sLN[r][0][1] + sLN[r][1][1] + sLN[r][2][1] + sLN[r][3][1];
                float mean = sum * (1.f / 128.f);
                float var = sq * (1.f / 128.f) - mean * mean;
                float inv = 1.f / sqrtf(var + 1e-5f);
                #pragma unroll
                for (int ni = 0; ni < 2; ++ni) {
                    int col = wn * 32 + ni * 16 + lc;
                    float v = acc[mi][ni][ee];
                    size_t o = (size_t)(rbase + ee) * 128 + col;
                    C[o] = v;
                    lnout[o] = f2bf((v - mean) * inv * lns[col] + lnb[col]);
                }
            }
        }
        return;
    }

    #pragma unroll
    for (int mi = 0; mi < MI; ++mi) {
        int rbase = m0 + mi * 16 + lg * 4;
        #pragma unroll
        for (int ni = 0; ni < 2; ++ni) {
            int col = n0 + wn * 32 + ni * 16 + lc;
            if (EPI == 0) {
                float bc = bias ? bias[col] : 0.f;
                #pragma unroll
                for (int ee = 0; ee < 4; ++ee)
                    C[(size_t)(rbase + ee) * ldc + col] = acc[mi][ni][ee] + bc;
            } else if (EPI == 1) {
                float bc = bias ? bias[col] : 0.f;
                #pragma unroll
                for (int ee = 0; ee < 4; ++ee) {
                    size_t o = (size_t)(rbase + ee) * ldc + col;
                    C[o] += acc[mi][ni][ee] + bc;
                }
            } else if (EPI == 2) {
                float bc = bias[col];
                if (n0 == 0) {
                    #pragma unroll
                    for (int ee = 0; ee < 4; ++ee)
                        C[(size_t)(rbase + ee) * 128 + col] = sigm(acc[mi][ni][ee] + bc);
                } else {
                    int c2 = col - 128;
                    #pragma unroll
                    for (int ee = 0; ee < 4; ++ee)
                        Cb[(size_t)(rbase + ee) * 256 + c2] = f2bf(silu(acc[mi][ni][ee] + bc));
                }
            } else if (EPI == 4) {
                float bc = bias ? bias[col] : 0.f;
                #pragma unroll
                for (int ee = 0; ee < 4; ++ee)
                    Cb[(size_t)(rbase + ee) * ldc + col] = f2bf(acc[mi][ni][ee] + bc);
            } else {
                #pragma unroll
                for (int ee = 0; ee < 4; ++ee) {
                    int m = rbase + ee;
                    size_t o = (size_t)m * 128 + col;
                    float v = acc[mi][ni][ee];
                    if (X1ACC) v += C[o];
                    v *= aux[(size_t)(m / 3) * 128 + col];
                    C[o] = v;
                    Cb[o] = f2bf(v);
                }
            }
        }
    }
}

template<int KD, int BM, int EPI, bool LN, bool X1ACC>
__global__ __launch_bounds__(256) void k_mgemm(
    const u16* __restrict__ A, const u16* __restrict__ WT,
    const float* __restrict__ bias, const float* __restrict__ aux,
    float* __restrict__ C, u16* __restrict__ Cb, int ldc,
    const float* __restrict__ lns, const float* __restrict__ lnb,
    u16* __restrict__ lnout)
{
    __shared__ u16 sA[64 * 40];
    __shared__ u16 sB[128 * 40];
    __shared__ float sLN[64 * 4 * 2];
    mgemm_body<KD, BM, EPI, LN, X1ACC>(A, WT, bias, aux, C, Cb, ldc, lns, lnb, lnout,
                                       blockIdx.x, blockIdx.y, sA, sB, sLN);
}

// dual GEMM: blocks [0,nx0) run part 0 (bx=id%nxdiv0, by=id/nxdiv0); rest part 1 (by=0)
template<int KD0, int BM0, int EPI0, bool LN0, bool XA0,
         int KD1, int BM1, int EPI1, bool LN1v, bool XA1>
__global__ __launch_bounds__(256) void k_mgemm_dual(
    const u16* A0, const u16* WT0, const float* b0, const float* aux0,
    float* C0, u16* Cb0, int ldc0, const float* lns0, const float* lnb0, u16* ln0,
    int nx0, int nxdiv0,
    const u16* A1, const u16* WT1, const float* b1, const float* aux1,
    float* C1, u16* Cb1, int ldc1, const float* lns1, const float* lnb1, u16* ln1)
{
    __shared__ u16 sA[64 * 40];
    __shared__ u16 sB[128 * 40];
    __shared__ float sLN[64 * 4 * 2];
    int id = blockIdx.x;
    if (id < nx0) {
        mgemm_body<KD0, BM0, EPI0, LN0, XA0>(A0, WT0, b0, aux0, C0, Cb0, ldc0, lns0, lnb0, ln0,
                                             id % nxdiv0, id / nxdiv0, sA, sB, sLN);
    } else {
        id -= nx0;
        mgemm_body<KD1, BM1, EPI1, LN1v, XA1>(A1, WT1, b1, aux1, C1, Cb1, ldc1, lns1, lnb1, ln1,
                                              id, 0, sA, sB, sLN);
    }
}

// ---------------- fused attention v3: wave-per-row, barrier-free ----------------
template<bool HASY1>
__global__ __launch_bounds__(256) void k_attn(
    const u16* __restrict__ qkvb, const int* __restrict__ idxv,
    const float* __restrict__ rbfv, const float* __restrict__ uv,
    const u16* __restrict__ y1b,
    const float* __restrict__ rw1T, const float* __restrict__ rb1,
    const float* __restrict__ rw2vT, const float* __restrict__ rwg,
    const float* __restrict__ rb2,
    u16* __restrict__ o0b, u16* __restrict__ o1b)
{
    const int wid = threadIdx.x >> 6, lane = threadIdx.x & 63;
    const int row = blockIdx.x * 4 + wid;
    const int b = row >> 12;
    const int ch0 = lane * 2;
    const int h = lane >> 4;

    __shared__ float sHid[4][6][16];
    __shared__ float sU[4][6][3];

    int jl = 0;
    if (lane < 6) jl = idxv[row * 6 + lane];
    int jj[6];
    #pragma unroll
    for (int k = 0; k < 6; ++k) jj[k] = __shfl(jl, k, 64);

    if (lane < 18) sU[wid][lane / 3][lane % 3] = uv[(size_t)row * 18 + lane];

    {
        int idx = lane;
        #pragma unroll
        for (int rep = 0; rep < 2; ++rep) {
            if (idx < 96) {
                int k = idx >> 4, hh = idx & 15;
                float a = rb1[hh];
                const float* rb = rbfv + (size_t)(row * 6 + k) * 16;
                const float* wr = rw1T + hh * 16;
                #pragma unroll
                for (int rr = 0; rr < 16; ++rr) a += rb[rr] * wr[rr];
                sHid[wid][k][hh] = silu(a);
            }
            idx += 64;
        }
    }
    __builtin_amdgcn_wave_barrier();
    __threadfence_block();
    __builtin_amdgcn_wave_barrier();

    u32 qp = *(const u32*)&qkvb[(size_t)row * 384 + ch0];
    float q0 = bf2f((u16)qp), q1 = bf2f((u16)(qp >> 16));

    float part[6];
    #pragma unroll
    for (int k = 0; k < 6; ++k) {
        u32 kp = *(const u32*)&qkvb[(size_t)(b * N_ + jj[k]) * 384 + 128 + ch0];
        part[k] = q0 * bf2f((u16)kp) + q1 * bf2f((u16)(kp >> 16));
    }
    #pragma unroll
    for (int off = 1; off < 16; off <<= 1)
        #pragma unroll
        for (int k = 0; k < 6; ++k)
            part[k] += __shfl_xor(part[k], off, 64);

    float lg[6];
    #pragma unroll
    for (int k = 0; k < 6; ++k) {
        float bias = rwg[64 + h];
        #pragma unroll
        for (int hh = 0; hh < 16; ++hh) bias += sHid[wid][k][hh] * rwg[hh * 4 + h];
        lg[k] = part[k] * 0.17677669529663687f + bias;
    }

    float mx = lg[0];
    #pragma unroll
    for (int k = 1; k < 6; ++k) mx = fmaxf(mx, lg[k]);
    float a[6], smv = 0.f;
    #pragma unroll
    for (int k = 0; k < 6; ++k) { a[k] = expf(lg[k] - mx); smv += a[k]; }
    float inv = 1.f / smv;
    #pragma unroll
    for (int k = 0; k < 6; ++k) a[k] *= inv;

    float rwc0[16], rwc1[16];
    {
        const float4* wp = (const float4*)(rw2vT + ch0 * 16);
        #pragma unroll
        for (int i = 0; i < 4; ++i) {
            float4 v0 = wp[i], v1 = wp[i + 4];
            rwc0[i * 4 + 0] = v0.x; rwc0[i * 4 + 1] = v0.y; rwc0[i * 4 + 2] = v0.z; rwc0[i * 4 + 3] = v0.w;
            rwc1[i * 4 + 0] = v1.x; rwc1[i * 4 + 1] = v1.y; rwc1[i * 4 + 2] = v1.z; rwc1[i * 4 + 3] = v1.w;
        }
    }
    float rb20 = rb2[128 + ch0], rb21 = rb2[128 + ch0 + 1];
    float rvk0[6], rvk1[6];
    #pragma unroll
    for (int k = 0; k < 6; ++k) {
        float a0 = rb20, a1 = rb21;
        #pragma unroll
        for (int hh = 0; hh < 16; ++hh) {
            float hv = sHid[wid][k][hh];
            a0 += hv * rwc0[hh];
            a1 += hv * rwc1[hh];
        }
        rvk0[k] = a0; rvk1[k] = a1;
    }

    float o00 = 0.f, o01 = 0.f;
    #pragma unroll
    for (int k = 0; k < 6; ++k) {
        u32 vp = *(const u32*)&qkvb[(size_t)(b * N_ + jj[k]) * 384 + 256 + ch0];
        o00 += a[k] * bf2f((u16)vp) * silu(rvk0[k]);
        o01 += a[k] * bf2f((u16)(vp >> 16)) * silu(rvk1[k]);
    }
    *(u32*)&o0b[(size_t)row * 128 + ch0] = (u32)f2bf(o00) | ((u32)f2bf(o01) << 16);

    #pragma unroll
    for (int c = 0; c < 3; ++c) {
        float s0 = 0.f, s1 = 0.f;
        #pragma unroll
        for (int k = 0; k < 6; ++k) {
            float b0 = 0.f, b1 = 0.f;
            if (HASY1) {
                u32 yp = *(const u32*)&y1b[((size_t)(b * N_ + jj[k]) * 3 + c) * 128 + ch0];
                b0 = bf2f((u16)yp); b1 = bf2f((u16)(yp >> 16));
            }
            float uk = sU[wid][k][c];
            s0 += a[k] * (b0 + rvk0[k] * uk);
            s1 += a[k] * (b1 + rvk1[k] * uk);
        }
        *(u32*)&o1b[((size_t)row * 3 + c) * 128 + ch0] = (u32)f2bf(s0) | ((u32)f2bf(s1) << 16);
    }
}

// ---------------- fused heads: blocks [0,128) state GEMM; [128,320) force1 ----------------
__global__ __launch_bounds__(256) void k_head(
    const float* __restrict__ x0, const float* __restrict__ W_state,
    const float* __restrict__ b_state, float* __restrict__ out,
    const float* __restrict__ x1, const float* __restrict__ W_force,
    const float* __restrict__ b_force, float* __restrict__ frc)
{
    __shared__ __align__(16) float As[32 * 132];
    __shared__ __align__(16) float Ws[32 * 68];
    const int tid = threadIdx.x;
    if (blockIdx.x < 128) {
        const int tx = tid & 15, ty = tid >> 4;
        const int m0 = blockIdx.x * 128, n0 = 0;
        float acc[8][4] = {};
        for (int k0 = 0; k0 < 128; k0 += 32) {
            __syncthreads();
            #pragma unroll
            for (int r = 0; r < 4; ++r) {
                int id = tid + r * 256;
                int row = id >> 3, kq = id & 7;
                float4 a4 = *(const float4*)&x0[(size_t)(m0 + row) * 128 + k0 + kq * 4];
                As[(kq * 4 + 0) * 132 + row] = a4.x;
                As[(kq * 4 + 1) * 132 + row] = a4.y;
                As[(kq * 4 + 2) * 132 + row] = a4.z;
                As[(kq * 4 + 3) * 132 + row] = a4.w;
            }
            #pragma unroll
            for (int r = 0; r < 2; ++r) {
                int id = tid + r * 256;
                int kr = id >> 4, cq = id & 15;
                *(float4*)&Ws[kr * 68 + cq * 4] =
                    *(const float4*)&W_state[(size_t)(k0 + kr) * 64 + n0 + cq * 4];
            }
            __syncthreads();
            #pragma unroll 8
            for (int k = 0; k < 32; ++k) {
                float4 aA = *(const float4*)&As[k * 132 + ty * 8];
                float4 aB = *(const float4*)&As[k * 132 + ty * 8 + 4];
                float4 w4 = *(const float4*)&Ws[k * 68 + tx * 4];
                float av[8] = {aA.x, aA.y, aA.z, aA.w, aB.x, aB.y, aB.z, aB.w};
                float wv[4] = {w4.x, w4.y, w4.z, w4.w};
                #pragma unroll
                for (int r = 0; r < 8; ++r)
                    #pragma unroll
                    for (int j = 0; j < 4; ++j)
                        acc[r][j] += av[r] * wv[j];
            }
        }
        float bv[4];
        #pragma unroll
        for (int j = 0; j < 4; ++j) bv[j] = b_state[n0 + tx * 4 + j];
        #pragma unroll
        for (int r = 0; r < 8; ++r) {
            int m = m0 + ty * 8 + r;
            int n = m & (N_ - 1), bb2 = m >> 12;
            if (n == 0) continue;
            float* dst = out + ((size_t)(bb2 * NC_ + n - 1)) * 64 + n0 + tx * 4;
            float4 res = {acc[r][0] + bv[0], acc[r][1] + bv[1], acc[r][2] + bv[2], acc[r][3] + bv[3]};
            *(float4*)dst = res;
        }
    } else {
        int g = (blockIdx.x - 128) * 256 + tid;
        if (g >= B_ * NC_ * 3) return;
        int c = g % 3, rr = g / 3;
        int b = rr / NC_, n = rr - b * NC_;
        const float* xr = x1 + (size_t)(b * N_ + n + 1) * 384 + c * 128;
        float a = b_force[0];
        for (int d = 0; d < 128; ++d) a += xr[d] * W_force[d];
        frc[g] = a;
    }
}

__global__ __launch_bounds__(256) void k_fsum(const float* __restrict__ frc, float* __restrict__ fsum)
{
    int b = blockIdx.x / 3, c = blockIdx.x % 3;
    __shared__ float red[256];
    float a = 0.f;
    for (int n = threadIdx.x; n < NC_; n += 256) a += frc[(b * NC_ + n) * 3 + c];
    red[threadIdx.x] = a; __syncthreads();
    for (int st = 128; st > 0; st >>= 1) { if (threadIdx.x < st) red[threadIdx.x] += red[threadIdx.x + st]; __syncthreads(); }
    if (threadIdx.x == 0) fsum[blockIdx.x] = red[0] / (float)NC_;
}

__global__ void k_force2(const float* __restrict__ frc, const float* __restrict__ fsum,
                         float* __restrict__ out)
{
    int g = blockIdx.x * 256 + threadIdx.x;
    if (g >= B_ * NC_ * 3) return;
    int c = g % 3;
    int b = g / (NC_ * 3);
    out[g] = frc[g] - fsum[b * 3 + c];
}

} // namespace

extern "C" void kernel_launch(void* const* d_in, const int* in_sizes, int n_in,
                              void* d_out, int out_size, void* d_ws, size_t ws_size,
                              hipStream_t stream)
{
    const float* X       = (const float*)d_in[0];
    const float* W_embed = (const float*)d_in[1];
    const float* b_embed = (const float*)d_in[2];
    const float* Wq      = (const float*)d_in[3];
    const float* Wk      = (const float*)d_in[4];
    const float* Wv      = (const float*)d_in[5];
    const float* Wvv     = (const float*)d_in[6];
    const float* rw1     = (const float*)d_in[7];
    const float* rb1     = (const float*)d_in[8];
    const float* rw2     = (const float*)d_in[9];
    const float* rb2     = (const float*)d_in[10];
    const float* Wo      = (const float*)d_in[11];
    const float* Wov     = (const float*)d_in[12];
    const float* ff_w1   = (const float*)d_in[13];
    const float* ff_b1   = (const float*)d_in[14];
    const float* ff_w2   = (const float*)d_in[15];
    const float* ff_b2   = (const float*)d_in[16];
    const float* gate_w  = (const float*)d_in[17];
    const float* gate_b  = (const float*)d_in[18];
    const float* ln1_s   = (const float*)d_in[19];
    const float* ln1_b   = (const float*)d_in[20];
    const float* ln2_s   = (const float*)d_in[21];
    const float* ln2_b   = (const float*)d_in[22];
    const float* W_state = (const float*)d_in[23];
    const float* b_state = (const float*)d_in[24];
    const float* W_force = (const float*)d_in[25];
    const float* b_force = (const float*)d_in[26];
    (void)in_sizes; (void)n_in; (void)out_size; (void)ws_size;

    float* out = (float*)d_out;
    float* w = (float*)d_ws;

    float4* pos4  = (float4*)w;                    // -> 65536
    int*    idxv  = (int*)(w + 65536);             // -> 163840
    float*  uv    = w + 163840;                    // -> 458752
    float*  rbfv  = w + 458752;                    // -> 2031616
    u16*    featsb= (u16*)(w + 2031616);           // -> 2555904 (frc/fsum alias later)
    float*  x0    = w + 2555904;                   // -> 4653056
    u16*    hbb   = (u16*)(w + 4653056);           // -> 5701632
    u16*    qkvbb = (u16*)(w + 5701632);           // -> 8847360 used
    float*  gb    = w + 11993088;                  // -> 14090240
    u16*    o0b   = (u16*)(w + 14090240);          // -> 15138816
    u16*    o1b   = (u16*)(w + 15138816);          // -> 18284544
    float*  x1    = w + 18284544;                  // -> 24576000
    u16*    x1b   = (u16*)(w + 24576000);          // -> 27721728
    u16*    t1b   = (u16*)(w + 27721728);          // bf16; also y1b (disjoint live ranges)
    u16*    y1b   = t1b;
    u16*    WqkvT = (u16*)(w + 34013184);
    u16*    Wc2T  = (u16*)(w + 34062336);
    u16*    WvvT  = (u16*)(w + 34111488);
    u16*    WovT  = (u16*)(w + 34127872);
    u16*    WoT   = (u16*)(w + 34144256);
    u16*    fw2T  = (u16*)(w + 34160640);
    u16*    WembT = (u16*)(w + 34193408);
    float*  bias2 = w + 34197504;                  // 2x384 -> 34198272
    float*  rwg   = w + 34198272;                  // 2x128 -> 34198528
    float*  rw1T  = w + 34198528;                  // 2x256 -> 34199040
    float*  rw2vT = w + 34199040;                  // 2x2048 -> 34203136
    float*  frc   = (float*)featsb;
    float*  fsum  = ((float*)featsb) + 49152;

    // fused prep + weight prep (4096 + 1494 blocks)
    k_prepall<<<5590, 256, 0, stream>>>(X, pos4, featsb,
                                        Wq, Wk, Wv, gate_w, ff_w1, gate_b, ff_b1,
                                        Wvv, Wov, Wo, ff_w2, rw2, rb2, W_embed, rw1,
                                        WqkvT, Wc2T, WvvT, WovT, WoT, fw2T, WembT,
                                        bias2, rwg, rw1T, rw2vT);
    k_knn<<<ROWS_ / 8, 256, 0, stream>>>(pos4, idxv, uv, rbfv);
    // x0 = feats @ W_embed + b_embed ; hbb = LN1(x0)
    k_mgemm<64, 32, 0, true, true><<<dim3(512, 1), 256, 0, stream>>>(
        featsb, WembT, b_embed, nullptr, x0, nullptr, 128, ln1_s, ln1_b, hbb);

    for (int l = 0; l < 2; ++l) {
        const float* rb1_l = rb1 + l * 16;
        const float* rb2_l = rb2 + l * 256;
        const float* fb2_l = ff_b2 + l * 128;

        // qkv (= h @ Wqkv, bf16 out); layer 1 fused with y1 = x1 @ Wvv
        if (l == 0)
            k_mgemm<128, 64, 4, false, true><<<dim3(256, 3), 256, 0, stream>>>(
                hbb, WqkvT, nullptr, nullptr, nullptr, qkvbb, 384, nullptr, nullptr, nullptr);
        else
            k_mgemm_dual<128, 64, 4, false, true, 128, 64, 4, false, true><<<1536, 256, 0, stream>>>(
                hbb, WqkvT + 49152, nullptr, nullptr, nullptr, qkvbb, 384, nullptr, nullptr, nullptr,
                768, 256,
                x1b, WvvT + 16384, nullptr, nullptr, nullptr, y1b, 128, nullptr, nullptr, nullptr);
        // attention (wave-per-row)
        if (l == 0)
            k_attn<false><<<ROWS_ / 4, 256, 0, stream>>>(qkvbb, idxv, rbfv, uv, nullptr,
                rw1T + l * 256, rb1_l, rw2vT + l * 2048, rwg + l * 128, rb2_l, o0b, o1b);
        else
            k_attn<true><<<ROWS_ / 4, 256, 0, stream>>>(qkvbb, idxv, rbfv, uv, y1b,
                rw1T + l * 256, rb1_l, rw2vT + l * 2048, rwg + l * 128, rb2_l, o0b, o1b);
        // x0 += o0 @ Wo ; hbb = LN2(x0)
        k_mgemm<128, 32, 1, true, true><<<dim3(512, 1), 256, 0, stream>>>(
            o0b, WoT + l * 16384, nullptr, nullptr, x0, nullptr, 128,
            ln2_s + l * 128, ln2_b + l * 128, hbb);
        // [gate fp32 | t1 bf16] = h2 @ [gate_w|ff_w1]
        k_mgemm<128, 64, 2, false, true><<<dim3(256, 3), 256, 0, stream>>>(
            hbb, Wc2T + l * 49152, bias2 + l * 384, nullptr, gb, t1b, 128, nullptr, nullptr, nullptr);
        // fused: x1 = ((l? x1:0) + o1 @ Wov) * gate  ||  x0 += t1 @ ff_w2 (+LN1' on l0)
        if (l == 0)
            k_mgemm_dual<128, 64, 3, false, false, 256, 32, 1, true, true><<<1280, 256, 0, stream>>>(
                o1b, WovT, nullptr, gb, x1, x1b, 128, nullptr, nullptr, nullptr,
                768, 768,
                t1b, fw2T, fb2_l, nullptr, x0, nullptr, 128, ln1_s + 128, ln1_b + 128, hbb);
        else
            k_mgemm_dual<128, 64, 3, false, true, 256, 32, 1, false, true><<<1280, 256, 0, stream>>>(
                o1b, WovT + 16384, nullptr, gb, x1, x1b, 128, nullptr, nullptr, nullptr,
                768, 768,
                t1b, fw2T + 32768, fb2_l, nullptr, x0, nullptr, 128, nullptr, nullptr, nullptr);
    }

    // fused: state head (128 blocks) + force1 (192 blocks)
    k_head<<<320, 256, 0, stream>>>(x0, W_state, b_state, out, x1, W_force, b_force, frc);
    k_fsum<<<12, 256, 0, stream>>>(frc, fsum);
    k_force2<<<(B_ * NC_ * 3 + 255) / 256, 256, 0, stream>>>(frc, fsum, out + (size_t)B_ * NC_ * DIN_);
}